// Round 2
// baseline (1114.254 us; speedup 1.0000x reference)
//
#include <hip/hip_runtime.h>
#include <cmath>

// CTC alignment loss (RAD-TTS style), B=64, T<=2000, K<=400.
// Strategy: one block per batch sample (serial t-recursion), 832 threads = 13 waves,
// one CTC state per thread, alpha in probability domain with power-of-2 rescaling
// (every 8 steps) instead of log-domain logaddexp -> ~6x fewer transcendentals.
// Pass 1 (fused, per block): masked logsumexp per row t -> lse_sh/blp_sh in LDS.
// Pass 2: sequential scan, alpha double-buffered in LDS, 1 barrier/step.

#define T_MAXN 2000
#define K_MAXN 400
#define S_MAXN 801        // 2*K+1
#define NTHREADS 832      // 13 waves of 64
#define NWAVES 13
#define RESCALE_MASK 7    // rescale every 8 steps

__global__ __launch_bounds__(NTHREADS)
void ctc_forward_kernel(const float* __restrict__ ap_all,
                        const int* __restrict__ in_lens,
                        const int* __restrict__ out_lens,
                        float* __restrict__ loss_out)
{
    __shared__ float lse_sh[T_MAXN];
    __shared__ float blp_sh[T_MAXN];
    __shared__ float bufA[S_MAXN + 3];   // [0],[1] = zero pads so s-1/s-2 reads never go OOB
    __shared__ float bufB[S_MAXN + 3];
    __shared__ float red_sh[NWAVES];

    const int b    = blockIdx.x;
    const int tid  = threadIdx.x;
    const int lane = tid & 63;
    const int wid  = tid >> 6;
    const int L    = in_lens[b];     // in [200,400]
    const int Tn   = out_lens[b];    // in [1000,2000]
    const float* __restrict__ ap = ap_all + (size_t)b * (T_MAXN * K_MAXN);

    // ---------- pass 1: lse[t] = logsumexp(blank=-1, ap[t][0..L-1]) for t < Tn ----------
    for (int t = wid; t < Tn; t += NWAVES) {
        const float* row = ap + t * K_MAXN;
        float v[7];
        float m = -1.0f;                       // blank logit always present
        #pragma unroll
        for (int i = 0; i < 7; ++i) {
            int k = lane + (i << 6);
            v[i] = (k < L) ? row[k] : -1e30f;  // predicated load, no OOB access
            m = fmaxf(m, v[i]);
        }
        #pragma unroll
        for (int off = 32; off; off >>= 1) m = fmaxf(m, __shfl_xor(m, off));
        float ssum = (lane == 0) ? __expf(-1.0f - m) : 0.0f;
        #pragma unroll
        for (int i = 0; i < 7; ++i) ssum += __expf(v[i] - m);   // exp(-1e30-m) -> 0
        #pragma unroll
        for (int off = 32; off; off >>= 1) ssum += __shfl_xor(ssum, off);
        if (lane == 0) {
            float lse = m + __logf(ssum);
            lse_sh[t] = lse;
            blp_sh[t] = __expf(-1.0f - lse);   // blank prob after log_softmax
        }
    }

    if (tid < 2) { bufA[tid] = 0.0f; bufB[tid] = 0.0f; }
    __syncthreads();

    // ---------- pass 2: sequential CTC scan in probability domain ----------
    const int  s      = tid;                 // state index
    const bool valids = (s < S_MAXN);
    const bool isOdd  = (s & 1) != 0;
    const int  k      = (s - 1) >> 1;        // label-1 column for odd states
    const bool kvalid = isOdd && (k < L) && valids;   // odd state within 2L

    float own = 0.0f;                         // alpha[t=0]
    if (s == 0) own = blp_sh[0];
    if (s == 1) own = __expf(ap[0] - lse_sh[0]);
    if (valids) bufA[2 + s] = own;
    __syncthreads();

    float* oldb = bufA;
    float* newb = bufB;
    int  E    = 0;       // accumulated power-of-2 exponent: alpha_true = alpha * 2^E
    bool dead = false;

    const float* pk     = ap + k;                         // this thread's label column
    float ap_cur        = kvalid ? pk[K_MAXN] : 0.0f;     // row t=1 (prefetched)
    const float* pnext  = pk + 2 * K_MAXN;                // row t=2

    for (int t = 1; t < Tn; ++t) {
        // prefetch next row's value (hide L3/HBM latency under this step's compute)
        float ap_nxt = 0.0f;
        if (kvalid && (t + 1 < Tn)) ap_nxt = *pnext;
        pnext += K_MAXN;

        const float lse_t = lse_sh[t];
        const float blp_t = blp_sh[t];

        float nw = 0.0f;
        if (valids) {
            float n1  = oldb[1 + s];          // alpha_old[s-1]  (pad -> 0 for s==0)
            float sum = own + n1;
            float f;
            if (isOdd) {
                sum += oldb[s];               // alpha_old[s-2]  (pad -> 0 for s==1)
                f = kvalid ? __expf(ap_cur - lse_t) : 0.0f;
            } else {
                f = blp_t;
            }
            nw = f * sum;
            newb[2 + s] = nw;
        }
        own    = nw;
        ap_cur = ap_nxt;

        if ((t & RESCALE_MASK) == 0) {
            // block max -> power-of-2 rescale (exact), accumulate exponent
            float mx = own;
            #pragma unroll
            for (int off = 32; off; off >>= 1) mx = fmaxf(mx, __shfl_xor(mx, off));
            if (lane == 0) red_sh[wid] = mx;
            __syncthreads();
            mx = red_sh[0];
            #pragma unroll
            for (int w = 1; w < NWAVES; ++w) mx = fmaxf(mx, red_sh[w]);
            if (mx == 0.0f) { dead = true; break; }   // block-uniform
            int e = (int)((__float_as_uint(mx) >> 23) & 0xFF) - 127;
            if (e != 0) {
                own = ldexpf(own, -e);
                E  += e;
                if (valids) newb[2 + s] = own;
            }
            __syncthreads();
        } else {
            __syncthreads();
        }
        float* tmp = oldb; oldb = newb; newb = tmp;
    }

    if (tid == 0) {
        float lossb = 0.0f;
        if (!dead) {
            float tot = oldb[2 + 2 * L] + oldb[1 + 2 * L];  // alpha[2L] + alpha[2L-1]
            if (tot > 0.0f) {
                double ll = log((double)tot) + (double)E * 0.69314718055994530942;
                lossb = (float)(-ll / (double)L);
            }
        }
        loss_out[b] = lossb;   // zero_infinity -> 0 handled by tot<=0 / dead
    }
}

__global__ void mean_kernel(const float* __restrict__ loss, float* __restrict__ out)
{
    float v = loss[threadIdx.x];   // 64 threads
    #pragma unroll
    for (int off = 32; off; off >>= 1) v += __shfl_xor(v, off);
    if (threadIdx.x == 0) out[0] = v * (1.0f / 64.0f);
}

extern "C" void kernel_launch(void* const* d_in, const int* in_sizes, int n_in,
                              void* d_out, int out_size, void* d_ws, size_t ws_size,
                              hipStream_t stream)
{
    // setup_inputs order: attn (unused), in_lens, out_lens, attn_logprob
    const int*   in_lens  = (const int*)d_in[1];
    const int*   out_lens = (const int*)d_in[2];
    const float* ap       = (const float*)d_in[3];
    float*       out      = (float*)d_out;
    float*       loss_ws  = (float*)d_ws;   // 64 floats

    hipLaunchKernelGGL(ctc_forward_kernel, dim3(64), dim3(NTHREADS), 0, stream,
                       ap, in_lens, out_lens, loss_ws);
    hipLaunchKernelGGL(mean_kernel, dim3(1), dim3(64), 0, stream, loss_ws, out);
}

// Round 3
// 391.814 us; speedup vs baseline: 2.8438x; 2.8438x over previous
//
#include <hip/hip_runtime.h>
#include <cmath>

// CTC alignment loss (RAD-TTS style), B=64, T<=2000, K<=400, S=2K+1<=801.
//
// Round-2 profile: 1114us, VALUBusy 5%, barrier-bound (13-wave __syncthreads per
// serial step). Redesign:
//   Kernel 1 (lse_kernel, massively parallel): per-row masked logsumexp -> ws.
//   Kernel 2 (ctc_scan_kernel): ONE WAVE per sample, 16 states/lane in registers,
//     zero barriers; cross-lane boundary via single __shfl_up per step.
//     Alpha is rescaled by prod(blank_prob) analytically: even factor == 1,
//     odd factor == exp(ap+1)  (no lse in the scan), correction added at end.
//     Power-of-2 rescale every 8 steps (exact, exponent tracked in int E).
//   Kernel 3: deterministic mean over 64 samples.

#define T_MAXN 2000
#define K_MAXN 400

// ---------------------------------------------------------------- pass 1: lse
__global__ __launch_bounds__(256)
void lse_kernel(const float* __restrict__ ap_all,
                const int* __restrict__ in_lens,
                float* __restrict__ lse_out)
{
    const int lane = threadIdx.x & 63;
    const int wglob = blockIdx.x * (blockDim.x >> 6) + (threadIdx.x >> 6);
    const int nwav = gridDim.x * (blockDim.x >> 6);
    const int nrows = 64 * T_MAXN;

    for (int row = wglob; row < nrows; row += nwav) {
        const int b = row / T_MAXN;
        const int L = in_lens[b];
        const float* rp = ap_all + (size_t)row * K_MAXN;
        const int c0 = lane * 8;
        const int cb = (c0 < 392) ? c0 : 392;          // clamp (lanes >=50 masked)
        const float4* p = reinterpret_cast<const float4*>(rp + cb);
        float4 x0 = p[0], x1 = p[1];
        float v[8] = {x0.x, x0.y, x0.z, x0.w, x1.x, x1.y, x1.z, x1.w};
        float m = -1.0f;                                // blank logit
        #pragma unroll
        for (int j = 0; j < 8; ++j) {
            v[j] = (c0 + j < L) ? v[j] : -1e30f;
            m = fmaxf(m, v[j]);
        }
        #pragma unroll
        for (int off = 32; off; off >>= 1) m = fmaxf(m, __shfl_xor(m, off));
        float s = (lane == 0) ? __expf(-1.0f - m) : 0.0f;
        #pragma unroll
        for (int j = 0; j < 8; ++j) s += __expf(v[j] - m);
        #pragma unroll
        for (int off = 32; off; off >>= 1) s += __shfl_xor(s, off);
        if (lane == 0) lse_out[row] = m + __logf(s);
    }
}

// ---------------------------------------------------------------- pass 2: scan
__global__ __launch_bounds__(64)
void ctc_scan_kernel(const float* __restrict__ ap_all,
                     const int* __restrict__ in_lens,
                     const int* __restrict__ out_lens,
                     const float* __restrict__ lse_all,
                     float* __restrict__ loss_out)
{
    __shared__ float afin[1024];

    const int b    = blockIdx.x;
    const int lane = threadIdx.x;
    const int L    = in_lens[b];      // [200,400]
    const int Tn   = out_lens[b];     // [1000,2000]
    const float* ap  = ap_all + (size_t)b * (T_MAXN * K_MAXN);
    const float* lse = lse_all + b * T_MAXN;

    // per-lane constants: lane covers states [16*lane, 16*lane+16),
    // odd-state labels -> columns c0..c0+7, c0 = 8*lane.
    const float LOG2E = 1.4426950408889634f;
    const int c0 = lane * 8;
    const int cb = (c0 < 392) ? c0 : 392;
    const float* rbase = ap + cb;
    float fa0,fa1,fa2,fa3,fa4,fa5,fa6,fa7;
    float fb0,fb1,fb2,fb3,fb4,fb5,fb6,fb7;
    #define MASKC(J, FA, FB) do { bool ok = (c0 + (J)) < L; \
        FA = ok ? LOG2E : 0.0f; FB = ok ? LOG2E : -1000.0f; } while (0)
    MASKC(0,fa0,fb0); MASKC(1,fa1,fb1); MASKC(2,fa2,fb2); MASKC(3,fa3,fb3);
    MASKC(4,fa4,fb4); MASKC(5,fa5,fb5); MASKC(6,fa6,fb6); MASKC(7,fa7,fb7);
    #undef MASKC

    // prefetch rows 1..4 early
    float4 p0a,p0b,p1a,p1b,p2a,p2b,p3a,p3b;
    #define LOADROW(PA, PB, T) do { \
        const float4* _p = reinterpret_cast<const float4*>(rbase + (size_t)(T) * K_MAXN); \
        PA = _p[0]; PB = _p[1]; } while (0)
    LOADROW(p0a,p0b,1); LOADROW(p1a,p1b,2); LOADROW(p2a,p2b,3); LOADROW(p3a,p3b,4);

    // prologue: S = sum_{t<Tn} lse[t]  (fixed deterministic order)
    float sl = 0.0f;
    for (int t = lane; t < Tn; t += 64) sl += lse[t];
    #pragma unroll
    for (int off = 32; off; off >>= 1) sl += __shfl_xor(sl, off);

    // init t=0 (scaled: alpha^[0]=1, alpha^[1]=exp(ap[0][0]+1))
    float x00 = ap[0];                                  // uniform broadcast load
    float a0=0,a1=0,a2=0,a3=0,a4=0,a5=0,a6=0,a7=0;
    float a8=0,a9=0,a10=0,a11=0,a12=0,a13=0,a14=0,a15=0;
    if (lane == 0) {
        a0 = 1.0f;
        a1 = __builtin_amdgcn_exp2f(fmaf(x00, LOG2E, LOG2E));
    }
    int E = 0;

    // one step: new_even[j] = old[2j]+old[2j-1]; new_odd[j] = f_j*(old[2j+1]+new_even[j])
    #define STEP(A0, A1) do { \
        float t1 = __shfl_up(a15, 1); \
        t1 = lane ? t1 : 0.0f; \
        const float f0 = __builtin_amdgcn_exp2f(fmaf((A0).x, fa0, fb0)); \
        const float f1 = __builtin_amdgcn_exp2f(fmaf((A0).y, fa1, fb1)); \
        const float f2 = __builtin_amdgcn_exp2f(fmaf((A0).z, fa2, fb2)); \
        const float f3 = __builtin_amdgcn_exp2f(fmaf((A0).w, fa3, fb3)); \
        const float f4 = __builtin_amdgcn_exp2f(fmaf((A1).x, fa4, fb4)); \
        const float f5 = __builtin_amdgcn_exp2f(fmaf((A1).y, fa5, fb5)); \
        const float f6 = __builtin_amdgcn_exp2f(fmaf((A1).z, fa6, fb6)); \
        const float f7 = __builtin_amdgcn_exp2f(fmaf((A1).w, fa7, fb7)); \
        const float e0 = a0 + t1,   e1 = a2 + a1,   e2 = a4 + a3,   e3 = a6 + a5; \
        const float e4 = a8 + a7,   e5 = a10 + a9,  e6 = a12 + a11, e7 = a14 + a13; \
        const float o0 = a1 + e0,   o1 = a3 + e1,   o2 = a5 + e2,   o3 = a7 + e3; \
        const float o4 = a9 + e4,   o5 = a11 + e5,  o6 = a13 + e6,  o7 = a15 + e7; \
        a0 = e0; a2 = e1; a4 = e2; a6 = e3; a8 = e4; a10 = e5; a12 = e6; a14 = e7; \
        a1 = f0*o0; a3 = f1*o1; a5 = f2*o2; a7 = f3*o3; \
        a9 = f4*o4; a11 = f5*o5; a13 = f6*o6; a15 = f7*o7; \
    } while (0)

    #define RESCALE do { \
        float mx = fmaxf(fmaxf(fmaxf(fmaxf(a0,a1),fmaxf(a2,a3)),fmaxf(fmaxf(a4,a5),fmaxf(a6,a7))), \
                         fmaxf(fmaxf(fmaxf(a8,a9),fmaxf(a10,a11)),fmaxf(fmaxf(a12,a13),fmaxf(a14,a15)))); \
        _Pragma("unroll") \
        for (int off = 32; off; off >>= 1) mx = fmaxf(mx, __shfl_xor(mx, off)); \
        int e = (int)((__float_as_uint(mx) >> 23) & 0xFF) - 127; \
        if (e != 0) { \
            E += e; \
            a0 = ldexpf(a0,-e);  a1 = ldexpf(a1,-e);  a2 = ldexpf(a2,-e);  a3 = ldexpf(a3,-e); \
            a4 = ldexpf(a4,-e);  a5 = ldexpf(a5,-e);  a6 = ldexpf(a6,-e);  a7 = ldexpf(a7,-e); \
            a8 = ldexpf(a8,-e);  a9 = ldexpf(a9,-e);  a10= ldexpf(a10,-e); a11= ldexpf(a11,-e); \
            a12= ldexpf(a12,-e); a13= ldexpf(a13,-e); a14= ldexpf(a14,-e); a15= ldexpf(a15,-e); \
        } \
    } while (0)

    int t = 1;
    while (t + 3 < Tn) {
        int tl;
        STEP(p0a,p0b); tl = (t+4 < T_MAXN) ? t+4 : T_MAXN-1; LOADROW(p0a,p0b,tl);
        STEP(p1a,p1b); tl = (t+5 < T_MAXN) ? t+5 : T_MAXN-1; LOADROW(p1a,p1b,tl);
        STEP(p2a,p2b); tl = (t+6 < T_MAXN) ? t+6 : T_MAXN-1; LOADROW(p2a,p2b,tl);
        STEP(p3a,p3b); tl = (t+7 < T_MAXN) ? t+7 : T_MAXN-1; LOADROW(p3a,p3b,tl);
        if ((t & 7) == 5) RESCALE;      // rescale after t = 8,16,24,...
        t += 4;
    }
    if (t < Tn) { STEP(p0a,p0b); ++t; }
    if (t < Tn) { STEP(p1a,p1b); ++t; }
    if (t < Tn) { STEP(p2a,p2b); ++t; }

    // readout: ll = log(alpha^[2L] + alpha^[2L-1]) + E*ln2 + sum_{t<Tn}(-1-lse_t)
    afin[16*lane+0]=a0;  afin[16*lane+1]=a1;  afin[16*lane+2]=a2;  afin[16*lane+3]=a3;
    afin[16*lane+4]=a4;  afin[16*lane+5]=a5;  afin[16*lane+6]=a6;  afin[16*lane+7]=a7;
    afin[16*lane+8]=a8;  afin[16*lane+9]=a9;  afin[16*lane+10]=a10; afin[16*lane+11]=a11;
    afin[16*lane+12]=a12; afin[16*lane+13]=a13; afin[16*lane+14]=a14; afin[16*lane+15]=a15;
    __syncthreads();
    if (lane == 0) {
        float tot = afin[2*L] + afin[2*L-1];
        float lossb = 0.0f;
        if (tot > 0.0f) {
            double ll = log((double)tot)
                      + (double)E * 0.69314718055994530942
                      + (double)(-(double)Tn - (double)sl);
            lossb = (float)(-ll / (double)L);
        }
        loss_out[b] = lossb;
    }
    #undef STEP
    #undef RESCALE
    #undef LOADROW
}

// ---------------------------------------------------------------- pass 3: mean
__global__ void mean_kernel(const float* __restrict__ loss, float* __restrict__ out)
{
    float v = loss[threadIdx.x];   // 64 threads
    #pragma unroll
    for (int off = 32; off; off >>= 1) v += __shfl_xor(v, off);
    if (threadIdx.x == 0) out[0] = v * (1.0f / 64.0f);
}

extern "C" void kernel_launch(void* const* d_in, const int* in_sizes, int n_in,
                              void* d_out, int out_size, void* d_ws, size_t ws_size,
                              hipStream_t stream)
{
    // setup_inputs order: attn (unused), in_lens, out_lens, attn_logprob
    const int*   in_lens  = (const int*)d_in[1];
    const int*   out_lens = (const int*)d_in[2];
    const float* ap       = (const float*)d_in[3];
    float*       out      = (float*)d_out;

    float* lse_ws  = (float*)d_ws;                             // 64*2000 f32 = 512000 B
    float* loss_ws = (float*)((char*)d_ws + 64 * T_MAXN * 4);  // +256 B

    hipLaunchKernelGGL(lse_kernel, dim3(512), dim3(256), 0, stream,
                       ap, in_lens, lse_ws);
    hipLaunchKernelGGL(ctc_scan_kernel, dim3(64), dim3(64), 0, stream,
                       ap, in_lens, out_lens, lse_ws, loss_ws);
    hipLaunchKernelGGL(mean_kernel, dim3(1), dim3(64), 0, stream, loss_ws, out);
}

// Round 4
// 267.032 us; speedup vs baseline: 4.1727x; 1.4673x over previous
//
#include <hip/hip_runtime.h>
#include <cmath>

// CTC alignment loss (RAD-TTS style), B=64, T<=2000, K<=400, S=2K+1<=801.
//
// Round-3 profile: scan = 327us of 392us, 393 cyc/step, VALUBusy 2.7% ->
// memory-LATENCY-bound (4-deep prefetch * step_time ~ HBM latency).
// Round-4 redesign (fast path, needs ~103MB ws; falls back to round-3 kernels):
//   prep_kernel: one pass over the 205MB input; per row computes masked
//     logsumexp -> lse_ws AND writes g[t][k] = exp(ap+1) (0 for k>=L) as fp16.
//     (alpha is analytically divided by prod(blank_prob): even factor == 1,
//      odd factor == g; correction  sum_t(-1-lse_t)  added at readout.)
//   ctc_scan_fp16_kernel: ONE WAVE per sample, 16 states/lane in registers,
//     zero barriers, 16-row-deep register prefetch (covers ~1200 cyc latency),
//     no transcendentals in the loop; power-of-2 rescale every 8 steps.
//   mean_kernel: deterministic mean of 64 losses.

#define T_MAXN 2000
#define K_MAXN 400

typedef _Float16 half8 __attribute__((ext_vector_type(8)));

// ---------------------------------------------------------- fast path: prep
__global__ __launch_bounds__(256)
void prep_kernel(const float* __restrict__ ap_all,
                 const int* __restrict__ in_lens,
                 const int* __restrict__ out_lens,
                 float* __restrict__ lse_out,
                 _Float16* __restrict__ g_out,
                 float* __restrict__ zerobuf)
{
    const int b    = blockIdx.y;
    const int L    = in_lens[b];
    const int Tn   = out_lens[b];
    const int lane = threadIdx.x & 63;
    const int wid  = blockIdx.x * (blockDim.x >> 6) + (threadIdx.x >> 6);
    const int nw   = gridDim.x * (blockDim.x >> 6);

    if (b == 0 && wid == 0 && lane < 16) zerobuf[lane] = 0.0f;   // shared zero row

    const float* base = ap_all + (size_t)b * (T_MAXN * K_MAXN);
    _Float16*    gb   = g_out  + (size_t)b * (T_MAXN * K_MAXN);
    const int c0 = lane * 8;
    const int cb = (c0 < 392) ? c0 : 392;        // clamped (lanes >= 50 fully masked)

    for (int t = wid; t < Tn; t += nw) {
        const float4* p = reinterpret_cast<const float4*>(base + (size_t)t * K_MAXN + cb);
        float4 x0 = p[0], x1 = p[1];
        float v[8] = {x0.x, x0.y, x0.z, x0.w, x1.x, x1.y, x1.z, x1.w};
        float m = -1.0f;                          // blank logit
        #pragma unroll
        for (int j = 0; j < 8; ++j) {
            v[j] = (c0 + j < L) ? v[j] : -1e30f;
            m = fmaxf(m, v[j]);
        }
        #pragma unroll
        for (int off = 32; off; off >>= 1) m = fmaxf(m, __shfl_xor(m, off));
        float s = (lane == 0) ? __expf(-1.0f - m) : 0.0f;
        #pragma unroll
        for (int j = 0; j < 8; ++j) s += __expf(v[j] - m);
        #pragma unroll
        for (int off = 32; off; off >>= 1) s += __shfl_xor(s, off);
        if (lane == 0) lse_out[b * T_MAXN + t] = m + __logf(s);

        half8 h;
        #pragma unroll
        for (int j = 0; j < 8; ++j) h[j] = (_Float16)__expf(v[j] + 1.0f);  // masked -> exp(-1e30)=0
        if (c0 < K_MAXN)
            *reinterpret_cast<half8*>(gb + (size_t)t * K_MAXN + c0) = h;
    }
}

// ---------------------------------------------------------- fast path: scan
__global__ __launch_bounds__(64)
void ctc_scan_fp16_kernel(const _Float16* __restrict__ g_all,
                          const int* __restrict__ in_lens,
                          const int* __restrict__ out_lens,
                          const float* __restrict__ lse_all,
                          const float* __restrict__ zerobuf,
                          float* __restrict__ loss_out)
{
    __shared__ float afin[1024];

    const int b    = blockIdx.x;
    const int lane = threadIdx.x;
    const int L    = in_lens[b];      // [200,400]
    const int Tn   = out_lens[b];     // [1000,2000]
    const _Float16* gb  = g_all + (size_t)b * (T_MAXN * K_MAXN);
    const float*    lse = lse_all + b * T_MAXN;

    // lane l owns states [16l,16l+16); odd-state label cols = [8l, 8l+8) = 16B of g row.
    const char* gbase;
    size_t      gstride;
    if (lane < 50) { gbase = (const char*)(gb + lane * 8); gstride = K_MAXN * 2; }
    else           { gbase = (const char*)zerobuf;         gstride = 0;          }

    // prologue: sl = sum_{t<Tn} lse[t]
    float sl = 0.0f;
    for (int t = lane; t < Tn; t += 64) sl += lse[t];
    #pragma unroll
    for (int off = 32; off; off >>= 1) sl += __shfl_xor(sl, off);

    // init t=0 (scaled): alpha^[0]=1, alpha^[1]=g[0][0]
    float a0=0,a1=0,a2=0,a3=0,a4=0,a5=0,a6=0,a7=0;
    float a8=0,a9=0,a10=0,a11=0,a12=0,a13=0,a14=0,a15=0;
    if (lane == 0) { a0 = 1.0f; a1 = (float)gb[0]; }
    int E = 0;

    #define TCL(X) ((X) < Tn ? (X) : (Tn - 1))
    #define LOADG(Q, T) (Q) = *reinterpret_cast<const half8*>(gbase + (size_t)(T) * gstride)

    half8 q0,q1,q2,q3,q4,q5,q6,q7,q8,q9,q10,q11,q12,q13,q14,q15;
    LOADG(q0, 1);  LOADG(q1, 2);  LOADG(q2, 3);  LOADG(q3, 4);
    LOADG(q4, 5);  LOADG(q5, 6);  LOADG(q6, 7);  LOADG(q7, 8);
    LOADG(q8, 9);  LOADG(q9, 10); LOADG(q10,11); LOADG(q11,12);
    LOADG(q12,13); LOADG(q13,14); LOADG(q14,15); LOADG(q15,16);

    // even s=2j: new = old[2j]+old[2j-1];  odd s=2j+1: new = g*(old[2j+1]+old[2j]+old[2j-1])
    #define STEPF(Q) do { \
        float t1 = __shfl_up(a15, 1); \
        t1 = lane ? t1 : 0.0f; \
        const float f0 = (float)(Q)[0]; const float f1 = (float)(Q)[1]; \
        const float f2 = (float)(Q)[2]; const float f3 = (float)(Q)[3]; \
        const float f4 = (float)(Q)[4]; const float f5 = (float)(Q)[5]; \
        const float f6 = (float)(Q)[6]; const float f7 = (float)(Q)[7]; \
        const float e0 = a0 + t1,   e1 = a2 + a1,   e2 = a4 + a3,   e3 = a6 + a5; \
        const float e4 = a8 + a7,   e5 = a10 + a9,  e6 = a12 + a11, e7 = a14 + a13; \
        const float o0 = a1 + e0,   o1 = a3 + e1,   o2 = a5 + e2,   o3 = a7 + e3; \
        const float o4 = a9 + e4,   o5 = a11 + e5,  o6 = a13 + e6,  o7 = a15 + e7; \
        a0 = e0; a2 = e1; a4 = e2; a6 = e3; a8 = e4; a10 = e5; a12 = e6; a14 = e7; \
        a1 = f0*o0; a3 = f1*o1; a5 = f2*o2; a7 = f3*o3; \
        a9 = f4*o4; a11 = f5*o5; a13 = f6*o6; a15 = f7*o7; \
    } while (0)

    #define RESCF do { \
        float mx = fmaxf(fmaxf(fmaxf(fmaxf(a0,a1),fmaxf(a2,a3)),fmaxf(fmaxf(a4,a5),fmaxf(a6,a7))), \
                         fmaxf(fmaxf(fmaxf(a8,a9),fmaxf(a10,a11)),fmaxf(fmaxf(a12,a13),fmaxf(a14,a15)))); \
        _Pragma("unroll") \
        for (int off = 32; off; off >>= 1) mx = fmaxf(mx, __shfl_xor(mx, off)); \
        int e = (int)((__float_as_uint(mx) >> 23) & 0xFF) - 127; \
        if (e != 0) { \
            E += e; \
            a0 = ldexpf(a0,-e);  a1 = ldexpf(a1,-e);  a2 = ldexpf(a2,-e);  a3 = ldexpf(a3,-e); \
            a4 = ldexpf(a4,-e);  a5 = ldexpf(a5,-e);  a6 = ldexpf(a6,-e);  a7 = ldexpf(a7,-e); \
            a8 = ldexpf(a8,-e);  a9 = ldexpf(a9,-e);  a10= ldexpf(a10,-e); a11= ldexpf(a11,-e); \
            a12= ldexpf(a12,-e); a13= ldexpf(a13,-e); a14= ldexpf(a14,-e); a15= ldexpf(a15,-e); \
        } \
    } while (0)

    int t = 1;
    while (t + 15 < Tn) {
        STEPF(q0);  LOADG(q0,  TCL(t+16));
        STEPF(q1);  LOADG(q1,  TCL(t+17));
        STEPF(q2);  LOADG(q2,  TCL(t+18));
        STEPF(q3);  LOADG(q3,  TCL(t+19));
        STEPF(q4);  LOADG(q4,  TCL(t+20));
        STEPF(q5);  LOADG(q5,  TCL(t+21));
        STEPF(q6);  LOADG(q6,  TCL(t+22));
        STEPF(q7);  LOADG(q7,  TCL(t+23));
        RESCF;
        STEPF(q8);  LOADG(q8,  TCL(t+24));
        STEPF(q9);  LOADG(q9,  TCL(t+25));
        STEPF(q10); LOADG(q10, TCL(t+26));
        STEPF(q11); LOADG(q11, TCL(t+27));
        STEPF(q12); LOADG(q12, TCL(t+28));
        STEPF(q13); LOADG(q13, TCL(t+29));
        STEPF(q14); LOADG(q14, TCL(t+30));
        STEPF(q15); LOADG(q15, TCL(t+31));
        RESCF;
        t += 16;
    }
    {
        const int r = Tn - t;   // 0..15; q_i holds row t+i for t+i < Tn
        if (r > 0)  STEPF(q0);
        if (r > 1)  STEPF(q1);
        if (r > 2)  STEPF(q2);
        if (r > 3)  STEPF(q3);
        if (r > 4)  STEPF(q4);
        if (r > 5)  STEPF(q5);
        if (r > 6)  STEPF(q6);
        if (r > 7)  STEPF(q7);
        if (r > 8)  { RESCF; STEPF(q8); }
        if (r > 9)  STEPF(q9);
        if (r > 10) STEPF(q10);
        if (r > 11) STEPF(q11);
        if (r > 12) STEPF(q12);
        if (r > 13) STEPF(q13);
        if (r > 14) STEPF(q14);
    }

    afin[16*lane+0]=a0;   afin[16*lane+1]=a1;   afin[16*lane+2]=a2;   afin[16*lane+3]=a3;
    afin[16*lane+4]=a4;   afin[16*lane+5]=a5;   afin[16*lane+6]=a6;   afin[16*lane+7]=a7;
    afin[16*lane+8]=a8;   afin[16*lane+9]=a9;   afin[16*lane+10]=a10; afin[16*lane+11]=a11;
    afin[16*lane+12]=a12; afin[16*lane+13]=a13; afin[16*lane+14]=a14; afin[16*lane+15]=a15;
    __syncthreads();
    if (lane == 0) {
        float tot = afin[2*L] + afin[2*L-1];
        float lossb = 0.0f;
        if (tot > 0.0f) {
            double ll = log((double)tot)
                      + (double)E * 0.69314718055994530942
                      + (double)(-(double)Tn - (double)sl);
            lossb = (float)(-ll / (double)L);
        }
        loss_out[b] = lossb;
    }
    #undef STEPF
    #undef RESCF
    #undef LOADG
    #undef TCL
}

// ------------------------------------------------- fallback (round-3, proven)
__global__ __launch_bounds__(256)
void lse_kernel(const float* __restrict__ ap_all,
                const int* __restrict__ in_lens,
                float* __restrict__ lse_out)
{
    const int lane = threadIdx.x & 63;
    const int wglob = blockIdx.x * (blockDim.x >> 6) + (threadIdx.x >> 6);
    const int nwav = gridDim.x * (blockDim.x >> 6);
    const int nrows = 64 * T_MAXN;

    for (int row = wglob; row < nrows; row += nwav) {
        const int b = row / T_MAXN;
        const int L = in_lens[b];
        const float* rp = ap_all + (size_t)row * K_MAXN;
        const int c0 = lane * 8;
        const int cb = (c0 < 392) ? c0 : 392;
        const float4* p = reinterpret_cast<const float4*>(rp + cb);
        float4 x0 = p[0], x1 = p[1];
        float v[8] = {x0.x, x0.y, x0.z, x0.w, x1.x, x1.y, x1.z, x1.w};
        float m = -1.0f;
        #pragma unroll
        for (int j = 0; j < 8; ++j) {
            v[j] = (c0 + j < L) ? v[j] : -1e30f;
            m = fmaxf(m, v[j]);
        }
        #pragma unroll
        for (int off = 32; off; off >>= 1) m = fmaxf(m, __shfl_xor(m, off));
        float s = (lane == 0) ? __expf(-1.0f - m) : 0.0f;
        #pragma unroll
        for (int j = 0; j < 8; ++j) s += __expf(v[j] - m);
        #pragma unroll
        for (int off = 32; off; off >>= 1) s += __shfl_xor(s, off);
        if (lane == 0) lse_out[row] = m + __logf(s);
    }
}

__global__ __launch_bounds__(64)
void ctc_scan_kernel(const float* __restrict__ ap_all,
                     const int* __restrict__ in_lens,
                     const int* __restrict__ out_lens,
                     const float* __restrict__ lse_all,
                     float* __restrict__ loss_out)
{
    __shared__ float afin[1024];

    const int b    = blockIdx.x;
    const int lane = threadIdx.x;
    const int L    = in_lens[b];
    const int Tn   = out_lens[b];
    const float* ap  = ap_all + (size_t)b * (T_MAXN * K_MAXN);
    const float* lse = lse_all + b * T_MAXN;

    const float LOG2E = 1.4426950408889634f;
    const int c0 = lane * 8;
    const int cb = (c0 < 392) ? c0 : 392;
    const float* rbase = ap + cb;
    float fa0,fa1,fa2,fa3,fa4,fa5,fa6,fa7;
    float fb0,fb1,fb2,fb3,fb4,fb5,fb6,fb7;
    #define MASKC(J, FA, FB) do { bool ok = (c0 + (J)) < L; \
        FA = ok ? LOG2E : 0.0f; FB = ok ? LOG2E : -1000.0f; } while (0)
    MASKC(0,fa0,fb0); MASKC(1,fa1,fb1); MASKC(2,fa2,fb2); MASKC(3,fa3,fb3);
    MASKC(4,fa4,fb4); MASKC(5,fa5,fb5); MASKC(6,fa6,fb6); MASKC(7,fa7,fb7);
    #undef MASKC

    float4 p0a,p0b,p1a,p1b,p2a,p2b,p3a,p3b;
    #define LOADROW(PA, PB, T) do { \
        const float4* _p = reinterpret_cast<const float4*>(rbase + (size_t)(T) * K_MAXN); \
        PA = _p[0]; PB = _p[1]; } while (0)
    LOADROW(p0a,p0b,1); LOADROW(p1a,p1b,2); LOADROW(p2a,p2b,3); LOADROW(p3a,p3b,4);

    float sl = 0.0f;
    for (int t = lane; t < Tn; t += 64) sl += lse[t];
    #pragma unroll
    for (int off = 32; off; off >>= 1) sl += __shfl_xor(sl, off);

    float x00 = ap[0];
    float a0=0,a1=0,a2=0,a3=0,a4=0,a5=0,a6=0,a7=0;
    float a8=0,a9=0,a10=0,a11=0,a12=0,a13=0,a14=0,a15=0;
    if (lane == 0) {
        a0 = 1.0f;
        a1 = __builtin_amdgcn_exp2f(fmaf(x00, LOG2E, LOG2E));
    }
    int E = 0;

    #define STEP(A0, A1) do { \
        float t1 = __shfl_up(a15, 1); \
        t1 = lane ? t1 : 0.0f; \
        const float f0 = __builtin_amdgcn_exp2f(fmaf((A0).x, fa0, fb0)); \
        const float f1 = __builtin_amdgcn_exp2f(fmaf((A0).y, fa1, fb1)); \
        const float f2 = __builtin_amdgcn_exp2f(fmaf((A0).z, fa2, fb2)); \
        const float f3 = __builtin_amdgcn_exp2f(fmaf((A0).w, fa3, fb3)); \
        const float f4 = __builtin_amdgcn_exp2f(fmaf((A1).x, fa4, fb4)); \
        const float f5 = __builtin_amdgcn_exp2f(fmaf((A1).y, fa5, fb5)); \
        const float f6 = __builtin_amdgcn_exp2f(fmaf((A1).z, fa6, fb6)); \
        const float f7 = __builtin_amdgcn_exp2f(fmaf((A1).w, fa7, fb7)); \
        const float e0 = a0 + t1,   e1 = a2 + a1,   e2 = a4 + a3,   e3 = a6 + a5; \
        const float e4 = a8 + a7,   e5 = a10 + a9,  e6 = a12 + a11, e7 = a14 + a13; \
        const float o0 = a1 + e0,   o1 = a3 + e1,   o2 = a5 + e2,   o3 = a7 + e3; \
        const float o4 = a9 + e4,   o5 = a11 + e5,  o6 = a13 + e6,  o7 = a15 + e7; \
        a0 = e0; a2 = e1; a4 = e2; a6 = e3; a8 = e4; a10 = e5; a12 = e6; a14 = e7; \
        a1 = f0*o0; a3 = f1*o1; a5 = f2*o2; a7 = f3*o3; \
        a9 = f4*o4; a11 = f5*o5; a13 = f6*o6; a15 = f7*o7; \
    } while (0)

    #define RESCALE do { \
        float mx = fmaxf(fmaxf(fmaxf(fmaxf(a0,a1),fmaxf(a2,a3)),fmaxf(fmaxf(a4,a5),fmaxf(a6,a7))), \
                         fmaxf(fmaxf(fmaxf(a8,a9),fmaxf(a10,a11)),fmaxf(fmaxf(a12,a13),fmaxf(a14,a15)))); \
        _Pragma("unroll") \
        for (int off = 32; off; off >>= 1) mx = fmaxf(mx, __shfl_xor(mx, off)); \
        int e = (int)((__float_as_uint(mx) >> 23) & 0xFF) - 127; \
        if (e != 0) { \
            E += e; \
            a0 = ldexpf(a0,-e);  a1 = ldexpf(a1,-e);  a2 = ldexpf(a2,-e);  a3 = ldexpf(a3,-e); \
            a4 = ldexpf(a4,-e);  a5 = ldexpf(a5,-e);  a6 = ldexpf(a6,-e);  a7 = ldexpf(a7,-e); \
            a8 = ldexpf(a8,-e);  a9 = ldexpf(a9,-e);  a10= ldexpf(a10,-e); a11= ldexpf(a11,-e); \
            a12= ldexpf(a12,-e); a13= ldexpf(a13,-e); a14= ldexpf(a14,-e); a15= ldexpf(a15,-e); \
        } \
    } while (0)

    int t = 1;
    while (t + 3 < Tn) {
        int tl;
        STEP(p0a,p0b); tl = (t+4 < T_MAXN) ? t+4 : T_MAXN-1; LOADROW(p0a,p0b,tl);
        STEP(p1a,p1b); tl = (t+5 < T_MAXN) ? t+5 : T_MAXN-1; LOADROW(p1a,p1b,tl);
        STEP(p2a,p2b); tl = (t+6 < T_MAXN) ? t+6 : T_MAXN-1; LOADROW(p2a,p2b,tl);
        STEP(p3a,p3b); tl = (t+7 < T_MAXN) ? t+7 : T_MAXN-1; LOADROW(p3a,p3b,tl);
        if ((t & 7) == 5) RESCALE;
        t += 4;
    }
    if (t < Tn) { STEP(p0a,p0b); ++t; }
    if (t < Tn) { STEP(p1a,p1b); ++t; }
    if (t < Tn) { STEP(p2a,p2b); ++t; }

    afin[16*lane+0]=a0;  afin[16*lane+1]=a1;  afin[16*lane+2]=a2;  afin[16*lane+3]=a3;
    afin[16*lane+4]=a4;  afin[16*lane+5]=a5;  afin[16*lane+6]=a6;  afin[16*lane+7]=a7;
    afin[16*lane+8]=a8;  afin[16*lane+9]=a9;  afin[16*lane+10]=a10; afin[16*lane+11]=a11;
    afin[16*lane+12]=a12; afin[16*lane+13]=a13; afin[16*lane+14]=a14; afin[16*lane+15]=a15;
    __syncthreads();
    if (lane == 0) {
        float tot = afin[2*L] + afin[2*L-1];
        float lossb = 0.0f;
        if (tot > 0.0f) {
            double ll = log((double)tot)
                      + (double)E * 0.69314718055994530942
                      + (double)(-(double)Tn - (double)sl);
            lossb = (float)(-ll / (double)L);
        }
        loss_out[b] = lossb;
    }
    #undef STEP
    #undef RESCALE
    #undef LOADROW
}

// ---------------------------------------------------------------- mean
__global__ void mean_kernel(const float* __restrict__ loss, float* __restrict__ out)
{
    float v = loss[threadIdx.x];   // 64 threads
    #pragma unroll
    for (int off = 32; off; off >>= 1) v += __shfl_xor(v, off);
    if (threadIdx.x == 0) out[0] = v * (1.0f / 64.0f);
}

extern "C" void kernel_launch(void* const* d_in, const int* in_sizes, int n_in,
                              void* d_out, int out_size, void* d_ws, size_t ws_size,
                              hipStream_t stream)
{
    // setup_inputs order: attn (unused), in_lens, out_lens, attn_logprob
    const int*   in_lens  = (const int*)d_in[1];
    const int*   out_lens = (const int*)d_in[2];
    const float* ap       = (const float*)d_in[3];
    float*       out      = (float*)d_out;

    const size_t G_BYTES   = (size_t)64 * T_MAXN * K_MAXN * 2;  // 102,400,000
    const size_t LSE_OFF   = G_BYTES;
    const size_t LSE_BYTES = (size_t)64 * T_MAXN * 4;           // 512,000
    const size_t ZERO_OFF  = LSE_OFF + LSE_BYTES;               // 16B-aligned
    const size_t LOSS_OFF  = ZERO_OFF + 64;
    const size_t NEED      = LOSS_OFF + 64 * 4;

    if (ws_size >= NEED) {
        _Float16* g       = (_Float16*)d_ws;
        float*    lse_ws  = (float*)((char*)d_ws + LSE_OFF);
        float*    zb      = (float*)((char*)d_ws + ZERO_OFF);
        float*    loss_ws = (float*)((char*)d_ws + LOSS_OFF);
        hipLaunchKernelGGL(prep_kernel, dim3(32, 64), dim3(256), 0, stream,
                           ap, in_lens, out_lens, lse_ws, g, zb);
        hipLaunchKernelGGL(ctc_scan_fp16_kernel, dim3(64), dim3(64), 0, stream,
                           g, in_lens, out_lens, lse_ws, zb, loss_ws);
        hipLaunchKernelGGL(mean_kernel, dim3(1), dim3(64), 0, stream, loss_ws, out);
    } else {
        float* lse_ws  = (float*)d_ws;
        float* loss_ws = (float*)((char*)d_ws + (size_t)64 * T_MAXN * 4);
        hipLaunchKernelGGL(lse_kernel, dim3(512), dim3(256), 0, stream,
                           ap, in_lens, lse_ws);
        hipLaunchKernelGGL(ctc_scan_kernel, dim3(64), dim3(64), 0, stream,
                           ap, in_lens, out_lens, lse_ws, loss_ws);
        hipLaunchKernelGGL(mean_kernel, dim3(1), dim3(64), 0, stream, loss_ws, out);
    }
}

// Round 6
// 214.464 us; speedup vs baseline: 5.1955x; 1.2451x over previous
//
#include <hip/hip_runtime.h>
#include <cmath>

// CTC alignment loss (RAD-TTS style), B=64, T<=2000, K<=400, S=2K+1<=801.
//
// Round-4 profile: scan 230us (276 cyc/step), VALUBusy ~9% on active CUs ->
// still latency/dependency-bound. Round-5 scan changes:
//   * 24-deep register prefetch (q0..q23), 4 loads per v_add (imm-folded).
//   * rescale pipelined across the 8-step group (lane max @ph0, one shfl_xor
//     per step ph1..6, exact pow2 apply @ph7). Safe because the wave max is
//     monotone non-decreasing in the blank-normalized domain.
//   * __shfl_up(a15) issued one step ahead (ds_permute latency off the path).
//   * uniform base + 32-bit rolling offset addressing; no clamp (over-reads
//     stay inside ws); dead lanes read a 4KB zero block.

#define T_MAXN 2000
#define K_MAXN 400

typedef _Float16 half8 __attribute__((ext_vector_type(8)));

// ws layout (fast path)
#define G_BYTES   ((size_t)64 * T_MAXN * K_MAXN * 2)   // 102,400,000
#define LSE_OFF   G_BYTES
#define LSE_BYTES ((size_t)64 * T_MAXN * 4)            // 512,000
#define ZERO_OFF  (LSE_OFF + LSE_BYTES)                // 4KB zero block
#define LOSS_OFF  (ZERO_OFF + 4096)
#define WS_NEED   (LOSS_OFF + 64 * 4)

// ---------------------------------------------------------- fast path: prep
__global__ __launch_bounds__(256)
void prep_kernel(const float* __restrict__ ap_all,
                 const int* __restrict__ in_lens,
                 const int* __restrict__ out_lens,
                 float* __restrict__ lse_out,
                 _Float16* __restrict__ g_out,
                 float* __restrict__ zerobuf)
{
    const int b    = blockIdx.y;
    const int L    = in_lens[b];
    const int Tn   = out_lens[b];
    const int lane = threadIdx.x & 63;
    const int wid  = blockIdx.x * (blockDim.x >> 6) + (threadIdx.x >> 6);
    const int nw   = gridDim.x * (blockDim.x >> 6);

    if (b == 0 && wid == 0) {                     // 4KB zero block for dead lanes
        for (int i = lane; i < 1024; i += 64) zerobuf[i] = 0.0f;
    }

    const float* base = ap_all + (size_t)b * (T_MAXN * K_MAXN);
    _Float16*    gb   = g_out  + (size_t)b * (T_MAXN * K_MAXN);
    const int c0 = lane * 8;
    const int cb = (c0 < 392) ? c0 : 392;         // clamped (lanes >= 50 fully masked)

    for (int t = wid; t < Tn; t += nw) {
        const float4* p = reinterpret_cast<const float4*>(base + (size_t)t * K_MAXN + cb);
        float4 x0 = p[0], x1 = p[1];
        float v[8] = {x0.x, x0.y, x0.z, x0.w, x1.x, x1.y, x1.z, x1.w};
        float m = -1.0f;                          // blank logit
        #pragma unroll
        for (int j = 0; j < 8; ++j) {
            v[j] = (c0 + j < L) ? v[j] : -1e30f;
            m = fmaxf(m, v[j]);
        }
        #pragma unroll
        for (int off = 32; off; off >>= 1) m = fmaxf(m, __shfl_xor(m, off));
        float s = (lane == 0) ? __expf(-1.0f - m) : 0.0f;
        #pragma unroll
        for (int j = 0; j < 8; ++j) s += __expf(v[j] - m);
        #pragma unroll
        for (int off = 32; off; off >>= 1) s += __shfl_xor(s, off);
        if (lane == 0) lse_out[b * T_MAXN + t] = m + __logf(s);

        half8 h;
        #pragma unroll
        for (int j = 0; j < 8; ++j) h[j] = (_Float16)__expf(v[j] + 1.0f);  // masked -> 0
        if (c0 < K_MAXN)
            *reinterpret_cast<half8*>(gb + (size_t)t * K_MAXN + c0) = h;
    }
}

// ---------------------------------------------------------- fast path: scan
__global__ __launch_bounds__(64)
void ctc_scan24_kernel(const char* wsro,
                       const int* __restrict__ in_lens,
                       const int* __restrict__ out_lens,
                       float* loss_out)
{
    __shared__ float afin[1024];

    const int b    = blockIdx.x;
    const int lane = threadIdx.x;
    const int L    = in_lens[b];      // [200,400]
    const int Tn   = out_lens[b];     // [1000,2000]
    const uint32_t goff = (uint32_t)b * (uint32_t)(T_MAXN * K_MAXN * 2);
    const float* lse = (const float*)(wsro + LSE_OFF) + b * T_MAXN;

    // uniform base + 32-bit rolling offset; dead lanes park on the zero block
    uint32_t off, inc4;
    if (lane < 50) { off = goff + (uint32_t)lane * 16u + 800u; inc4 = 3200u; }
    else           { off = (uint32_t)ZERO_OFF;                  inc4 = 0u;    }

    // prologue: sl = sum_{t<Tn} lse[t]
    float sl = 0.0f;
    for (int t = lane; t < Tn; t += 64) sl += lse[t];
    #pragma unroll
    for (int o = 32; o; o >>= 1) sl += __shfl_xor(sl, o);

    // init t=0 (blank-normalized): alpha^[0]=1, alpha^[1]=g[0][0]
    float a0=0,a1=0,a2=0,a3=0,a4=0,a5=0,a6=0,a7=0;
    float a8=0,a9=0,a10=0,a11=0,a12=0,a13=0,a14=0,a15=0;
    if (lane == 0) {
        a0 = 1.0f;
        a1 = (float)*reinterpret_cast<const _Float16*>(wsro + goff);
    }
    int   E  = 0;
    float t1 = 0.0f;    // pipelined boundary: lane-1's a15 from previous step
    float rm = 0.0f;    // pipelined rescale max

    #define LOADG4(QA, QB, QC, QD) do { \
        QA = *reinterpret_cast<const half8*>(wsro + off); \
        QB = *reinterpret_cast<const half8*>(wsro + off + 800); \
        QC = *reinterpret_cast<const half8*>(wsro + off + 1600); \
        QD = *reinterpret_cast<const half8*>(wsro + off + 2400); \
        off += inc4; \
    } while (0)

    half8 q0,q1,q2,q3,q4,q5,q6,q7,q8,q9,q10,q11;
    half8 q12,q13,q14,q15,q16,q17,q18,q19,q20,q21,q22,q23;
    LOADG4(q0,q1,q2,q3);     LOADG4(q4,q5,q6,q7);     LOADG4(q8,q9,q10,q11);
    LOADG4(q12,q13,q14,q15); LOADG4(q16,q17,q18,q19); LOADG4(q20,q21,q22,q23);

    // even s=2j: new = old[2j]+old[2j-1];  odd: new = g*(old[2j+1]+new_even)
    #define STEPF(Q) do { \
        const float f0 = (float)(Q)[0], f1 = (float)(Q)[1], f2 = (float)(Q)[2], f3 = (float)(Q)[3]; \
        const float f4 = (float)(Q)[4], f5 = (float)(Q)[5], f6 = (float)(Q)[6], f7 = (float)(Q)[7]; \
        const float e0 = a0 + t1,  e1 = a2 + a1,   e2 = a4 + a3,   e3 = a6 + a5; \
        const float e4 = a8 + a7,  e5 = a10 + a9,  e6 = a12 + a11, e7 = a14 + a13; \
        const float o0 = a1 + e0,  o1 = a3 + e1,   o2 = a5 + e2,   o3 = a7 + e3; \
        const float o4 = a9 + e4,  o5 = a11 + e5,  o6 = a13 + e6,  o7 = a15 + e7; \
        a0 = e0; a2 = e1; a4 = e2; a6 = e3; a8 = e4; a10 = e5; a12 = e6; a14 = e7; \
        a1 = f0*o0; a3 = f1*o1; a5 = f2*o2; a7 = f3*o3; \
        a9 = f4*o4; a11 = f5*o5; a13 = f6*o6; a15 = f7*o7; \
        t1 = __shfl_up(a15, 1); \
        t1 = lane ? t1 : 0.0f; \
    } while (0)

    // pipelined rescale phases (wave max is monotone non-decreasing -> stale-safe)
    #define PH0 do { \
        float m01 = fmaxf(a0,a1),  m23 = fmaxf(a2,a3),   m45 = fmaxf(a4,a5),   m67 = fmaxf(a6,a7); \
        float m89 = fmaxf(a8,a9),  mab = fmaxf(a10,a11), mcd = fmaxf(a12,a13), mef = fmaxf(a14,a15); \
        float mA = fmaxf(m01,m23), mB = fmaxf(m45,m67),  mC = fmaxf(m89,mab),  mD = fmaxf(mcd,mef); \
        rm = fmaxf(fmaxf(mA,mB), fmaxf(mC,mD)); \
    } while (0)
    #define PHX(MASK) rm = fmaxf(rm, __shfl_xor(rm, MASK))
    #define PH7 do { \
        int e = (int)((__float_as_uint(rm) >> 23) & 0xFF) - 127; \
        E += e; \
        const float sc = __uint_as_float((uint32_t)(127 - e) << 23);  /* 2^-e exact */ \
        a0*=sc; a1*=sc; a2*=sc;  a3*=sc;  a4*=sc;  a5*=sc;  a6*=sc;  a7*=sc; \
        a8*=sc; a9*=sc; a10*=sc; a11*=sc; a12*=sc; a13*=sc; a14*=sc; a15*=sc; \
        t1 *= sc; \
    } while (0)
    #define RESCDEP do { \
        PH0; \
        rm = fmaxf(rm, __shfl_xor(rm, 1));  rm = fmaxf(rm, __shfl_xor(rm, 2)); \
        rm = fmaxf(rm, __shfl_xor(rm, 4));  rm = fmaxf(rm, __shfl_xor(rm, 8)); \
        rm = fmaxf(rm, __shfl_xor(rm, 16)); rm = fmaxf(rm, __shfl_xor(rm, 32)); \
        PH7; \
    } while (0)

    int t = 1;
    while (t + 23 < Tn) {
        STEPF(q0);  PH0;
        STEPF(q1);  PHX(1);
        STEPF(q2);  PHX(2);
        STEPF(q3);  PHX(4);  LOADG4(q0,q1,q2,q3);
        STEPF(q4);  PHX(8);
        STEPF(q5);  PHX(16);
        STEPF(q6);  PHX(32);
        STEPF(q7);  PH7;     LOADG4(q4,q5,q6,q7);
        STEPF(q8);  PH0;
        STEPF(q9);  PHX(1);
        STEPF(q10); PHX(2);
        STEPF(q11); PHX(4);  LOADG4(q8,q9,q10,q11);
        STEPF(q12); PHX(8);
        STEPF(q13); PHX(16);
        STEPF(q14); PHX(32);
        STEPF(q15); PH7;     LOADG4(q12,q13,q14,q15);
        STEPF(q16); PH0;
        STEPF(q17); PHX(1);
        STEPF(q18); PHX(2);
        STEPF(q19); PHX(4);  LOADG4(q16,q17,q18,q19);
        STEPF(q20); PHX(8);
        STEPF(q21); PHX(16);
        STEPF(q22); PHX(32);
        STEPF(q23); PH7;     LOADG4(q20,q21,q22,q23);
        t += 24;
    }
    {
        const int r = Tn - t;   // 0..23; q_i holds row t+i
        if (r > 0)  STEPF(q0);
        if (r > 1)  STEPF(q1);
        if (r > 2)  STEPF(q2);
        if (r > 3)  STEPF(q3);
        if (r > 4)  STEPF(q4);
        if (r > 5)  STEPF(q5);
        if (r > 6)  STEPF(q6);
        if (r > 7)  STEPF(q7);
        if (r > 8)  { RESCDEP; STEPF(q8); }
        if (r > 9)  STEPF(q9);
        if (r > 10) STEPF(q10);
        if (r > 11) STEPF(q11);
        if (r > 12) STEPF(q12);
        if (r > 13) STEPF(q13);
        if (r > 14) STEPF(q14);
        if (r > 15) STEPF(q15);
        if (r > 16) { RESCDEP; STEPF(q16); }
        if (r > 17) STEPF(q17);
        if (r > 18) STEPF(q18);
        if (r > 19) STEPF(q19);
        if (r > 20) STEPF(q20);
        if (r > 21) STEPF(q21);
        if (r > 22) STEPF(q22);
    }

    afin[16*lane+0]=a0;   afin[16*lane+1]=a1;   afin[16*lane+2]=a2;   afin[16*lane+3]=a3;
    afin[16*lane+4]=a4;   afin[16*lane+5]=a5;   afin[16*lane+6]=a6;   afin[16*lane+7]=a7;
    afin[16*lane+8]=a8;   afin[16*lane+9]=a9;   afin[16*lane+10]=a10; afin[16*lane+11]=a11;
    afin[16*lane+12]=a12; afin[16*lane+13]=a13; afin[16*lane+14]=a14; afin[16*lane+15]=a15;
    __syncthreads();
    if (lane == 0) {
        float tot = afin[2*L] + afin[2*L-1];
        float lossb = 0.0f;
        if (tot > 0.0f) {
            double ll = log((double)tot)
                      + (double)E * 0.69314718055994530942
                      + (double)(-(double)Tn - (double)sl);
            lossb = (float)(-ll / (double)L);
        }
        loss_out[b] = lossb;
    }
    #undef STEPF
    #undef PH0
    #undef PHX
    #undef PH7
    #undef RESCDEP
    #undef LOADG4
}

// ------------------------------------------------- fallback (round-3, proven)
__global__ __launch_bounds__(256)
void lse_kernel(const float* __restrict__ ap_all,
                const int* __restrict__ in_lens,
                float* __restrict__ lse_out)
{
    const int lane = threadIdx.x & 63;
    const int wglob = blockIdx.x * (blockDim.x >> 6) + (threadIdx.x >> 6);
    const int nwav = gridDim.x * (blockDim.x >> 6);
    const int nrows = 64 * T_MAXN;

    for (int row = wglob; row < nrows; row += nwav) {
        const int b = row / T_MAXN;
        const int L = in_lens[b];
        const float* rp = ap_all + (size_t)row * K_MAXN;
        const int c0 = lane * 8;
        const int cb = (c0 < 392) ? c0 : 392;
        const float4* p = reinterpret_cast<const float4*>(rp + cb);
        float4 x0 = p[0], x1 = p[1];
        float v[8] = {x0.x, x0.y, x0.z, x0.w, x1.x, x1.y, x1.z, x1.w};
        float m = -1.0f;
        #pragma unroll
        for (int j = 0; j < 8; ++j) {
            v[j] = (c0 + j < L) ? v[j] : -1e30f;
            m = fmaxf(m, v[j]);
        }
        #pragma unroll
        for (int off = 32; off; off >>= 1) m = fmaxf(m, __shfl_xor(m, off));
        float s = (lane == 0) ? __expf(-1.0f - m) : 0.0f;
        #pragma unroll
        for (int j = 0; j < 8; ++j) s += __expf(v[j] - m);
        #pragma unroll
        for (int off = 32; off; off >>= 1) s += __shfl_xor(s, off);
        if (lane == 0) lse_out[row] = m + __logf(s);
    }
}

__global__ __launch_bounds__(64)
void ctc_scan_kernel(const float* __restrict__ ap_all,
                     const int* __restrict__ in_lens,
                     const int* __restrict__ out_lens,
                     const float* __restrict__ lse_all,
                     float* __restrict__ loss_out)
{
    __shared__ float afin[1024];

    const int b    = blockIdx.x;
    const int lane = threadIdx.x;
    const int L    = in_lens[b];
    const int Tn   = out_lens[b];
    const float* ap  = ap_all + (size_t)b * (T_MAXN * K_MAXN);
    const float* lse = lse_all + b * T_MAXN;

    const float LOG2E = 1.4426950408889634f;
    const int c0 = lane * 8;
    const int cb = (c0 < 392) ? c0 : 392;
    const float* rbase = ap + cb;
    float fa0,fa1,fa2,fa3,fa4,fa5,fa6,fa7;
    float fb0,fb1,fb2,fb3,fb4,fb5,fb6,fb7;
    #define MASKC(J, FA, FB) do { bool ok = (c0 + (J)) < L; \
        FA = ok ? LOG2E : 0.0f; FB = ok ? LOG2E : -1000.0f; } while (0)
    MASKC(0,fa0,fb0); MASKC(1,fa1,fb1); MASKC(2,fa2,fb2); MASKC(3,fa3,fb3);
    MASKC(4,fa4,fb4); MASKC(5,fa5,fb5); MASKC(6,fa6,fb6); MASKC(7,fa7,fb7);
    #undef MASKC

    float4 p0a,p0b,p1a,p1b,p2a,p2b,p3a,p3b;
    #define LOADROW(PA, PB, T) do { \
        const float4* _p = reinterpret_cast<const float4*>(rbase + (size_t)(T) * K_MAXN); \
        PA = _p[0]; PB = _p[1]; } while (0)
    LOADROW(p0a,p0b,1); LOADROW(p1a,p1b,2); LOADROW(p2a,p2b,3); LOADROW(p3a,p3b,4);

    float sl = 0.0f;
    for (int t = lane; t < Tn; t += 64) sl += lse[t];
    #pragma unroll
    for (int off = 32; off; off >>= 1) sl += __shfl_xor(sl, off);

    float x00 = ap[0];
    float a0=0,a1=0,a2=0,a3=0,a4=0,a5=0,a6=0,a7=0;
    float a8=0,a9=0,a10=0,a11=0,a12=0,a13=0,a14=0,a15=0;
    if (lane == 0) {
        a0 = 1.0f;
        a1 = __builtin_amdgcn_exp2f(fmaf(x00, LOG2E, LOG2E));
    }
    int E = 0;

    #define STEP(A0, A1) do { \
        float t1 = __shfl_up(a15, 1); \
        t1 = lane ? t1 : 0.0f; \
        const float f0 = __builtin_amdgcn_exp2f(fmaf((A0).x, fa0, fb0)); \
        const float f1 = __builtin_amdgcn_exp2f(fmaf((A0).y, fa1, fb1)); \
        const float f2 = __builtin_amdgcn_exp2f(fmaf((A0).z, fa2, fb2)); \
        const float f3 = __builtin_amdgcn_exp2f(fmaf((A0).w, fa3, fb3)); \
        const float f4 = __builtin_amdgcn_exp2f(fmaf((A1).x, fa4, fb4)); \
        const float f5 = __builtin_amdgcn_exp2f(fmaf((A1).y, fa5, fb5)); \
        const float f6 = __builtin_amdgcn_exp2f(fmaf((A1).z, fa6, fb6)); \
        const float f7 = __builtin_amdgcn_exp2f(fmaf((A1).w, fa7, fb7)); \
        const float e0 = a0 + t1,   e1 = a2 + a1,   e2 = a4 + a3,   e3 = a6 + a5; \
        const float e4 = a8 + a7,   e5 = a10 + a9,  e6 = a12 + a11, e7 = a14 + a13; \
        const float o0 = a1 + e0,   o1 = a3 + e1,   o2 = a5 + e2,   o3 = a7 + e3; \
        const float o4 = a9 + e4,   o5 = a11 + e5,  o6 = a13 + e6,  o7 = a15 + e7; \
        a0 = e0; a2 = e1; a4 = e2; a6 = e3; a8 = e4; a10 = e5; a12 = e6; a14 = e7; \
        a1 = f0*o0; a3 = f1*o1; a5 = f2*o2; a7 = f3*o3; \
        a9 = f4*o4; a11 = f5*o5; a13 = f6*o6; a15 = f7*o7; \
    } while (0)

    #define RESCALE do { \
        float mx = fmaxf(fmaxf(fmaxf(fmaxf(a0,a1),fmaxf(a2,a3)),fmaxf(fmaxf(a4,a5),fmaxf(a6,a7))), \
                         fmaxf(fmaxf(fmaxf(a8,a9),fmaxf(a10,a11)),fmaxf(fmaxf(a12,a13),fmaxf(a14,a15)))); \
        _Pragma("unroll") \
        for (int off = 32; off; off >>= 1) mx = fmaxf(mx, __shfl_xor(mx, off)); \
        int e = (int)((__float_as_uint(mx) >> 23) & 0xFF) - 127; \
        if (e != 0) { \
            E += e; \
            a0 = ldexpf(a0,-e);  a1 = ldexpf(a1,-e);  a2 = ldexpf(a2,-e);  a3 = ldexpf(a3,-e); \
            a4 = ldexpf(a4,-e);  a5 = ldexpf(a5,-e);  a6 = ldexpf(a6,-e);  a7 = ldexpf(a7,-e); \
            a8 = ldexpf(a8,-e);  a9 = ldexpf(a9,-e);  a10= ldexpf(a10,-e); a11= ldexpf(a11,-e); \
            a12= ldexpf(a12,-e); a13= ldexpf(a13,-e); a14= ldexpf(a14,-e); a15= ldexpf(a15,-e); \
        } \
    } while (0)

    int t = 1;
    while (t + 3 < Tn) {
        int tl;
        STEP(p0a,p0b); tl = (t+4 < T_MAXN) ? t+4 : T_MAXN-1; LOADROW(p0a,p0b,tl);
        STEP(p1a,p1b); tl = (t+5 < T_MAXN) ? t+5 : T_MAXN-1; LOADROW(p1a,p1b,tl);
        STEP(p2a,p2b); tl = (t+6 < T_MAXN) ? t+6 : T_MAXN-1; LOADROW(p2a,p2b,tl);
        STEP(p3a,p3b); tl = (t+7 < T_MAXN) ? t+7 : T_MAXN-1; LOADROW(p3a,p3b,tl);
        if ((t & 7) == 5) RESCALE;
        t += 4;
    }
    if (t < Tn) { STEP(p0a,p0b); ++t; }
    if (t < Tn) { STEP(p1a,p1b); ++t; }
    if (t < Tn) { STEP(p2a,p2b); ++t; }

    afin[16*lane+0]=a0;  afin[16*lane+1]=a1;  afin[16*lane+2]=a2;  afin[16*lane+3]=a3;
    afin[16*lane+4]=a4;  afin[16*lane+5]=a5;  afin[16*lane+6]=a6;  afin[16*lane+7]=a7;
    afin[16*lane+8]=a8;  afin[16*lane+9]=a9;  afin[16*lane+10]=a10; afin[16*lane+11]=a11;
    afin[16*lane+12]=a12; afin[16*lane+13]=a13; afin[16*lane+14]=a14; afin[16*lane+15]=a15;
    __syncthreads();
    if (lane == 0) {
        float tot = afin[2*L] + afin[2*L-1];
        float lossb = 0.0f;
        if (tot > 0.0f) {
            double ll = log((double)tot)
                      + (double)E * 0.69314718055994530942
                      + (double)(-(double)Tn - (double)sl);
            lossb = (float)(-ll / (double)L);
        }
        loss_out[b] = lossb;
    }
    #undef STEP
    #undef RESCALE
    #undef LOADROW
}

// ---------------------------------------------------------------- mean
__global__ void mean_kernel(const float* __restrict__ loss, float* __restrict__ out)
{
    float v = loss[threadIdx.x];   // 64 threads
    #pragma unroll
    for (int off = 32; off; off >>= 1) v += __shfl_xor(v, off);
    if (threadIdx.x == 0) out[0] = v * (1.0f / 64.0f);
}

extern "C" void kernel_launch(void* const* d_in, const int* in_sizes, int n_in,
                              void* d_out, int out_size, void* d_ws, size_t ws_size,
                              hipStream_t stream)
{
    // setup_inputs order: attn (unused), in_lens, out_lens, attn_logprob
    const int*   in_lens  = (const int*)d_in[1];
    const int*   out_lens = (const int*)d_in[2];
    const float* ap       = (const float*)d_in[3];
    float*       out      = (float*)d_out;

    if (ws_size >= WS_NEED) {
        char*     wsb     = (char*)d_ws;
        _Float16* g       = (_Float16*)wsb;
        float*    lse_ws  = (float*)(wsb + LSE_OFF);
        float*    zb      = (float*)(wsb + ZERO_OFF);
        float*    loss_ws = (float*)(wsb + LOSS_OFF);
        hipLaunchKernelGGL(prep_kernel, dim3(32, 64), dim3(256), 0, stream,
                           ap, in_lens, out_lens, lse_ws, g, zb);
        hipLaunchKernelGGL(ctc_scan24_kernel, dim3(64), dim3(64), 0, stream,
                           (const char*)wsb, in_lens, out_lens, loss_ws);
        hipLaunchKernelGGL(mean_kernel, dim3(1), dim3(64), 0, stream, loss_ws, out);
    } else {
        float* lse_ws  = (float*)d_ws;
        float* loss_ws = (float*)((char*)d_ws + (size_t)64 * T_MAXN * 4);
        hipLaunchKernelGGL(lse_kernel, dim3(512), dim3(256), 0, stream,
                           ap, in_lens, lse_ws);
        hipLaunchKernelGGL(ctc_scan_kernel, dim3(64), dim3(64), 0, stream,
                           ap, in_lens, out_lens, lse_ws, loss_ws);
        hipLaunchKernelGGL(mean_kernel, dim3(1), dim3(64), 0, stream, loss_ws, out);
    }
}

// Round 7
// 212.476 us; speedup vs baseline: 5.2441x; 1.0094x over previous
//
#include <hip/hip_runtime.h>
#include <cmath>

// CTC alignment loss (RAD-TTS style), B=64, T<=2000, K<=400, S=2K+1<=801.
//
// Round-6 profile: scan 178us (214 cyc/step). ~70 cyc VALU issue + ~140 cyc
// stall; the only slack-free DS op is the per-step __shfl_up(a15,1) (issued at
// step end, consumed at next step start -> ~100cy ds_permute latency exposed).
// Round-7 change: boundary transfer via DPP wave_shr1 (0x138) — one VALU mov,
// bound_ctrl zero-fills lane 0. No other changes.

#define T_MAXN 2000
#define K_MAXN 400

typedef _Float16 half8 __attribute__((ext_vector_type(8)));

// ws layout (fast path)
#define G_BYTES   ((size_t)64 * T_MAXN * K_MAXN * 2)   // 102,400,000
#define LSE_OFF   G_BYTES
#define LSE_BYTES ((size_t)64 * T_MAXN * 4)            // 512,000
#define ZERO_OFF  (LSE_OFF + LSE_BYTES)                // 4KB zero block
#define LOSS_OFF  (ZERO_OFF + 4096)
#define WS_NEED   (LOSS_OFF + 64 * 4)

// lane-1's value (shift wave right by 1), lane 0 -> 0.0f; single VALU op
__device__ __forceinline__ float dpp_wave_shr1(float x)
{
    int r = __builtin_amdgcn_update_dpp(0, (int)__float_as_uint(x),
                                        0x138 /*wave_shr:1*/, 0xF, 0xF, true);
    return __uint_as_float((uint32_t)r);
}

// ---------------------------------------------------------- fast path: prep
__global__ __launch_bounds__(256)
void prep_kernel(const float* __restrict__ ap_all,
                 const int* __restrict__ in_lens,
                 const int* __restrict__ out_lens,
                 float* __restrict__ lse_out,
                 _Float16* __restrict__ g_out,
                 float* __restrict__ zerobuf)
{
    const int b    = blockIdx.y;
    const int L    = in_lens[b];
    const int Tn   = out_lens[b];
    const int lane = threadIdx.x & 63;
    const int wid  = blockIdx.x * (blockDim.x >> 6) + (threadIdx.x >> 6);
    const int nw   = gridDim.x * (blockDim.x >> 6);

    if (b == 0 && wid == 0) {                     // 4KB zero block for dead lanes
        for (int i = lane; i < 1024; i += 64) zerobuf[i] = 0.0f;
    }

    const float* base = ap_all + (size_t)b * (T_MAXN * K_MAXN);
    _Float16*    gb   = g_out  + (size_t)b * (T_MAXN * K_MAXN);
    const int c0 = lane * 8;
    const int cb = (c0 < 392) ? c0 : 392;         // clamped (lanes >= 50 fully masked)

    for (int t = wid; t < Tn; t += nw) {
        const float4* p = reinterpret_cast<const float4*>(base + (size_t)t * K_MAXN + cb);
        float4 x0 = p[0], x1 = p[1];
        float v[8] = {x0.x, x0.y, x0.z, x0.w, x1.x, x1.y, x1.z, x1.w};
        float m = -1.0f;                          // blank logit
        #pragma unroll
        for (int j = 0; j < 8; ++j) {
            v[j] = (c0 + j < L) ? v[j] : -1e30f;
            m = fmaxf(m, v[j]);
        }
        #pragma unroll
        for (int off = 32; off; off >>= 1) m = fmaxf(m, __shfl_xor(m, off));
        float s = (lane == 0) ? __expf(-1.0f - m) : 0.0f;
        #pragma unroll
        for (int j = 0; j < 8; ++j) s += __expf(v[j] - m);
        #pragma unroll
        for (int off = 32; off; off >>= 1) s += __shfl_xor(s, off);
        if (lane == 0) lse_out[b * T_MAXN + t] = m + __logf(s);

        half8 h;
        #pragma unroll
        for (int j = 0; j < 8; ++j) h[j] = (_Float16)__expf(v[j] + 1.0f);  // masked -> 0
        if (c0 < K_MAXN)
            *reinterpret_cast<half8*>(gb + (size_t)t * K_MAXN + c0) = h;
    }
}

// ---------------------------------------------------------- fast path: scan
__global__ __launch_bounds__(64)
void ctc_scan24_kernel(const char* wsro,
                       const int* __restrict__ in_lens,
                       const int* __restrict__ out_lens,
                       float* loss_out)
{
    __shared__ float afin[1024];

    const int b    = blockIdx.x;
    const int lane = threadIdx.x;
    const int L    = in_lens[b];      // [200,400]
    const int Tn   = out_lens[b];     // [1000,2000]
    const uint32_t goff = (uint32_t)b * (uint32_t)(T_MAXN * K_MAXN * 2);
    const float* lse = (const float*)(wsro + LSE_OFF) + b * T_MAXN;

    // uniform base + 32-bit rolling offset; dead lanes park on the zero block
    uint32_t off, inc4;
    if (lane < 50) { off = goff + (uint32_t)lane * 16u + 800u; inc4 = 3200u; }
    else           { off = (uint32_t)ZERO_OFF;                  inc4 = 0u;    }

    // prologue: sl = sum_{t<Tn} lse[t]
    float sl = 0.0f;
    for (int t = lane; t < Tn; t += 64) sl += lse[t];
    #pragma unroll
    for (int o = 32; o; o >>= 1) sl += __shfl_xor(sl, o);

    // init t=0 (blank-normalized): alpha^[0]=1, alpha^[1]=g[0][0]
    float a0=0,a1=0,a2=0,a3=0,a4=0,a5=0,a6=0,a7=0;
    float a8=0,a9=0,a10=0,a11=0,a12=0,a13=0,a14=0,a15=0;
    if (lane == 0) {
        a0 = 1.0f;
        a1 = (float)*reinterpret_cast<const _Float16*>(wsro + goff);
    }
    int   E  = 0;
    float t1 = 0.0f;    // boundary: lane-1's a15 from previous step (via DPP)
    float rm = 0.0f;    // pipelined rescale max

    #define LOADG4(QA, QB, QC, QD) do { \
        QA = *reinterpret_cast<const half8*>(wsro + off); \
        QB = *reinterpret_cast<const half8*>(wsro + off + 800); \
        QC = *reinterpret_cast<const half8*>(wsro + off + 1600); \
        QD = *reinterpret_cast<const half8*>(wsro + off + 2400); \
        off += inc4; \
    } while (0)

    half8 q0,q1,q2,q3,q4,q5,q6,q7,q8,q9,q10,q11;
    half8 q12,q13,q14,q15,q16,q17,q18,q19,q20,q21,q22,q23;
    LOADG4(q0,q1,q2,q3);     LOADG4(q4,q5,q6,q7);     LOADG4(q8,q9,q10,q11);
    LOADG4(q12,q13,q14,q15); LOADG4(q16,q17,q18,q19); LOADG4(q20,q21,q22,q23);

    // even s=2j: new = old[2j]+old[2j-1];  odd: new = g*(old[2j+1]+new_even)
    #define STEPF(Q) do { \
        const float f0 = (float)(Q)[0], f1 = (float)(Q)[1], f2 = (float)(Q)[2], f3 = (float)(Q)[3]; \
        const float f4 = (float)(Q)[4], f5 = (float)(Q)[5], f6 = (float)(Q)[6], f7 = (float)(Q)[7]; \
        const float e0 = a0 + t1,  e1 = a2 + a1,   e2 = a4 + a3,   e3 = a6 + a5; \
        const float e4 = a8 + a7,  e5 = a10 + a9,  e6 = a12 + a11, e7 = a14 + a13; \
        const float o0 = a1 + e0,  o1 = a3 + e1,   o2 = a5 + e2,   o3 = a7 + e3; \
        const float o4 = a9 + e4,  o5 = a11 + e5,  o6 = a13 + e6,  o7 = a15 + e7; \
        a0 = e0; a2 = e1; a4 = e2; a6 = e3; a8 = e4; a10 = e5; a12 = e6; a14 = e7; \
        a1 = f0*o0; a3 = f1*o1; a5 = f2*o2; a7 = f3*o3; \
        a9 = f4*o4; a11 = f5*o5; a13 = f6*o6; a15 = f7*o7; \
        t1 = dpp_wave_shr1(a15); \
    } while (0)

    // pipelined rescale phases (wave max is monotone non-decreasing -> stale-safe)
    #define PH0 do { \
        float m01 = fmaxf(a0,a1),  m23 = fmaxf(a2,a3),   m45 = fmaxf(a4,a5),   m67 = fmaxf(a6,a7); \
        float m89 = fmaxf(a8,a9),  mab = fmaxf(a10,a11), mcd = fmaxf(a12,a13), mef = fmaxf(a14,a15); \
        float mA = fmaxf(m01,m23), mB = fmaxf(m45,m67),  mC = fmaxf(m89,mab),  mD = fmaxf(mcd,mef); \
        rm = fmaxf(fmaxf(mA,mB), fmaxf(mC,mD)); \
    } while (0)
    #define PHX(MASK) rm = fmaxf(rm, __shfl_xor(rm, MASK))
    #define PH7 do { \
        int e = (int)((__float_as_uint(rm) >> 23) & 0xFF) - 127; \
        E += e; \
        const float sc = __uint_as_float((uint32_t)(127 - e) << 23);  /* 2^-e exact */ \
        a0*=sc; a1*=sc; a2*=sc;  a3*=sc;  a4*=sc;  a5*=sc;  a6*=sc;  a7*=sc; \
        a8*=sc; a9*=sc; a10*=sc; a11*=sc; a12*=sc; a13*=sc; a14*=sc; a15*=sc; \
        t1 *= sc; \
    } while (0)
    #define RESCDEP do { \
        PH0; \
        rm = fmaxf(rm, __shfl_xor(rm, 1));  rm = fmaxf(rm, __shfl_xor(rm, 2)); \
        rm = fmaxf(rm, __shfl_xor(rm, 4));  rm = fmaxf(rm, __shfl_xor(rm, 8)); \
        rm = fmaxf(rm, __shfl_xor(rm, 16)); rm = fmaxf(rm, __shfl_xor(rm, 32)); \
        PH7; \
    } while (0)

    int t = 1;
    while (t + 23 < Tn) {
        STEPF(q0);  PH0;
        STEPF(q1);  PHX(1);
        STEPF(q2);  PHX(2);
        STEPF(q3);  PHX(4);  LOADG4(q0,q1,q2,q3);
        STEPF(q4);  PHX(8);
        STEPF(q5);  PHX(16);
        STEPF(q6);  PHX(32);
        STEPF(q7);  PH7;     LOADG4(q4,q5,q6,q7);
        STEPF(q8);  PH0;
        STEPF(q9);  PHX(1);
        STEPF(q10); PHX(2);
        STEPF(q11); PHX(4);  LOADG4(q8,q9,q10,q11);
        STEPF(q12); PHX(8);
        STEPF(q13); PHX(16);
        STEPF(q14); PHX(32);
        STEPF(q15); PH7;     LOADG4(q12,q13,q14,q15);
        STEPF(q16); PH0;
        STEPF(q17); PHX(1);
        STEPF(q18); PHX(2);
        STEPF(q19); PHX(4);  LOADG4(q16,q17,q18,q19);
        STEPF(q20); PHX(8);
        STEPF(q21); PHX(16);
        STEPF(q22); PHX(32);
        STEPF(q23); PH7;     LOADG4(q20,q21,q22,q23);
        t += 24;
    }
    {
        const int r = Tn - t;   // 0..23; q_i holds row t+i
        if (r > 0)  STEPF(q0);
        if (r > 1)  STEPF(q1);
        if (r > 2)  STEPF(q2);
        if (r > 3)  STEPF(q3);
        if (r > 4)  STEPF(q4);
        if (r > 5)  STEPF(q5);
        if (r > 6)  STEPF(q6);
        if (r > 7)  STEPF(q7);
        if (r > 8)  { RESCDEP; STEPF(q8); }
        if (r > 9)  STEPF(q9);
        if (r > 10) STEPF(q10);
        if (r > 11) STEPF(q11);
        if (r > 12) STEPF(q12);
        if (r > 13) STEPF(q13);
        if (r > 14) STEPF(q14);
        if (r > 15) STEPF(q15);
        if (r > 16) { RESCDEP; STEPF(q16); }
        if (r > 17) STEPF(q17);
        if (r > 18) STEPF(q18);
        if (r > 19) STEPF(q19);
        if (r > 20) STEPF(q20);
        if (r > 21) STEPF(q21);
        if (r > 22) STEPF(q22);
    }

    afin[16*lane+0]=a0;   afin[16*lane+1]=a1;   afin[16*lane+2]=a2;   afin[16*lane+3]=a3;
    afin[16*lane+4]=a4;   afin[16*lane+5]=a5;   afin[16*lane+6]=a6;   afin[16*lane+7]=a7;
    afin[16*lane+8]=a8;   afin[16*lane+9]=a9;   afin[16*lane+10]=a10; afin[16*lane+11]=a11;
    afin[16*lane+12]=a12; afin[16*lane+13]=a13; afin[16*lane+14]=a14; afin[16*lane+15]=a15;
    __syncthreads();
    if (lane == 0) {
        float tot = afin[2*L] + afin[2*L-1];
        float lossb = 0.0f;
        if (tot > 0.0f) {
            double ll = log((double)tot)
                      + (double)E * 0.69314718055994530942
                      + (double)(-(double)Tn - (double)sl);
            lossb = (float)(-ll / (double)L);
        }
        loss_out[b] = lossb;
    }
    #undef STEPF
    #undef PH0
    #undef PHX
    #undef PH7
    #undef RESCDEP
    #undef LOADG4
}

// ------------------------------------------------- fallback (round-3, proven)
__global__ __launch_bounds__(256)
void lse_kernel(const float* __restrict__ ap_all,
                const int* __restrict__ in_lens,
                float* __restrict__ lse_out)
{
    const int lane = threadIdx.x & 63;
    const int wglob = blockIdx.x * (blockDim.x >> 6) + (threadIdx.x >> 6);
    const int nwav = gridDim.x * (blockDim.x >> 6);
    const int nrows = 64 * T_MAXN;

    for (int row = wglob; row < nrows; row += nwav) {
        const int b = row / T_MAXN;
        const int L = in_lens[b];
        const float* rp = ap_all + (size_t)row * K_MAXN;
        const int c0 = lane * 8;
        const int cb = (c0 < 392) ? c0 : 392;
        const float4* p = reinterpret_cast<const float4*>(rp + cb);
        float4 x0 = p[0], x1 = p[1];
        float v[8] = {x0.x, x0.y, x0.z, x0.w, x1.x, x1.y, x1.z, x1.w};
        float m = -1.0f;
        #pragma unroll
        for (int j = 0; j < 8; ++j) {
            v[j] = (c0 + j < L) ? v[j] : -1e30f;
            m = fmaxf(m, v[j]);
        }
        #pragma unroll
        for (int off = 32; off; off >>= 1) m = fmaxf(m, __shfl_xor(m, off));
        float s = (lane == 0) ? __expf(-1.0f - m) : 0.0f;
        #pragma unroll
        for (int j = 0; j < 8; ++j) s += __expf(v[j] - m);
        #pragma unroll
        for (int off = 32; off; off >>= 1) s += __shfl_xor(s, off);
        if (lane == 0) lse_out[row] = m + __logf(s);
    }
}

__global__ __launch_bounds__(64)
void ctc_scan_kernel(const float* __restrict__ ap_all,
                     const int* __restrict__ in_lens,
                     const int* __restrict__ out_lens,
                     const float* __restrict__ lse_all,
                     float* __restrict__ loss_out)
{
    __shared__ float afin[1024];

    const int b    = blockIdx.x;
    const int lane = threadIdx.x;
    const int L    = in_lens[b];
    const int Tn   = out_lens[b];
    const float* ap  = ap_all + (size_t)b * (T_MAXN * K_MAXN);
    const float* lse = lse_all + b * T_MAXN;

    const float LOG2E = 1.4426950408889634f;
    const int c0 = lane * 8;
    const int cb = (c0 < 392) ? c0 : 392;
    const float* rbase = ap + cb;
    float fa0,fa1,fa2,fa3,fa4,fa5,fa6,fa7;
    float fb0,fb1,fb2,fb3,fb4,fb5,fb6,fb7;
    #define MASKC(J, FA, FB) do { bool ok = (c0 + (J)) < L; \
        FA = ok ? LOG2E : 0.0f; FB = ok ? LOG2E : -1000.0f; } while (0)
    MASKC(0,fa0,fb0); MASKC(1,fa1,fb1); MASKC(2,fa2,fb2); MASKC(3,fa3,fb3);
    MASKC(4,fa4,fb4); MASKC(5,fa5,fb5); MASKC(6,fa6,fb6); MASKC(7,fa7,fb7);
    #undef MASKC

    float4 p0a,p0b,p1a,p1b,p2a,p2b,p3a,p3b;
    #define LOADROW(PA, PB, T) do { \
        const float4* _p = reinterpret_cast<const float4*>(rbase + (size_t)(T) * K_MAXN); \
        PA = _p[0]; PB = _p[1]; } while (0)
    LOADROW(p0a,p0b,1); LOADROW(p1a,p1b,2); LOADROW(p2a,p2b,3); LOADROW(p3a,p3b,4);

    float sl = 0.0f;
    for (int t = lane; t < Tn; t += 64) sl += lse[t];
    #pragma unroll
    for (int off = 32; off; off >>= 1) sl += __shfl_xor(sl, off);

    float x00 = ap[0];
    float a0=0,a1=0,a2=0,a3=0,a4=0,a5=0,a6=0,a7=0;
    float a8=0,a9=0,a10=0,a11=0,a12=0,a13=0,a14=0,a15=0;
    if (lane == 0) {
        a0 = 1.0f;
        a1 = __builtin_amdgcn_exp2f(fmaf(x00, LOG2E, LOG2E));
    }
    int E = 0;

    #define STEP(A0, A1) do { \
        float t1 = __shfl_up(a15, 1); \
        t1 = lane ? t1 : 0.0f; \
        const float f0 = __builtin_amdgcn_exp2f(fmaf((A0).x, fa0, fb0)); \
        const float f1 = __builtin_amdgcn_exp2f(fmaf((A0).y, fa1, fb1)); \
        const float f2 = __builtin_amdgcn_exp2f(fmaf((A0).z, fa2, fb2)); \
        const float f3 = __builtin_amdgcn_exp2f(fmaf((A0).w, fa3, fb3)); \
        const float f4 = __builtin_amdgcn_exp2f(fmaf((A1).x, fa4, fb4)); \
        const float f5 = __builtin_amdgcn_exp2f(fmaf((A1).y, fa5, fb5)); \
        const float f6 = __builtin_amdgcn_exp2f(fmaf((A1).z, fa6, fb6)); \
        const float f7 = __builtin_amdgcn_exp2f(fmaf((A1).w, fa7, fb7)); \
        const float e0 = a0 + t1,   e1 = a2 + a1,   e2 = a4 + a3,   e3 = a6 + a5; \
        const float e4 = a8 + a7,   e5 = a10 + a9,  e6 = a12 + a11, e7 = a14 + a13; \
        const float o0 = a1 + e0,   o1 = a3 + e1,   o2 = a5 + e2,   o3 = a7 + e3; \
        const float o4 = a9 + e4,   o5 = a11 + e5,  o6 = a13 + e6,  o7 = a15 + e7; \
        a0 = e0; a2 = e1; a4 = e2; a6 = e3; a8 = e4; a10 = e5; a12 = e6; a14 = e7; \
        a1 = f0*o0; a3 = f1*o1; a5 = f2*o2; a7 = f3*o3; \
        a9 = f4*o4; a11 = f5*o5; a13 = f6*o6; a15 = f7*o7; \
    } while (0)

    #define RESCALE do { \
        float mx = fmaxf(fmaxf(fmaxf(fmaxf(a0,a1),fmaxf(a2,a3)),fmaxf(fmaxf(a4,a5),fmaxf(a6,a7))), \
                         fmaxf(fmaxf(fmaxf(a8,a9),fmaxf(a10,a11)),fmaxf(fmaxf(a12,a13),fmaxf(a14,a15)))); \
        _Pragma("unroll") \
        for (int off = 32; off; off >>= 1) mx = fmaxf(mx, __shfl_xor(mx, off)); \
        int e = (int)((__float_as_uint(mx) >> 23) & 0xFF) - 127; \
        if (e != 0) { \
            E += e; \
            a0 = ldexpf(a0,-e);  a1 = ldexpf(a1,-e);  a2 = ldexpf(a2,-e);  a3 = ldexpf(a3,-e); \
            a4 = ldexpf(a4,-e);  a5 = ldexpf(a5,-e);  a6 = ldexpf(a6,-e);  a7 = ldexpf(a7,-e); \
            a8 = ldexpf(a8,-e);  a9 = ldexpf(a9,-e);  a10= ldexpf(a10,-e); a11= ldexpf(a11,-e); \
            a12= ldexpf(a12,-e); a13= ldexpf(a13,-e); a14= ldexpf(a14,-e); a15= ldexpf(a15,-e); \
        } \
    } while (0)

    int t = 1;
    while (t + 3 < Tn) {
        int tl;
        STEP(p0a,p0b); tl = (t+4 < T_MAXN) ? t+4 : T_MAXN-1; LOADROW(p0a,p0b,tl);
        STEP(p1a,p1b); tl = (t+5 < T_MAXN) ? t+5 : T_MAXN-1; LOADROW(p1a,p1b,tl);
        STEP(p2a,p2b); tl = (t+6 < T_MAXN) ? t+6 : T_MAXN-1; LOADROW(p2a,p2b,tl);
        STEP(p3a,p3b); tl = (t+7 < T_MAXN) ? t+7 : T_MAXN-1; LOADROW(p3a,p3b,tl);
        if ((t & 7) == 5) RESCALE;
        t += 4;
    }
    if (t < Tn) { STEP(p0a,p0b); ++t; }
    if (t < Tn) { STEP(p1a,p1b); ++t; }
    if (t < Tn) { STEP(p2a,p2b); ++t; }

    afin[16*lane+0]=a0;  afin[16*lane+1]=a1;  afin[16*lane+2]=a2;  afin[16*lane+3]=a3;
    afin[16*lane+4]=a4;  afin[16*lane+5]=a5;  afin[16*lane+6]=a6;  afin[16*lane+7]=a7;
    afin[16*lane+8]=a8;  afin[16*lane+9]=a9;  afin[16*lane+10]=a10; afin[16*lane+11]=a11;
    afin[16*lane+12]=a12; afin[16*lane+13]=a13; afin[16*lane+14]=a14; afin[16*lane+15]=a15;
    __syncthreads();
    if (lane == 0) {
        float tot = afin[2*L] + afin[2*L-1];
        float lossb = 0.0f;
        if (tot > 0.0f) {
            double ll = log((double)tot)
                      + (double)E * 0.69314718055994530942
                      + (double)(-(double)Tn - (double)sl);
            lossb = (float)(-ll / (double)L);
        }
        loss_out[b] = lossb;
    }
    #undef STEP
    #undef RESCALE
    #undef LOADROW
}

// ---------------------------------------------------------------- mean
__global__ void mean_kernel(const float* __restrict__ loss, float* __restrict__ out)
{
    float v = loss[threadIdx.x];   // 64 threads
    #pragma unroll
    for (int off = 32; off; off >>= 1) v += __shfl_xor(v, off);
    if (threadIdx.x == 0) out[0] = v * (1.0f / 64.0f);
}

extern "C" void kernel_launch(void* const* d_in, const int* in_sizes, int n_in,
                              void* d_out, int out_size, void* d_ws, size_t ws_size,
                              hipStream_t stream)
{
    // setup_inputs order: attn (unused), in_lens, out_lens, attn_logprob
    const int*   in_lens  = (const int*)d_in[1];
    const int*   out_lens = (const int*)d_in[2];
    const float* ap       = (const float*)d_in[3];
    float*       out      = (float*)d_out;

    if (ws_size >= WS_NEED) {
        char*     wsb     = (char*)d_ws;
        _Float16* g       = (_Float16*)wsb;
        float*    lse_ws  = (float*)(wsb + LSE_OFF);
        float*    zb      = (float*)(wsb + ZERO_OFF);
        float*    loss_ws = (float*)(wsb + LOSS_OFF);
        hipLaunchKernelGGL(prep_kernel, dim3(32, 64), dim3(256), 0, stream,
                           ap, in_lens, out_lens, lse_ws, g, zb);
        hipLaunchKernelGGL(ctc_scan24_kernel, dim3(64), dim3(64), 0, stream,
                           (const char*)wsb, in_lens, out_lens, loss_ws);
        hipLaunchKernelGGL(mean_kernel, dim3(1), dim3(64), 0, stream, loss_ws, out);
    } else {
        float* lse_ws  = (float*)d_ws;
        float* loss_ws = (float*)((char*)d_ws + (size_t)64 * T_MAXN * 4);
        hipLaunchKernelGGL(lse_kernel, dim3(512), dim3(256), 0, stream,
                           ap, in_lens, lse_ws);
        hipLaunchKernelGGL(ctc_scan_kernel, dim3(64), dim3(64), 0, stream,
                           ap, in_lens, out_lens, lse_ws, loss_ws);
        hipLaunchKernelGGL(mean_kernel, dim3(1), dim3(64), 0, stream, loss_ws, out);
    }
}

// Round 9
// 211.703 us; speedup vs baseline: 5.2633x; 1.0037x over previous
//
#include <hip/hip_runtime.h>
#include <cmath>

// CTC alignment loss (RAD-TTS style), B=64, T<=2000, K<=400, S=2K+1<=801.
//
// Round-7 post-mortem: DPP boundary fix was neutral. VGPR_Count=88 exposes the
// real issue: 24 half8 prefetch slots need 96 VGPRs alone -> the allocator
// (tuned for occupancy we can't use; grid is only 64 blocks) sank the loads,
// collapsing effective prefetch depth. Round-8 change: __launch_bounds__(64,1)
// on the scan (1 wave/EU -> full VGPR file -> real 24-deep in-flight window).
// Everything else identical to round 7.

#define T_MAXN 2000
#define K_MAXN 400

typedef _Float16 half8 __attribute__((ext_vector_type(8)));

// ws layout (fast path)
#define G_BYTES   ((size_t)64 * T_MAXN * K_MAXN * 2)   // 102,400,000
#define LSE_OFF   G_BYTES
#define LSE_BYTES ((size_t)64 * T_MAXN * 4)            // 512,000
#define ZERO_OFF  (LSE_OFF + LSE_BYTES)                // 4KB zero block
#define LOSS_OFF  (ZERO_OFF + 4096)
#define WS_NEED   (LOSS_OFF + 64 * 4)

// lane-1's value (shift wave right by 1), lane 0 -> 0.0f; single VALU op
__device__ __forceinline__ float dpp_wave_shr1(float x)
{
    int r = __builtin_amdgcn_update_dpp(0, (int)__float_as_uint(x),
                                        0x138 /*wave_shr:1*/, 0xF, 0xF, true);
    return __uint_as_float((uint32_t)r);
}

// ---------------------------------------------------------- fast path: prep
__global__ __launch_bounds__(256)
void prep_kernel(const float* __restrict__ ap_all,
                 const int* __restrict__ in_lens,
                 const int* __restrict__ out_lens,
                 float* __restrict__ lse_out,
                 _Float16* __restrict__ g_out,
                 float* __restrict__ zerobuf)
{
    const int b    = blockIdx.y;
    const int L    = in_lens[b];
    const int Tn   = out_lens[b];
    const int lane = threadIdx.x & 63;
    const int wid  = blockIdx.x * (blockDim.x >> 6) + (threadIdx.x >> 6);
    const int nw   = gridDim.x * (blockDim.x >> 6);

    if (b == 0 && wid == 0) {                     // 4KB zero block for dead lanes
        for (int i = lane; i < 1024; i += 64) zerobuf[i] = 0.0f;
    }

    const float* base = ap_all + (size_t)b * (T_MAXN * K_MAXN);
    _Float16*    gb   = g_out  + (size_t)b * (T_MAXN * K_MAXN);
    const int c0 = lane * 8;
    const int cb = (c0 < 392) ? c0 : 392;         // clamped (lanes >= 50 fully masked)

    for (int t = wid; t < Tn; t += nw) {
        const float4* p = reinterpret_cast<const float4*>(base + (size_t)t * K_MAXN + cb);
        float4 x0 = p[0], x1 = p[1];
        float v[8] = {x0.x, x0.y, x0.z, x0.w, x1.x, x1.y, x1.z, x1.w};
        float m = -1.0f;                          // blank logit
        #pragma unroll
        for (int j = 0; j < 8; ++j) {
            v[j] = (c0 + j < L) ? v[j] : -1e30f;
            m = fmaxf(m, v[j]);
        }
        #pragma unroll
        for (int off = 32; off; off >>= 1) m = fmaxf(m, __shfl_xor(m, off));
        float s = (lane == 0) ? __expf(-1.0f - m) : 0.0f;
        #pragma unroll
        for (int j = 0; j < 8; ++j) s += __expf(v[j] - m);
        #pragma unroll
        for (int off = 32; off; off >>= 1) s += __shfl_xor(s, off);
        if (lane == 0) lse_out[b * T_MAXN + t] = m + __logf(s);

        half8 h;
        #pragma unroll
        for (int j = 0; j < 8; ++j) h[j] = (_Float16)__expf(v[j] + 1.0f);  // masked -> 0
        if (c0 < K_MAXN)
            *reinterpret_cast<half8*>(gb + (size_t)t * K_MAXN + c0) = h;
    }
}

// ---------------------------------------------------------- fast path: scan
__global__ __launch_bounds__(64, 1)
void ctc_scan24_kernel(const char* wsro,
                       const int* __restrict__ in_lens,
                       const int* __restrict__ out_lens,
                       float* loss_out)
{
    __shared__ float afin[1024];

    const int b    = blockIdx.x;
    const int lane = threadIdx.x;
    const int L    = in_lens[b];      // [200,400]
    const int Tn   = out_lens[b];     // [1000,2000]
    const uint32_t goff = (uint32_t)b * (uint32_t)(T_MAXN * K_MAXN * 2);
    const float* lse = (const float*)(wsro + LSE_OFF) + b * T_MAXN;

    // uniform base + 32-bit rolling offset; dead lanes park on the zero block
    uint32_t off, inc4;
    if (lane < 50) { off = goff + (uint32_t)lane * 16u + 800u; inc4 = 3200u; }
    else           { off = (uint32_t)ZERO_OFF;                  inc4 = 0u;    }

    // prologue: sl = sum_{t<Tn} lse[t]
    float sl = 0.0f;
    for (int t = lane; t < Tn; t += 64) sl += lse[t];
    #pragma unroll
    for (int o = 32; o; o >>= 1) sl += __shfl_xor(sl, o);

    // init t=0 (blank-normalized): alpha^[0]=1, alpha^[1]=g[0][0]
    float a0=0,a1=0,a2=0,a3=0,a4=0,a5=0,a6=0,a7=0;
    float a8=0,a9=0,a10=0,a11=0,a12=0,a13=0,a14=0,a15=0;
    if (lane == 0) {
        a0 = 1.0f;
        a1 = (float)*reinterpret_cast<const _Float16*>(wsro + goff);
    }
    int   E  = 0;
    float t1 = 0.0f;    // boundary: lane-1's a15 from previous step (via DPP)
    float rm = 0.0f;    // pipelined rescale max

    #define LOADG4(QA, QB, QC, QD) do { \
        QA = *reinterpret_cast<const half8*>(wsro + off); \
        QB = *reinterpret_cast<const half8*>(wsro + off + 800); \
        QC = *reinterpret_cast<const half8*>(wsro + off + 1600); \
        QD = *reinterpret_cast<const half8*>(wsro + off + 2400); \
        off += inc4; \
    } while (0)

    half8 q0,q1,q2,q3,q4,q5,q6,q7,q8,q9,q10,q11;
    half8 q12,q13,q14,q15,q16,q17,q18,q19,q20,q21,q22,q23;
    LOADG4(q0,q1,q2,q3);     LOADG4(q4,q5,q6,q7);     LOADG4(q8,q9,q10,q11);
    LOADG4(q12,q13,q14,q15); LOADG4(q16,q17,q18,q19); LOADG4(q20,q21,q22,q23);

    // even s=2j: new = old[2j]+old[2j-1];  odd: new = g*(old[2j+1]+new_even)
    #define STEPF(Q) do { \
        const float f0 = (float)(Q)[0], f1 = (float)(Q)[1], f2 = (float)(Q)[2], f3 = (float)(Q)[3]; \
        const float f4 = (float)(Q)[4], f5 = (float)(Q)[5], f6 = (float)(Q)[6], f7 = (float)(Q)[7]; \
        const float e0 = a0 + t1,  e1 = a2 + a1,   e2 = a4 + a3,   e3 = a6 + a5; \
        const float e4 = a8 + a7,  e5 = a10 + a9,  e6 = a12 + a11, e7 = a14 + a13; \
        const float o0 = a1 + e0,  o1 = a3 + e1,   o2 = a5 + e2,   o3 = a7 + e3; \
        const float o4 = a9 + e4,  o5 = a11 + e5,  o6 = a13 + e6,  o7 = a15 + e7; \
        a0 = e0; a2 = e1; a4 = e2; a6 = e3; a8 = e4; a10 = e5; a12 = e6; a14 = e7; \
        a1 = f0*o0; a3 = f1*o1; a5 = f2*o2; a7 = f3*o3; \
        a9 = f4*o4; a11 = f5*o5; a13 = f6*o6; a15 = f7*o7; \
        t1 = dpp_wave_shr1(a15); \
    } while (0)

    // pipelined rescale phases (wave max is monotone non-decreasing -> stale-safe)
    #define PH0 do { \
        float m01 = fmaxf(a0,a1),  m23 = fmaxf(a2,a3),   m45 = fmaxf(a4,a5),   m67 = fmaxf(a6,a7); \
        float m89 = fmaxf(a8,a9),  mab = fmaxf(a10,a11), mcd = fmaxf(a12,a13), mef = fmaxf(a14,a15); \
        float mA = fmaxf(m01,m23), mB = fmaxf(m45,m67),  mC = fmaxf(m89,mab),  mD = fmaxf(mcd,mef); \
        rm = fmaxf(fmaxf(mA,mB), fmaxf(mC,mD)); \
    } while (0)
    #define PHX(MASK) rm = fmaxf(rm, __shfl_xor(rm, MASK))
    #define PH7 do { \
        int e = (int)((__float_as_uint(rm) >> 23) & 0xFF) - 127; \
        E += e; \
        const float sc = __uint_as_float((uint32_t)(127 - e) << 23);  /* 2^-e exact */ \
        a0*=sc; a1*=sc; a2*=sc;  a3*=sc;  a4*=sc;  a5*=sc;  a6*=sc;  a7*=sc; \
        a8*=sc; a9*=sc; a10*=sc; a11*=sc; a12*=sc; a13*=sc; a14*=sc; a15*=sc; \
        t1 *= sc; \
    } while (0)
    #define RESCDEP do { \
        PH0; \
        rm = fmaxf(rm, __shfl_xor(rm, 1));  rm = fmaxf(rm, __shfl_xor(rm, 2)); \
        rm = fmaxf(rm, __shfl_xor(rm, 4));  rm = fmaxf(rm, __shfl_xor(rm, 8)); \
        rm = fmaxf(rm, __shfl_xor(rm, 16)); rm = fmaxf(rm, __shfl_xor(rm, 32)); \
        PH7; \
    } while (0)

    int t = 1;
    while (t + 23 < Tn) {
        STEPF(q0);  PH0;
        STEPF(q1);  PHX(1);
        STEPF(q2);  PHX(2);
        STEPF(q3);  PHX(4);  LOADG4(q0,q1,q2,q3);
        STEPF(q4);  PHX(8);
        STEPF(q5);  PHX(16);
        STEPF(q6);  PHX(32);
        STEPF(q7);  PH7;     LOADG4(q4,q5,q6,q7);
        STEPF(q8);  PH0;
        STEPF(q9);  PHX(1);
        STEPF(q10); PHX(2);
        STEPF(q11); PHX(4);  LOADG4(q8,q9,q10,q11);
        STEPF(q12); PHX(8);
        STEPF(q13); PHX(16);
        STEPF(q14); PHX(32);
        STEPF(q15); PH7;     LOADG4(q12,q13,q14,q15);
        STEPF(q16); PH0;
        STEPF(q17); PHX(1);
        STEPF(q18); PHX(2);
        STEPF(q19); PHX(4);  LOADG4(q16,q17,q18,q19);
        STEPF(q20); PHX(8);
        STEPF(q21); PHX(16);
        STEPF(q22); PHX(32);
        STEPF(q23); PH7;     LOADG4(q20,q21,q22,q23);
        t += 24;
    }
    {
        const int r = Tn - t;   // 0..23; q_i holds row t+i
        if (r > 0)  STEPF(q0);
        if (r > 1)  STEPF(q1);
        if (r > 2)  STEPF(q2);
        if (r > 3)  STEPF(q3);
        if (r > 4)  STEPF(q4);
        if (r > 5)  STEPF(q5);
        if (r > 6)  STEPF(q6);
        if (r > 7)  STEPF(q7);
        if (r > 8)  { RESCDEP; STEPF(q8); }
        if (r > 9)  STEPF(q9);
        if (r > 10) STEPF(q10);
        if (r > 11) STEPF(q11);
        if (r > 12) STEPF(q12);
        if (r > 13) STEPF(q13);
        if (r > 14) STEPF(q14);
        if (r > 15) STEPF(q15);
        if (r > 16) { RESCDEP; STEPF(q16); }
        if (r > 17) STEPF(q17);
        if (r > 18) STEPF(q18);
        if (r > 19) STEPF(q19);
        if (r > 20) STEPF(q20);
        if (r > 21) STEPF(q21);
        if (r > 22) STEPF(q22);
    }

    afin[16*lane+0]=a0;   afin[16*lane+1]=a1;   afin[16*lane+2]=a2;   afin[16*lane+3]=a3;
    afin[16*lane+4]=a4;   afin[16*lane+5]=a5;   afin[16*lane+6]=a6;   afin[16*lane+7]=a7;
    afin[16*lane+8]=a8;   afin[16*lane+9]=a9;   afin[16*lane+10]=a10; afin[16*lane+11]=a11;
    afin[16*lane+12]=a12; afin[16*lane+13]=a13; afin[16*lane+14]=a14; afin[16*lane+15]=a15;
    __syncthreads();
    if (lane == 0) {
        float tot = afin[2*L] + afin[2*L-1];
        float lossb = 0.0f;
        if (tot > 0.0f) {
            double ll = log((double)tot)
                      + (double)E * 0.69314718055994530942
                      + (double)(-(double)Tn - (double)sl);
            lossb = (float)(-ll / (double)L);
        }
        loss_out[b] = lossb;
    }
    #undef STEPF
    #undef PH0
    #undef PHX
    #undef PH7
    #undef RESCDEP
    #undef LOADG4
}

// ------------------------------------------------- fallback (round-3, proven)
__global__ __launch_bounds__(256)
void lse_kernel(const float* __restrict__ ap_all,
                const int* __restrict__ in_lens,
                float* __restrict__ lse_out)
{
    const int lane = threadIdx.x & 63;
    const int wglob = blockIdx.x * (blockDim.x >> 6) + (threadIdx.x >> 6);
    const int nwav = gridDim.x * (blockDim.x >> 6);
    const int nrows = 64 * T_MAXN;

    for (int row = wglob; row < nrows; row += nwav) {
        const int b = row / T_MAXN;
        const int L = in_lens[b];
        const float* rp = ap_all + (size_t)row * K_MAXN;
        const int c0 = lane * 8;
        const int cb = (c0 < 392) ? c0 : 392;
        const float4* p = reinterpret_cast<const float4*>(rp + cb);
        float4 x0 = p[0], x1 = p[1];
        float v[8] = {x0.x, x0.y, x0.z, x0.w, x1.x, x1.y, x1.z, x1.w};
        float m = -1.0f;
        #pragma unroll
        for (int j = 0; j < 8; ++j) {
            v[j] = (c0 + j < L) ? v[j] : -1e30f;
            m = fmaxf(m, v[j]);
        }
        #pragma unroll
        for (int off = 32; off; off >>= 1) m = fmaxf(m, __shfl_xor(m, off));
        float s = (lane == 0) ? __expf(-1.0f - m) : 0.0f;
        #pragma unroll
        for (int j = 0; j < 8; ++j) s += __expf(v[j] - m);
        #pragma unroll
        for (int off = 32; off; off >>= 1) s += __shfl_xor(s, off);
        if (lane == 0) lse_out[row] = m + __logf(s);
    }
}

__global__ __launch_bounds__(64)
void ctc_scan_kernel(const float* __restrict__ ap_all,
                     const int* __restrict__ in_lens,
                     const int* __restrict__ out_lens,
                     const float* __restrict__ lse_all,
                     float* __restrict__ loss_out)
{
    __shared__ float afin[1024];

    const int b    = blockIdx.x;
    const int lane = threadIdx.x;
    const int L    = in_lens[b];
    const int Tn   = out_lens[b];
    const float* ap  = ap_all + (size_t)b * (T_MAXN * K_MAXN);
    const float* lse = lse_all + b * T_MAXN;

    const float LOG2E = 1.4426950408889634f;
    const int c0 = lane * 8;
    const int cb = (c0 < 392) ? c0 : 392;
    const float* rbase = ap + cb;
    float fa0,fa1,fa2,fa3,fa4,fa5,fa6,fa7;
    float fb0,fb1,fb2,fb3,fb4,fb5,fb6,fb7;
    #define MASKC(J, FA, FB) do { bool ok = (c0 + (J)) < L; \
        FA = ok ? LOG2E : 0.0f; FB = ok ? LOG2E : -1000.0f; } while (0)
    MASKC(0,fa0,fb0); MASKC(1,fa1,fb1); MASKC(2,fa2,fb2); MASKC(3,fa3,fb3);
    MASKC(4,fa4,fb4); MASKC(5,fa5,fb5); MASKC(6,fa6,fb6); MASKC(7,fa7,fb7);
    #undef MASKC

    float4 p0a,p0b,p1a,p1b,p2a,p2b,p3a,p3b;
    #define LOADROW(PA, PB, T) do { \
        const float4* _p = reinterpret_cast<const float4*>(rbase + (size_t)(T) * K_MAXN); \
        PA = _p[0]; PB = _p[1]; } while (0)
    LOADROW(p0a,p0b,1); LOADROW(p1a,p1b,2); LOADROW(p2a,p2b,3); LOADROW(p3a,p3b,4);

    float sl = 0.0f;
    for (int t = lane; t < Tn; t += 64) sl += lse[t];
    #pragma unroll
    for (int off = 32; off; off >>= 1) sl += __shfl_xor(sl, off);

    float x00 = ap[0];
    float a0=0,a1=0,a2=0,a3=0,a4=0,a5=0,a6=0,a7=0;
    float a8=0,a9=0,a10=0,a11=0,a12=0,a13=0,a14=0,a15=0;
    if (lane == 0) {
        a0 = 1.0f;
        a1 = __builtin_amdgcn_exp2f(fmaf(x00, LOG2E, LOG2E));
    }
    int E = 0;

    #define STEP(A0, A1) do { \
        float t1 = __shfl_up(a15, 1); \
        t1 = lane ? t1 : 0.0f; \
        const float f0 = __builtin_amdgcn_exp2f(fmaf((A0).x, fa0, fb0)); \
        const float f1 = __builtin_amdgcn_exp2f(fmaf((A0).y, fa1, fb1)); \
        const float f2 = __builtin_amdgcn_exp2f(fmaf((A0).z, fa2, fb2)); \
        const float f3 = __builtin_amdgcn_exp2f(fmaf((A0).w, fa3, fb3)); \
        const float f4 = __builtin_amdgcn_exp2f(fmaf((A1).x, fa4, fb4)); \
        const float f5 = __builtin_amdgcn_exp2f(fmaf((A1).y, fa5, fb5)); \
        const float f6 = __builtin_amdgcn_exp2f(fmaf((A1).z, fa6, fb6)); \
        const float f7 = __builtin_amdgcn_exp2f(fmaf((A1).w, fa7, fb7)); \
        const float e0 = a0 + t1,   e1 = a2 + a1,   e2 = a4 + a3,   e3 = a6 + a5; \
        const float e4 = a8 + a7,   e5 = a10 + a9,  e6 = a12 + a11, e7 = a14 + a13; \
        const float o0 = a1 + e0,   o1 = a3 + e1,   o2 = a5 + e2,   o3 = a7 + e3; \
        const float o4 = a9 + e4,   o5 = a11 + e5,  o6 = a13 + e6,  o7 = a15 + e7; \
        a0 = e0; a2 = e1; a4 = e2; a6 = e3; a8 = e4; a10 = e5; a12 = e6; a14 = e7; \
        a1 = f0*o0; a3 = f1*o1; a5 = f2*o2; a7 = f3*o3; \
        a9 = f4*o4; a11 = f5*o5; a13 = f6*o6; a15 = f7*o7; \
    } while (0)

    #define RESCALE do { \
        float mx = fmaxf(fmaxf(fmaxf(fmaxf(a0,a1),fmaxf(a2,a3)),fmaxf(fmaxf(a4,a5),fmaxf(a6,a7))), \
                         fmaxf(fmaxf(fmaxf(a8,a9),fmaxf(a10,a11)),fmaxf(fmaxf(a12,a13),fmaxf(a14,a15)))); \
        _Pragma("unroll") \
        for (int off = 32; off; off >>= 1) mx = fmaxf(mx, __shfl_xor(mx, off)); \
        int e = (int)((__float_as_uint(mx) >> 23) & 0xFF) - 127; \
        if (e != 0) { \
            E += e; \
            a0 = ldexpf(a0,-e);  a1 = ldexpf(a1,-e);  a2 = ldexpf(a2,-e);  a3 = ldexpf(a3,-e); \
            a4 = ldexpf(a4,-e);  a5 = ldexpf(a5,-e);  a6 = ldexpf(a6,-e);  a7 = ldexpf(a7,-e); \
            a8 = ldexpf(a8,-e);  a9 = ldexpf(a9,-e);  a10= ldexpf(a10,-e); a11= ldexpf(a11,-e); \
            a12= ldexpf(a12,-e); a13= ldexpf(a13,-e); a14= ldexpf(a14,-e); a15= ldexpf(a15,-e); \
        } \
    } while (0)

    int t = 1;
    while (t + 3 < Tn) {
        int tl;
        STEP(p0a,p0b); tl = (t+4 < T_MAXN) ? t+4 : T_MAXN-1; LOADROW(p0a,p0b,tl);
        STEP(p1a,p1b); tl = (t+5 < T_MAXN) ? t+5 : T_MAXN-1; LOADROW(p1a,p1b,tl);
        STEP(p2a,p2b); tl = (t+6 < T_MAXN) ? t+6 : T_MAXN-1; LOADROW(p2a,p2b,tl);
        STEP(p3a,p3b); tl = (t+7 < T_MAXN) ? t+7 : T_MAXN-1; LOADROW(p3a,p3b,tl);
        if ((t & 7) == 5) RESCALE;
        t += 4;
    }
    if (t < Tn) { STEP(p0a,p0b); ++t; }
    if (t < Tn) { STEP(p1a,p1b); ++t; }
    if (t < Tn) { STEP(p2a,p2b); ++t; }

    afin[16*lane+0]=a0;  afin[16*lane+1]=a1;  afin[16*lane+2]=a2;  afin[16*lane+3]=a3;
    afin[16*lane+4]=a4;  afin[16*lane+5]=a5;  afin[16*lane+6]=a6;  afin[16*lane+7]=a7;
    afin[16*lane+8]=a8;  afin[16*lane+9]=a9;  afin[16*lane+10]=a10; afin[16*lane+11]=a11;
    afin[16*lane+12]=a12; afin[16*lane+13]=a13; afin[16*lane+14]=a14; afin[16*lane+15]=a15;
    __syncthreads();
    if (lane == 0) {
        float tot = afin[2*L] + afin[2*L-1];
        float lossb = 0.0f;
        if (tot > 0.0f) {
            double ll = log((double)tot)
                      + (double)E * 0.69314718055994530942
                      + (double)(-(double)Tn - (double)sl);
            lossb = (float)(-ll / (double)L);
        }
        loss_out[b] = lossb;
    }
    #undef STEP
    #undef RESCALE
    #undef LOADROW
}

// ---------------------------------------------------------------- mean
__global__ void mean_kernel(const float* __restrict__ loss, float* __restrict__ out)
{
    float v = loss[threadIdx.x];   // 64 threads
    #pragma unroll
    for (int off = 32; off; off >>= 1) v += __shfl_xor(v, off);
    if (threadIdx.x == 0) out[0] = v * (1.0f / 64.0f);
}

extern "C" void kernel_launch(void* const* d_in, const int* in_sizes, int n_in,
                              void* d_out, int out_size, void* d_ws, size_t ws_size,
                              hipStream_t stream)
{
    // setup_inputs order: attn (unused), in_lens, out_lens, attn_logprob
    const int*   in_lens  = (const int*)d_in[1];
    const int*   out_lens = (const int*)d_in[2];
    const float* ap       = (const float*)d_in[3];
    float*       out      = (float*)d_out;

    if (ws_size >= WS_NEED) {
        char*     wsb     = (char*)d_ws;
        _Float16* g       = (_Float16*)wsb;
        float*    lse_ws  = (float*)(wsb + LSE_OFF);
        float*    zb      = (float*)(wsb + ZERO_OFF);
        float*    loss_ws = (float*)(wsb + LOSS_OFF);
        hipLaunchKernelGGL(prep_kernel, dim3(32, 64), dim3(256), 0, stream,
                           ap, in_lens, out_lens, lse_ws, g, zb);
        hipLaunchKernelGGL(ctc_scan24_kernel, dim3(64), dim3(64), 0, stream,
                           (const char*)wsb, in_lens, out_lens, loss_ws);
        hipLaunchKernelGGL(mean_kernel, dim3(1), dim3(64), 0, stream, loss_ws, out);
    } else {
        float* lse_ws  = (float*)d_ws;
        float* loss_ws = (float*)((char*)d_ws + (size_t)64 * T_MAXN * 4);
        hipLaunchKernelGGL(lse_kernel, dim3(512), dim3(256), 0, stream,
                           ap, in_lens, lse_ws);
        hipLaunchKernelGGL(ctc_scan_kernel, dim3(64), dim3(64), 0, stream,
                           ap, in_lens, out_lens, lse_ws, loss_ws);
        hipLaunchKernelGGL(mean_kernel, dim3(1), dim3(64), 0, stream, loss_ws, out);
    }
}

// Round 11
// 191.805 us; speedup vs baseline: 5.8093x; 1.1037x over previous
//
#include <hip/hip_runtime.h>
#include <cmath>

// CTC alignment loss (RAD-TTS style), B=64, T<=2000, K<=400, S=2K+1<=801.
//
// Round-9 post-mortem: __launch_bounds__(64,1) did NOT raise VGPR_Count (88) —
// the scheduler minimizes live ranges and sinks prefetch loads regardless of
// budget. Round-10 changes (scan only):
//   1. asm volatile("" ::: "memory") after each LOADG4 — compiler memory fence
//      pins load issue points; 24 rows genuinely in flight (VGPR must rise).
//   2. rescale max via DPP row_shr/row_bcast chain (all VALU, 1 op/step phase,
//      readlane(63) at apply) — removes per-step ds_swizzle latency. bound_ctrl
//      zero-fill is identity for max of non-negative alphas.

#define T_MAXN 2000
#define K_MAXN 400

typedef _Float16 half8 __attribute__((ext_vector_type(8)));

// ws layout (fast path)
#define G_BYTES   ((size_t)64 * T_MAXN * K_MAXN * 2)   // 102,400,000
#define LSE_OFF   G_BYTES
#define LSE_BYTES ((size_t)64 * T_MAXN * 4)            // 512,000
#define ZERO_OFF  (LSE_OFF + LSE_BYTES)                // 4KB zero block
#define LOSS_OFF  (ZERO_OFF + 4096)
#define WS_NEED   (LOSS_OFF + 64 * 4)

// lane-1's value (shift wave right by 1), lane 0 -> 0.0f; single VALU op
__device__ __forceinline__ float dpp_wave_shr1(float x)
{
    int r = __builtin_amdgcn_update_dpp(0, (int)__float_as_uint(x),
                                        0x138 /*wave_shr:1*/, 0xF, 0xF, true);
    return __uint_as_float((uint32_t)r);
}

template <int CTRL>
__device__ __forceinline__ float dpp_mov(float x)
{
    int r = __builtin_amdgcn_update_dpp(0, (int)__float_as_uint(x),
                                        CTRL, 0xF, 0xF, true);
    return __uint_as_float((uint32_t)r);
}

// ---------------------------------------------------------- fast path: prep
__global__ __launch_bounds__(256)
void prep_kernel(const float* __restrict__ ap_all,
                 const int* __restrict__ in_lens,
                 const int* __restrict__ out_lens,
                 float* __restrict__ lse_out,
                 _Float16* __restrict__ g_out,
                 float* __restrict__ zerobuf)
{
    const int b    = blockIdx.y;
    const int L    = in_lens[b];
    const int Tn   = out_lens[b];
    const int lane = threadIdx.x & 63;
    const int wid  = blockIdx.x * (blockDim.x >> 6) + (threadIdx.x >> 6);
    const int nw   = gridDim.x * (blockDim.x >> 6);

    if (b == 0 && wid == 0) {                     // 4KB zero block for dead lanes
        for (int i = lane; i < 1024; i += 64) zerobuf[i] = 0.0f;
    }

    const float* base = ap_all + (size_t)b * (T_MAXN * K_MAXN);
    _Float16*    gb   = g_out  + (size_t)b * (T_MAXN * K_MAXN);
    const int c0 = lane * 8;
    const int cb = (c0 < 392) ? c0 : 392;         // clamped (lanes >= 50 fully masked)

    for (int t = wid; t < Tn; t += nw) {
        const float4* p = reinterpret_cast<const float4*>(base + (size_t)t * K_MAXN + cb);
        float4 x0 = p[0], x1 = p[1];
        float v[8] = {x0.x, x0.y, x0.z, x0.w, x1.x, x1.y, x1.z, x1.w};
        float m = -1.0f;                          // blank logit
        #pragma unroll
        for (int j = 0; j < 8; ++j) {
            v[j] = (c0 + j < L) ? v[j] : -1e30f;
            m = fmaxf(m, v[j]);
        }
        #pragma unroll
        for (int off = 32; off; off >>= 1) m = fmaxf(m, __shfl_xor(m, off));
        float s = (lane == 0) ? __expf(-1.0f - m) : 0.0f;
        #pragma unroll
        for (int j = 0; j < 8; ++j) s += __expf(v[j] - m);
        #pragma unroll
        for (int off = 32; off; off >>= 1) s += __shfl_xor(s, off);
        if (lane == 0) lse_out[b * T_MAXN + t] = m + __logf(s);

        half8 h;
        #pragma unroll
        for (int j = 0; j < 8; ++j) h[j] = (_Float16)__expf(v[j] + 1.0f);  // masked -> 0
        if (c0 < K_MAXN)
            *reinterpret_cast<half8*>(gb + (size_t)t * K_MAXN + c0) = h;
    }
}

// ---------------------------------------------------------- fast path: scan
__global__ __launch_bounds__(64, 1)
void ctc_scan24_kernel(const char* wsro,
                       const int* __restrict__ in_lens,
                       const int* __restrict__ out_lens,
                       float* loss_out)
{
    __shared__ float afin[1024];

    const int b    = blockIdx.x;
    const int lane = threadIdx.x;
    const int L    = in_lens[b];      // [200,400]
    const int Tn   = out_lens[b];     // [1000,2000]
    const uint32_t goff = (uint32_t)b * (uint32_t)(T_MAXN * K_MAXN * 2);
    const float* lse = (const float*)(wsro + LSE_OFF) + b * T_MAXN;

    // uniform base + 32-bit rolling offset; dead lanes park on the zero block
    uint32_t off, inc4;
    if (lane < 50) { off = goff + (uint32_t)lane * 16u + 800u; inc4 = 3200u; }
    else           { off = (uint32_t)ZERO_OFF;                  inc4 = 0u;    }

    // prologue: sl = sum_{t<Tn} lse[t]
    float sl = 0.0f;
    for (int t = lane; t < Tn; t += 64) sl += lse[t];
    #pragma unroll
    for (int o = 32; o; o >>= 1) sl += __shfl_xor(sl, o);

    // init t=0 (blank-normalized): alpha^[0]=1, alpha^[1]=g[0][0]
    float a0=0,a1=0,a2=0,a3=0,a4=0,a5=0,a6=0,a7=0;
    float a8=0,a9=0,a10=0,a11=0,a12=0,a13=0,a14=0,a15=0;
    if (lane == 0) {
        a0 = 1.0f;
        a1 = (float)*reinterpret_cast<const _Float16*>(wsro + goff);
    }
    int   E  = 0;
    float t1 = 0.0f;    // boundary: lane-1's a15 from previous step (via DPP)
    float rm = 0.0f;    // pipelined rescale max (all lanes >= 0)

    // loads pinned by a compiler memory fence so they cannot be sunk to uses
    #define LOADG4(QA, QB, QC, QD) do { \
        QA = *reinterpret_cast<const half8*>(wsro + off); \
        QB = *reinterpret_cast<const half8*>(wsro + off + 800); \
        QC = *reinterpret_cast<const half8*>(wsro + off + 1600); \
        QD = *reinterpret_cast<const half8*>(wsro + off + 2400); \
        off += inc4; \
        asm volatile("" ::: "memory"); \
    } while (0)

    half8 q0,q1,q2,q3,q4,q5,q6,q7,q8,q9,q10,q11;
    half8 q12,q13,q14,q15,q16,q17,q18,q19,q20,q21,q22,q23;
    LOADG4(q0,q1,q2,q3);     LOADG4(q4,q5,q6,q7);     LOADG4(q8,q9,q10,q11);
    LOADG4(q12,q13,q14,q15); LOADG4(q16,q17,q18,q19); LOADG4(q20,q21,q22,q23);

    // even s=2j: new = old[2j]+old[2j-1];  odd: new = g*(old[2j+1]+new_even)
    #define STEPF(Q) do { \
        const float f0 = (float)(Q)[0], f1 = (float)(Q)[1], f2 = (float)(Q)[2], f3 = (float)(Q)[3]; \
        const float f4 = (float)(Q)[4], f5 = (float)(Q)[5], f6 = (float)(Q)[6], f7 = (float)(Q)[7]; \
        const float e0 = a0 + t1,  e1 = a2 + a1,   e2 = a4 + a3,   e3 = a6 + a5; \
        const float e4 = a8 + a7,  e5 = a10 + a9,  e6 = a12 + a11, e7 = a14 + a13; \
        const float o0 = a1 + e0,  o1 = a3 + e1,   o2 = a5 + e2,   o3 = a7 + e3; \
        const float o4 = a9 + e4,  o5 = a11 + e5,  o6 = a13 + e6,  o7 = a15 + e7; \
        a0 = e0; a2 = e1; a4 = e2; a6 = e3; a8 = e4; a10 = e5; a12 = e6; a14 = e7; \
        a1 = f0*o0; a3 = f1*o1; a5 = f2*o2; a7 = f3*o3; \
        a9 = f4*o4; a11 = f5*o5; a13 = f6*o6; a15 = f7*o7; \
        t1 = dpp_wave_shr1(a15); \
    } while (0)

    // pipelined rescale: lane-tree max at ph0; one DPP combine per phase
    // (row_shr 1/2/4/8 then row_bcast15/31 -> lane 63 holds wave max);
    // bound_ctrl zero-fill is identity for max of non-negatives. Wave max is
    // monotone non-decreasing in the blank-normalized domain -> stale-safe.
    #define PH0 do { \
        float m01 = fmaxf(a0,a1),  m23 = fmaxf(a2,a3),   m45 = fmaxf(a4,a5),   m67 = fmaxf(a6,a7); \
        float m89 = fmaxf(a8,a9),  mab = fmaxf(a10,a11), mcd = fmaxf(a12,a13), mef = fmaxf(a14,a15); \
        float mA = fmaxf(m01,m23), mB = fmaxf(m45,m67),  mC = fmaxf(m89,mab),  mD = fmaxf(mcd,mef); \
        rm = fmaxf(fmaxf(mA,mB), fmaxf(mC,mD)); \
    } while (0)
    #define PHD(CTRL) rm = fmaxf(rm, dpp_mov<CTRL>(rm))
    #define PH7 do { \
        float rmu = __uint_as_float((uint32_t)__builtin_amdgcn_readlane((int)__float_as_uint(rm), 63)); \
        int e = (int)((__float_as_uint(rmu) >> 23) & 0xFF) - 127; \
        E += e; \
        const float sc = __uint_as_float((uint32_t)(127 - e) << 23);  /* 2^-e exact */ \
        a0*=sc; a1*=sc; a2*=sc;  a3*=sc;  a4*=sc;  a5*=sc;  a6*=sc;  a7*=sc; \
        a8*=sc; a9*=sc; a10*=sc; a11*=sc; a12*=sc; a13*=sc; a14*=sc; a15*=sc; \
        t1 *= sc; \
    } while (0)
    #define RESCDEP do { \
        PH0; \
        PHD(0x111); PHD(0x112); PHD(0x114); PHD(0x118); \
        PHD(0x142); PHD(0x143); \
        PH7; \
    } while (0)

    int t = 1;
    while (t + 23 < Tn) {
        STEPF(q0);  PH0;
        STEPF(q1);  PHD(0x111);
        STEPF(q2);  PHD(0x112);
        STEPF(q3);  PHD(0x114);  LOADG4(q0,q1,q2,q3);
        STEPF(q4);  PHD(0x118);
        STEPF(q5);  PHD(0x142);
        STEPF(q6);  PHD(0x143);
        STEPF(q7);  PH7;         LOADG4(q4,q5,q6,q7);
        STEPF(q8);  PH0;
        STEPF(q9);  PHD(0x111);
        STEPF(q10); PHD(0x112);
        STEPF(q11); PHD(0x114);  LOADG4(q8,q9,q10,q11);
        STEPF(q12); PHD(0x118);
        STEPF(q13); PHD(0x142);
        STEPF(q14); PHD(0x143);
        STEPF(q15); PH7;         LOADG4(q12,q13,q14,q15);
        STEPF(q16); PH0;
        STEPF(q17); PHD(0x111);
        STEPF(q18); PHD(0x112);
        STEPF(q19); PHD(0x114);  LOADG4(q16,q17,q18,q19);
        STEPF(q20); PHD(0x118);
        STEPF(q21); PHD(0x142);
        STEPF(q22); PHD(0x143);
        STEPF(q23); PH7;         LOADG4(q20,q21,q22,q23);
        t += 24;
    }
    {
        const int r = Tn - t;   // 0..23; q_i holds row t+i
        if (r > 0)  STEPF(q0);
        if (r > 1)  STEPF(q1);
        if (r > 2)  STEPF(q2);
        if (r > 3)  STEPF(q3);
        if (r > 4)  STEPF(q4);
        if (r > 5)  STEPF(q5);
        if (r > 6)  STEPF(q6);
        if (r > 7)  STEPF(q7);
        if (r > 8)  { RESCDEP; STEPF(q8); }
        if (r > 9)  STEPF(q9);
        if (r > 10) STEPF(q10);
        if (r > 11) STEPF(q11);
        if (r > 12) STEPF(q12);
        if (r > 13) STEPF(q13);
        if (r > 14) STEPF(q14);
        if (r > 15) STEPF(q15);
        if (r > 16) { RESCDEP; STEPF(q16); }
        if (r > 17) STEPF(q17);
        if (r > 18) STEPF(q18);
        if (r > 19) STEPF(q19);
        if (r > 20) STEPF(q20);
        if (r > 21) STEPF(q21);
        if (r > 22) STEPF(q22);
    }

    afin[16*lane+0]=a0;   afin[16*lane+1]=a1;   afin[16*lane+2]=a2;   afin[16*lane+3]=a3;
    afin[16*lane+4]=a4;   afin[16*lane+5]=a5;   afin[16*lane+6]=a6;   afin[16*lane+7]=a7;
    afin[16*lane+8]=a8;   afin[16*lane+9]=a9;   afin[16*lane+10]=a10; afin[16*lane+11]=a11;
    afin[16*lane+12]=a12; afin[16*lane+13]=a13; afin[16*lane+14]=a14; afin[16*lane+15]=a15;
    __syncthreads();
    if (lane == 0) {
        float tot = afin[2*L] + afin[2*L-1];
        float lossb = 0.0f;
        if (tot > 0.0f) {
            double ll = log((double)tot)
                      + (double)E * 0.69314718055994530942
                      + (double)(-(double)Tn - (double)sl);
            lossb = (float)(-ll / (double)L);
        }
        loss_out[b] = lossb;
    }
    #undef STEPF
    #undef PH0
    #undef PHD
    #undef PH7
    #undef RESCDEP
    #undef LOADG4
}

// ------------------------------------------------- fallback (round-3, proven)
__global__ __launch_bounds__(256)
void lse_kernel(const float* __restrict__ ap_all,
                const int* __restrict__ in_lens,
                float* __restrict__ lse_out)
{
    const int lane = threadIdx.x & 63;
    const int wglob = blockIdx.x * (blockDim.x >> 6) + (threadIdx.x >> 6);
    const int nwav = gridDim.x * (blockDim.x >> 6);
    const int nrows = 64 * T_MAXN;

    for (int row = wglob; row < nrows; row += nwav) {
        const int b = row / T_MAXN;
        const int L = in_lens[b];
        const float* rp = ap_all + (size_t)row * K_MAXN;
        const int c0 = lane * 8;
        const int cb = (c0 < 392) ? c0 : 392;
        const float4* p = reinterpret_cast<const float4*>(rp + cb);
        float4 x0 = p[0], x1 = p[1];
        float v[8] = {x0.x, x0.y, x0.z, x0.w, x1.x, x1.y, x1.z, x1.w};
        float m = -1.0f;
        #pragma unroll
        for (int j = 0; j < 8; ++j) {
            v[j] = (c0 + j < L) ? v[j] : -1e30f;
            m = fmaxf(m, v[j]);
        }
        #pragma unroll
        for (int off = 32; off; off >>= 1) m = fmaxf(m, __shfl_xor(m, off));
        float s = (lane == 0) ? __expf(-1.0f - m) : 0.0f;
        #pragma unroll
        for (int j = 0; j < 8; ++j) s += __expf(v[j] - m);
        #pragma unroll
        for (int off = 32; off; off >>= 1) s += __shfl_xor(s, off);
        if (lane == 0) lse_out[row] = m + __logf(s);
    }
}

__global__ __launch_bounds__(64)
void ctc_scan_kernel(const float* __restrict__ ap_all,
                     const int* __restrict__ in_lens,
                     const int* __restrict__ out_lens,
                     const float* __restrict__ lse_all,
                     float* __restrict__ loss_out)
{
    __shared__ float afin[1024];

    const int b    = blockIdx.x;
    const int lane = threadIdx.x;
    const int L    = in_lens[b];
    const int Tn   = out_lens[b];
    const float* ap  = ap_all + (size_t)b * (T_MAXN * K_MAXN);
    const float* lse = lse_all + b * T_MAXN;

    const float LOG2E = 1.4426950408889634f;
    const int c0 = lane * 8;
    const int cb = (c0 < 392) ? c0 : 392;
    const float* rbase = ap + cb;
    float fa0,fa1,fa2,fa3,fa4,fa5,fa6,fa7;
    float fb0,fb1,fb2,fb3,fb4,fb5,fb6,fb7;
    #define MASKC(J, FA, FB) do { bool ok = (c0 + (J)) < L; \
        FA = ok ? LOG2E : 0.0f; FB = ok ? LOG2E : -1000.0f; } while (0)
    MASKC(0,fa0,fb0); MASKC(1,fa1,fb1); MASKC(2,fa2,fb2); MASKC(3,fa3,fb3);
    MASKC(4,fa4,fb4); MASKC(5,fa5,fb5); MASKC(6,fa6,fb6); MASKC(7,fa7,fb7);
    #undef MASKC

    float4 p0a,p0b,p1a,p1b,p2a,p2b,p3a,p3b;
    #define LOADROW(PA, PB, T) do { \
        const float4* _p = reinterpret_cast<const float4*>(rbase + (size_t)(T) * K_MAXN); \
        PA = _p[0]; PB = _p[1]; } while (0)
    LOADROW(p0a,p0b,1); LOADROW(p1a,p1b,2); LOADROW(p2a,p2b,3); LOADROW(p3a,p3b,4);

    float sl = 0.0f;
    for (int t = lane; t < Tn; t += 64) sl += lse[t];
    #pragma unroll
    for (int off = 32; off; off >>= 1) sl += __shfl_xor(sl, off);

    float x00 = ap[0];
    float a0=0,a1=0,a2=0,a3=0,a4=0,a5=0,a6=0,a7=0;
    float a8=0,a9=0,a10=0,a11=0,a12=0,a13=0,a14=0,a15=0;
    if (lane == 0) {
        a0 = 1.0f;
        a1 = __builtin_amdgcn_exp2f(fmaf(x00, LOG2E, LOG2E));
    }
    int E = 0;

    #define STEP(A0, A1) do { \
        float t1 = __shfl_up(a15, 1); \
        t1 = lane ? t1 : 0.0f; \
        const float f0 = __builtin_amdgcn_exp2f(fmaf((A0).x, fa0, fb0)); \
        const float f1 = __builtin_amdgcn_exp2f(fmaf((A0).y, fa1, fb1)); \
        const float f2 = __builtin_amdgcn_exp2f(fmaf((A0).z, fa2, fb2)); \
        const float f3 = __builtin_amdgcn_exp2f(fmaf((A0).w, fa3, fb3)); \
        const float f4 = __builtin_amdgcn_exp2f(fmaf((A1).x, fa4, fb4)); \
        const float f5 = __builtin_amdgcn_exp2f(fmaf((A1).y, fa5, fb5)); \
        const float f6 = __builtin_amdgcn_exp2f(fmaf((A1).z, fa6, fb6)); \
        const float f7 = __builtin_amdgcn_exp2f(fmaf((A1).w, fa7, fb7)); \
        const float e0 = a0 + t1,   e1 = a2 + a1,   e2 = a4 + a3,   e3 = a6 + a5; \
        const float e4 = a8 + a7,   e5 = a10 + a9,  e6 = a12 + a11, e7 = a14 + a13; \
        const float o0 = a1 + e0,   o1 = a3 + e1,   o2 = a5 + e2,   o3 = a7 + e3; \
        const float o4 = a9 + e4,   o5 = a11 + e5,  o6 = a13 + e6,  o7 = a15 + e7; \
        a0 = e0; a2 = e1; a4 = e2; a6 = e3; a8 = e4; a10 = e5; a12 = e6; a14 = e7; \
        a1 = f0*o0; a3 = f1*o1; a5 = f2*o2; a7 = f3*o3; \
        a9 = f4*o4; a11 = f5*o5; a13 = f6*o6; a15 = f7*o7; \
    } while (0)

    #define RESCALE do { \
        float mx = fmaxf(fmaxf(fmaxf(fmaxf(a0,a1),fmaxf(a2,a3)),fmaxf(fmaxf(a4,a5),fmaxf(a6,a7))), \
                         fmaxf(fmaxf(fmaxf(a8,a9),fmaxf(a10,a11)),fmaxf(fmaxf(a12,a13),fmaxf(a14,a15)))); \
        _Pragma("unroll") \
        for (int off = 32; off; off >>= 1) mx = fmaxf(mx, __shfl_xor(mx, off)); \
        int e = (int)((__float_as_uint(mx) >> 23) & 0xFF) - 127; \
        if (e != 0) { \
            E += e; \
            a0 = ldexpf(a0,-e);  a1 = ldexpf(a1,-e);  a2 = ldexpf(a2,-e);  a3 = ldexpf(a3,-e); \
            a4 = ldexpf(a4,-e);  a5 = ldexpf(a5,-e);  a6 = ldexpf(a6,-e);  a7 = ldexpf(a7,-e); \
            a8 = ldexpf(a8,-e);  a9 = ldexpf(a9,-e);  a10= ldexpf(a10,-e); a11= ldexpf(a11,-e); \
            a12= ldexpf(a12,-e); a13= ldexpf(a13,-e); a14= ldexpf(a14,-e); a15= ldexpf(a15,-e); \
        } \
    } while (0)

    int t = 1;
    while (t + 3 < Tn) {
        int tl;
        STEP(p0a,p0b); tl = (t+4 < T_MAXN) ? t+4 : T_MAXN-1; LOADROW(p0a,p0b,tl);
        STEP(p1a,p1b); tl = (t+5 < T_MAXN) ? t+5 : T_MAXN-1; LOADROW(p1a,p1b,tl);
        STEP(p2a,p2b); tl = (t+6 < T_MAXN) ? t+6 : T_MAXN-1; LOADROW(p2a,p2b,tl);
        STEP(p3a,p3b); tl = (t+7 < T_MAXN) ? t+7 : T_MAXN-1; LOADROW(p3a,p3b,tl);
        if ((t & 7) == 5) RESCALE;
        t += 4;
    }
    if (t < Tn) { STEP(p0a,p0b); ++t; }
    if (t < Tn) { STEP(p1a,p1b); ++t; }
    if (t < Tn) { STEP(p2a,p2b); ++t; }

    afin[16*lane+0]=a0;  afin[16*lane+1]=a1;  afin[16*lane+2]=a2;  afin[16*lane+3]=a3;
    afin[16*lane+4]=a4;  afin[16*lane+5]=a5;  afin[16*lane+6]=a6;  afin[16*lane+7]=a7;
    afin[16*lane+8]=a8;  afin[16*lane+9]=a9;  afin[16*lane+10]=a10; afin[16*lane+11]=a11;
    afin[16*lane+12]=a12; afin[16*lane+13]=a13; afin[16*lane+14]=a14; afin[16*lane+15]=a15;
    __syncthreads();
    if (lane == 0) {
        float tot = afin[2*L] + afin[2*L-1];
        float lossb = 0.0f;
        if (tot > 0.0f) {
            double ll = log((double)tot)
                      + (double)E * 0.69314718055994530942
                      + (double)(-(double)Tn - (double)sl);
            lossb = (float)(-ll / (double)L);
        }
        loss_out[b] = lossb;
    }
    #undef STEP
    #undef RESCALE
    #undef LOADROW
}

// ---------------------------------------------------------------- mean
__global__ void mean_kernel(const float* __restrict__ loss, float* __restrict__ out)
{
    float v = loss[threadIdx.x];   // 64 threads
    #pragma unroll
    for (int off = 32; off; off >>= 1) v += __shfl_xor(v, off);
    if (threadIdx.x == 0) out[0] = v * (1.0f / 64.0f);
}

extern "C" void kernel_launch(void* const* d_in, const int* in_sizes, int n_in,
                              void* d_out, int out_size, void* d_ws, size_t ws_size,
                              hipStream_t stream)
{
    // setup_inputs order: attn (unused), in_lens, out_lens, attn_logprob
    const int*   in_lens  = (const int*)d_in[1];
    const int*   out_lens = (const int*)d_in[2];
    const float* ap       = (const float*)d_in[3];
    float*       out      = (float*)d_out;

    if (ws_size >= WS_NEED) {
        char*     wsb     = (char*)d_ws;
        _Float16* g       = (_Float16*)wsb;
        float*    lse_ws  = (float*)(wsb + LSE_OFF);
        float*    zb      = (float*)(wsb + ZERO_OFF);
        float*    loss_ws = (float*)(wsb + LOSS_OFF);
        hipLaunchKernelGGL(prep_kernel, dim3(32, 64), dim3(256), 0, stream,
                           ap, in_lens, out_lens, lse_ws, g, zb);
        hipLaunchKernelGGL(ctc_scan24_kernel, dim3(64), dim3(64), 0, stream,
                           (const char*)wsb, in_lens, out_lens, loss_ws);
        hipLaunchKernelGGL(mean_kernel, dim3(1), dim3(64), 0, stream, loss_ws, out);
    } else {
        float* lse_ws  = (float*)d_ws;
        float* loss_ws = (float*)((char*)d_ws + (size_t)64 * T_MAXN * 4);
        hipLaunchKernelGGL(lse_kernel, dim3(512), dim3(256), 0, stream,
                           ap, in_lens, lse_ws);
        hipLaunchKernelGGL(ctc_scan_kernel, dim3(64), dim3(64), 0, stream,
                           ap, in_lens, out_lens, lse_ws, loss_ws);
        hipLaunchKernelGGL(mean_kernel, dim3(1), dim3(64), 0, stream, loss_ws, out);
    }
}

// Round 12
// 188.727 us; speedup vs baseline: 5.9040x; 1.0163x over previous
//
#include <hip/hip_runtime.h>
#include <cmath>

// CTC alignment loss (RAD-TTS style), B=64, T<=2000, K<=400, S=2K+1<=801.
//
// Round-11 post-mortem: DPP rescale gained 27 cy/step (174->156us scan), but
// VGPR stayed 88 — the empty memory-clobber did NOT pin the prefetch loads.
// Round-12: loads via real inline-asm global_load_dwordx4 (saddr form) with
// counted s_waitcnt vmcnt(20) + sched_barrier(0) before each consume group
// (T4 pattern; guide rule #18). Asm outputs are structurally live -> 24 rows
// genuinely in flight; VGPR must rise to ~130+. Everything else unchanged.

#define T_MAXN 2000
#define K_MAXN 400

typedef _Float16 half8 __attribute__((ext_vector_type(8)));

// ws layout (fast path)
#define G_BYTES   ((size_t)64 * T_MAXN * K_MAXN * 2)   // 102,400,000
#define LSE_OFF   G_BYTES
#define LSE_BYTES ((size_t)64 * T_MAXN * 4)            // 512,000
#define ZERO_OFF  (LSE_OFF + LSE_BYTES)                // 4KB zero block
#define LOSS_OFF  (ZERO_OFF + 4096)
#define WS_NEED   (LOSS_OFF + 64 * 4)

// lane-1's value (shift wave right by 1), lane 0 -> 0.0f; single VALU op
__device__ __forceinline__ float dpp_wave_shr1(float x)
{
    int r = __builtin_amdgcn_update_dpp(0, (int)__float_as_uint(x),
                                        0x138 /*wave_shr:1*/, 0xF, 0xF, true);
    return __uint_as_float((uint32_t)r);
}

template <int CTRL>
__device__ __forceinline__ float dpp_mov(float x)
{
    int r = __builtin_amdgcn_update_dpp(0, (int)__float_as_uint(x),
                                        CTRL, 0xF, 0xF, true);
    return __uint_as_float((uint32_t)r);
}

// ---------------------------------------------------------- fast path: prep
__global__ __launch_bounds__(256)
void prep_kernel(const float* __restrict__ ap_all,
                 const int* __restrict__ in_lens,
                 const int* __restrict__ out_lens,
                 float* __restrict__ lse_out,
                 _Float16* __restrict__ g_out,
                 float* __restrict__ zerobuf)
{
    const int b    = blockIdx.y;
    const int L    = in_lens[b];
    const int Tn   = out_lens[b];
    const int lane = threadIdx.x & 63;
    const int wid  = blockIdx.x * (blockDim.x >> 6) + (threadIdx.x >> 6);
    const int nw   = gridDim.x * (blockDim.x >> 6);

    if (b == 0 && wid == 0) {                     // 4KB zero block for dead lanes
        for (int i = lane; i < 1024; i += 64) zerobuf[i] = 0.0f;
    }

    const float* base = ap_all + (size_t)b * (T_MAXN * K_MAXN);
    _Float16*    gb   = g_out  + (size_t)b * (T_MAXN * K_MAXN);
    const int c0 = lane * 8;
    const int cb = (c0 < 392) ? c0 : 392;         // clamped (lanes >= 50 fully masked)

    for (int t = wid; t < Tn; t += nw) {
        const float4* p = reinterpret_cast<const float4*>(base + (size_t)t * K_MAXN + cb);
        float4 x0 = p[0], x1 = p[1];
        float v[8] = {x0.x, x0.y, x0.z, x0.w, x1.x, x1.y, x1.z, x1.w};
        float m = -1.0f;                          // blank logit
        #pragma unroll
        for (int j = 0; j < 8; ++j) {
            v[j] = (c0 + j < L) ? v[j] : -1e30f;
            m = fmaxf(m, v[j]);
        }
        #pragma unroll
        for (int off = 32; off; off >>= 1) m = fmaxf(m, __shfl_xor(m, off));
        float s = (lane == 0) ? __expf(-1.0f - m) : 0.0f;
        #pragma unroll
        for (int j = 0; j < 8; ++j) s += __expf(v[j] - m);
        #pragma unroll
        for (int off = 32; off; off >>= 1) s += __shfl_xor(s, off);
        if (lane == 0) lse_out[b * T_MAXN + t] = m + __logf(s);

        half8 h;
        #pragma unroll
        for (int j = 0; j < 8; ++j) h[j] = (_Float16)__expf(v[j] + 1.0f);  // masked -> 0
        if (c0 < K_MAXN)
            *reinterpret_cast<half8*>(gb + (size_t)t * K_MAXN + c0) = h;
    }
}

// ---------------------------------------------------------- fast path: scan
__global__ __launch_bounds__(64, 1)
void ctc_scan24_kernel(const char* wsro,
                       const int* __restrict__ in_lens,
                       const int* __restrict__ out_lens,
                       float* loss_out)
{
    __shared__ float afin[1024];

    const int b    = blockIdx.x;
    const int lane = threadIdx.x;
    const int L    = in_lens[b];      // [200,400]
    const int Tn   = out_lens[b];     // [1000,2000]
    const uint32_t goff = (uint32_t)b * (uint32_t)(T_MAXN * K_MAXN * 2);
    const float* lse = (const float*)(wsro + LSE_OFF) + b * T_MAXN;

    // uniform SGPR base + 32-bit rolling voffset; dead lanes park on zero block
    uint32_t off, inc4;
    if (lane < 50) { off = goff + (uint32_t)lane * 16u + 800u; inc4 = 3200u; }
    else           { off = (uint32_t)ZERO_OFF;                  inc4 = 0u;    }

    // prologue: sl = sum_{t<Tn} lse[t]
    float sl = 0.0f;
    for (int t = lane; t < Tn; t += 64) sl += lse[t];
    #pragma unroll
    for (int o = 32; o; o >>= 1) sl += __shfl_xor(sl, o);

    // init t=0 (blank-normalized): alpha^[0]=1, alpha^[1]=g[0][0]
    float a0=0,a1=0,a2=0,a3=0,a4=0,a5=0,a6=0,a7=0;
    float a8=0,a9=0,a10=0,a11=0,a12=0,a13=0,a14=0,a15=0;
    if (lane == 0) {
        a0 = 1.0f;
        a1 = (float)*reinterpret_cast<const _Float16*>(wsro + goff);
    }
    int   E  = 0;
    float t1 = 0.0f;    // boundary: lane-1's a15 from previous step (via DPP)
    float rm = 0.0f;    // pipelined rescale max (all lanes >= 0)

    // 4 pinned loads per group: asm volatile cannot be sunk; outputs live
    // until use -> true 24-row in-flight window. saddr form: 32-bit voffset.
    #define LOADG4(QA, QB, QC, QD) do { \
        asm volatile("global_load_dwordx4 %0, %1, %2 offset:0"    : "=v"(QA) : "v"(off), "s"(wsro)); \
        asm volatile("global_load_dwordx4 %0, %1, %2 offset:800"  : "=v"(QB) : "v"(off), "s"(wsro)); \
        asm volatile("global_load_dwordx4 %0, %1, %2 offset:1600" : "=v"(QC) : "v"(off), "s"(wsro)); \
        asm volatile("global_load_dwordx4 %0, %1, %2 offset:2400" : "=v"(QD) : "v"(off), "s"(wsro)); \
        off += inc4; \
    } while (0)

    // counted-vmcnt wait: oldest 4 of 24 outstanding complete; sched_barrier
    // stops hipcc hoisting register-only consumers above it (rule #18).
    #define WAITG20 do { \
        asm volatile("s_waitcnt vmcnt(20)" ::: "memory"); \
        __builtin_amdgcn_sched_barrier(0); \
    } while (0)
    #define WAITG0 do { \
        asm volatile("s_waitcnt vmcnt(0)" ::: "memory"); \
        __builtin_amdgcn_sched_barrier(0); \
    } while (0)

    half8 q0,q1,q2,q3,q4,q5,q6,q7,q8,q9,q10,q11;
    half8 q12,q13,q14,q15,q16,q17,q18,q19,q20,q21,q22,q23;
    LOADG4(q0,q1,q2,q3);     LOADG4(q4,q5,q6,q7);     LOADG4(q8,q9,q10,q11);
    LOADG4(q12,q13,q14,q15); LOADG4(q16,q17,q18,q19); LOADG4(q20,q21,q22,q23);

    // even s=2j: new = old[2j]+old[2j-1];  odd: new = g*(old[2j+1]+new_even)
    #define STEPF(Q) do { \
        const float f0 = (float)(Q)[0], f1 = (float)(Q)[1], f2 = (float)(Q)[2], f3 = (float)(Q)[3]; \
        const float f4 = (float)(Q)[4], f5 = (float)(Q)[5], f6 = (float)(Q)[6], f7 = (float)(Q)[7]; \
        const float e0 = a0 + t1,  e1 = a2 + a1,   e2 = a4 + a3,   e3 = a6 + a5; \
        const float e4 = a8 + a7,  e5 = a10 + a9,  e6 = a12 + a11, e7 = a14 + a13; \
        const float o0 = a1 + e0,  o1 = a3 + e1,   o2 = a5 + e2,   o3 = a7 + e3; \
        const float o4 = a9 + e4,  o5 = a11 + e5,  o6 = a13 + e6,  o7 = a15 + e7; \
        a0 = e0; a2 = e1; a4 = e2; a6 = e3; a8 = e4; a10 = e5; a12 = e6; a14 = e7; \
        a1 = f0*o0; a3 = f1*o1; a5 = f2*o2; a7 = f3*o3; \
        a9 = f4*o4; a11 = f5*o5; a13 = f6*o6; a15 = f7*o7; \
        t1 = dpp_wave_shr1(a15); \
    } while (0)

    // pipelined rescale: lane-tree max at ph0; one DPP combine per phase
    // (row_shr 1/2/4/8 then row_bcast15/31 -> lane 63 holds wave max);
    // bound_ctrl zero-fill is identity for max of non-negatives. Wave max is
    // monotone non-decreasing in the blank-normalized domain -> stale-safe.
    #define PH0 do { \
        float m01 = fmaxf(a0,a1),  m23 = fmaxf(a2,a3),   m45 = fmaxf(a4,a5),   m67 = fmaxf(a6,a7); \
        float m89 = fmaxf(a8,a9),  mab = fmaxf(a10,a11), mcd = fmaxf(a12,a13), mef = fmaxf(a14,a15); \
        float mA = fmaxf(m01,m23), mB = fmaxf(m45,m67),  mC = fmaxf(m89,mab),  mD = fmaxf(mcd,mef); \
        rm = fmaxf(fmaxf(mA,mB), fmaxf(mC,mD)); \
    } while (0)
    #define PHD(CTRL) rm = fmaxf(rm, dpp_mov<CTRL>(rm))
    #define PH7 do { \
        float rmu = __uint_as_float((uint32_t)__builtin_amdgcn_readlane((int)__float_as_uint(rm), 63)); \
        int e = (int)((__float_as_uint(rmu) >> 23) & 0xFF) - 127; \
        E += e; \
        const float sc = __uint_as_float((uint32_t)(127 - e) << 23);  /* 2^-e exact */ \
        a0*=sc; a1*=sc; a2*=sc;  a3*=sc;  a4*=sc;  a5*=sc;  a6*=sc;  a7*=sc; \
        a8*=sc; a9*=sc; a10*=sc; a11*=sc; a12*=sc; a13*=sc; a14*=sc; a15*=sc; \
        t1 *= sc; \
    } while (0)
    #define RESCDEP do { \
        PH0; \
        PHD(0x111); PHD(0x112); PHD(0x114); PHD(0x118); \
        PHD(0x142); PHD(0x143); \
        PH7; \
    } while (0)

    int t = 1;
    while (t + 23 < Tn) {
        WAITG20;
        STEPF(q0);  PH0;
        STEPF(q1);  PHD(0x111);
        STEPF(q2);  PHD(0x112);
        STEPF(q3);  PHD(0x114);
        LOADG4(q0,q1,q2,q3);
        WAITG20;
        STEPF(q4);  PHD(0x118);
        STEPF(q5);  PHD(0x142);
        STEPF(q6);  PHD(0x143);
        STEPF(q7);  PH7;
        LOADG4(q4,q5,q6,q7);
        WAITG20;
        STEPF(q8);  PH0;
        STEPF(q9);  PHD(0x111);
        STEPF(q10); PHD(0x112);
        STEPF(q11); PHD(0x114);
        LOADG4(q8,q9,q10,q11);
        WAITG20;
        STEPF(q12); PHD(0x118);
        STEPF(q13); PHD(0x142);
        STEPF(q14); PHD(0x143);
        STEPF(q15); PH7;
        LOADG4(q12,q13,q14,q15);
        WAITG20;
        STEPF(q16); PH0;
        STEPF(q17); PHD(0x111);
        STEPF(q18); PHD(0x112);
        STEPF(q19); PHD(0x114);
        LOADG4(q16,q17,q18,q19);
        WAITG20;
        STEPF(q20); PHD(0x118);
        STEPF(q21); PHD(0x142);
        STEPF(q22); PHD(0x143);
        STEPF(q23); PH7;
        LOADG4(q20,q21,q22,q23);
        t += 24;
    }
    WAITG0;
    {
        const int r = Tn - t;   // 0..23; q_i holds row t+i
        if (r > 0)  STEPF(q0);
        if (r > 1)  STEPF(q1);
        if (r > 2)  STEPF(q2);
        if (r > 3)  STEPF(q3);
        if (r > 4)  STEPF(q4);
        if (r > 5)  STEPF(q5);
        if (r > 6)  STEPF(q6);
        if (r > 7)  STEPF(q7);
        if (r > 8)  { RESCDEP; STEPF(q8); }
        if (r > 9)  STEPF(q9);
        if (r > 10) STEPF(q10);
        if (r > 11) STEPF(q11);
        if (r > 12) STEPF(q12);
        if (r > 13) STEPF(q13);
        if (r > 14) STEPF(q14);
        if (r > 15) STEPF(q15);
        if (r > 16) { RESCDEP; STEPF(q16); }
        if (r > 17) STEPF(q17);
        if (r > 18) STEPF(q18);
        if (r > 19) STEPF(q19);
        if (r > 20) STEPF(q20);
        if (r > 21) STEPF(q21);
        if (r > 22) STEPF(q22);
    }

    afin[16*lane+0]=a0;   afin[16*lane+1]=a1;   afin[16*lane+2]=a2;   afin[16*lane+3]=a3;
    afin[16*lane+4]=a4;   afin[16*lane+5]=a5;   afin[16*lane+6]=a6;   afin[16*lane+7]=a7;
    afin[16*lane+8]=a8;   afin[16*lane+9]=a9;   afin[16*lane+10]=a10; afin[16*lane+11]=a11;
    afin[16*lane+12]=a12; afin[16*lane+13]=a13; afin[16*lane+14]=a14; afin[16*lane+15]=a15;
    __syncthreads();
    if (lane == 0) {
        float tot = afin[2*L] + afin[2*L-1];
        float lossb = 0.0f;
        if (tot > 0.0f) {
            double ll = log((double)tot)
                      + (double)E * 0.69314718055994530942
                      + (double)(-(double)Tn - (double)sl);
            lossb = (float)(-ll / (double)L);
        }
        loss_out[b] = lossb;
    }
    #undef STEPF
    #undef PH0
    #undef PHD
    #undef PH7
    #undef RESCDEP
    #undef LOADG4
    #undef WAITG20
    #undef WAITG0
}

// ------------------------------------------------- fallback (round-3, proven)
__global__ __launch_bounds__(256)
void lse_kernel(const float* __restrict__ ap_all,
                const int* __restrict__ in_lens,
                float* __restrict__ lse_out)
{
    const int lane = threadIdx.x & 63;
    const int wglob = blockIdx.x * (blockDim.x >> 6) + (threadIdx.x >> 6);
    const int nwav = gridDim.x * (blockDim.x >> 6);
    const int nrows = 64 * T_MAXN;

    for (int row = wglob; row < nrows; row += nwav) {
        const int b = row / T_MAXN;
        const int L = in_lens[b];
        const float* rp = ap_all + (size_t)row * K_MAXN;
        const int c0 = lane * 8;
        const int cb = (c0 < 392) ? c0 : 392;
        const float4* p = reinterpret_cast<const float4*>(rp + cb);
        float4 x0 = p[0], x1 = p[1];
        float v[8] = {x0.x, x0.y, x0.z, x0.w, x1.x, x1.y, x1.z, x1.w};
        float m = -1.0f;
        #pragma unroll
        for (int j = 0; j < 8; ++j) {
            v[j] = (c0 + j < L) ? v[j] : -1e30f;
            m = fmaxf(m, v[j]);
        }
        #pragma unroll
        for (int off = 32; off; off >>= 1) m = fmaxf(m, __shfl_xor(m, off));
        float s = (lane == 0) ? __expf(-1.0f - m) : 0.0f;
        #pragma unroll
        for (int j = 0; j < 8; ++j) s += __expf(v[j] - m);
        #pragma unroll
        for (int off = 32; off; off >>= 1) s += __shfl_xor(s, off);
        if (lane == 0) lse_out[row] = m + __logf(s);
    }
}

__global__ __launch_bounds__(64)
void ctc_scan_kernel(const float* __restrict__ ap_all,
                     const int* __restrict__ in_lens,
                     const int* __restrict__ out_lens,
                     const float* __restrict__ lse_all,
                     float* __restrict__ loss_out)
{
    __shared__ float afin[1024];

    const int b    = blockIdx.x;
    const int lane = threadIdx.x;
    const int L    = in_lens[b];
    const int Tn   = out_lens[b];
    const float* ap  = ap_all + (size_t)b * (T_MAXN * K_MAXN);
    const float* lse = lse_all + b * T_MAXN;

    const float LOG2E = 1.4426950408889634f;
    const int c0 = lane * 8;
    const int cb = (c0 < 392) ? c0 : 392;
    const float* rbase = ap + cb;
    float fa0,fa1,fa2,fa3,fa4,fa5,fa6,fa7;
    float fb0,fb1,fb2,fb3,fb4,fb5,fb6,fb7;
    #define MASKC(J, FA, FB) do { bool ok = (c0 + (J)) < L; \
        FA = ok ? LOG2E : 0.0f; FB = ok ? LOG2E : -1000.0f; } while (0)
    MASKC(0,fa0,fb0); MASKC(1,fa1,fb1); MASKC(2,fa2,fb2); MASKC(3,fa3,fb3);
    MASKC(4,fa4,fb4); MASKC(5,fa5,fb5); MASKC(6,fa6,fb6); MASKC(7,fa7,fb7);
    #undef MASKC

    float4 p0a,p0b,p1a,p1b,p2a,p2b,p3a,p3b;
    #define LOADROW(PA, PB, T) do { \
        const float4* _p = reinterpret_cast<const float4*>(rbase + (size_t)(T) * K_MAXN); \
        PA = _p[0]; PB = _p[1]; } while (0)
    LOADROW(p0a,p0b,1); LOADROW(p1a,p1b,2); LOADROW(p2a,p2b,3); LOADROW(p3a,p3b,4);

    float sl = 0.0f;
    for (int t = lane; t < Tn; t += 64) sl += lse[t];
    #pragma unroll
    for (int off = 32; off; off >>= 1) sl += __shfl_xor(sl, off);

    float x00 = ap[0];
    float a0=0,a1=0,a2=0,a3=0,a4=0,a5=0,a6=0,a7=0;
    float a8=0,a9=0,a10=0,a11=0,a12=0,a13=0,a14=0,a15=0;
    if (lane == 0) {
        a0 = 1.0f;
        a1 = __builtin_amdgcn_exp2f(fmaf(x00, LOG2E, LOG2E));
    }
    int E = 0;

    #define STEP(A0, A1) do { \
        float t1 = __shfl_up(a15, 1); \
        t1 = lane ? t1 : 0.0f; \
        const float f0 = __builtin_amdgcn_exp2f(fmaf((A0).x, fa0, fb0)); \
        const float f1 = __builtin_amdgcn_exp2f(fmaf((A0).y, fa1, fb1)); \
        const float f2 = __builtin_amdgcn_exp2f(fmaf((A0).z, fa2, fb2)); \
        const float f3 = __builtin_amdgcn_exp2f(fmaf((A0).w, fa3, fb3)); \
        const float f4 = __builtin_amdgcn_exp2f(fmaf((A1).x, fa4, fb4)); \
        const float f5 = __builtin_amdgcn_exp2f(fmaf((A1).y, fa5, fb5)); \
        const float f6 = __builtin_amdgcn_exp2f(fmaf((A1).z, fa6, fb6)); \
        const float f7 = __builtin_amdgcn_exp2f(fmaf((A1).w, fa7, fb7)); \
        const float e0 = a0 + t1,   e1 = a2 + a1,   e2 = a4 + a3,   e3 = a6 + a5; \
        const float e4 = a8 + a7,   e5 = a10 + a9,  e6 = a12 + a11, e7 = a14 + a13; \
        const float o0 = a1 + e0,   o1 = a3 + e1,   o2 = a5 + e2,   o3 = a7 + e3; \
        const float o4 = a9 + e4,   o5 = a11 + e5,  o6 = a13 + e6,  o7 = a15 + e7; \
        a0 = e0; a2 = e1; a4 = e2; a6 = e3; a8 = e4; a10 = e5; a12 = e6; a14 = e7; \
        a1 = f0*o0; a3 = f1*o1; a5 = f2*o2; a7 = f3*o3; \
        a9 = f4*o4; a11 = f5*o5; a13 = f6*o6; a15 = f7*o7; \
    } while (0)

    #define RESCALE do { \
        float mx = fmaxf(fmaxf(fmaxf(fmaxf(a0,a1),fmaxf(a2,a3)),fmaxf(fmaxf(a4,a5),fmaxf(a6,a7))), \
                         fmaxf(fmaxf(fmaxf(a8,a9),fmaxf(a10,a11)),fmaxf(fmaxf(a12,a13),fmaxf(a14,a15)))); \
        _Pragma("unroll") \
        for (int off = 32; off; off >>= 1) mx = fmaxf(mx, __shfl_xor(mx, off)); \
        int e = (int)((__float_as_uint(mx) >> 23) & 0xFF) - 127; \
        if (e != 0) { \
            E += e; \
            a0 = ldexpf(a0,-e);  a1 = ldexpf(a1,-e);  a2 = ldexpf(a2,-e);  a3 = ldexpf(a3,-e); \
            a4 = ldexpf(a4,-e);  a5 = ldexpf(a5,-e);  a6 = ldexpf(a6,-e);  a7 = ldexpf(a7,-e); \
            a8 = ldexpf(a8,-e);  a9 = ldexpf(a9,-e);  a10= ldexpf(a10,-e); a11= ldexpf(a11,-e); \
            a12= ldexpf(a12,-e); a13= ldexpf(a13,-e); a14= ldexpf(a14,-e); a15= ldexpf(a15,-e); \
        } \
    } while (0)

    int t = 1;
    while (t + 3 < Tn) {
        int tl;
        STEP(p0a,p0b); tl = (t+4 < T_MAXN) ? t+4 : T_MAXN-1; LOADROW(p0a,p0b,tl);
        STEP(p1a,p1b); tl = (t+5 < T_MAXN) ? t+5 : T_MAXN-1; LOADROW(p1a,p1b,tl);
        STEP(p2a,p2b); tl = (t+6 < T_MAXN) ? t+6 : T_MAXN-1; LOADROW(p2a,p2b,tl);
        STEP(p3a,p3b); tl = (t+7 < T_MAXN) ? t+7 : T_MAXN-1; LOADROW(p3a,p3b,tl);
        if ((t & 7) == 5) RESCALE;
        t += 4;
    }
    if (t < Tn) { STEP(p0a,p0b); ++t; }
    if (t < Tn) { STEP(p1a,p1b); ++t; }
    if (t < Tn) { STEP(p2a,p2b); ++t; }

    afin[16*lane+0]=a0;  afin[16*lane+1]=a1;  afin[16*lane+2]=a2;  afin[16*lane+3]=a3;
    afin[16*lane+4]=a4;  afin[16*lane+5]=a5;  afin[16*lane+6]=a6;  afin[16*lane+7]=a7;
    afin[16*lane+8]=a8;  afin[16*lane+9]=a9;  afin[16*lane+10]=a10; afin[16*lane+11]=a11;
    afin[16*lane+12]=a12; afin[16*lane+13]=a13; afin[16*lane+14]=a14; afin[16*lane+15]=a15;
    __syncthreads();
    if (lane == 0) {
        float tot = afin[2*L] + afin[2*L-1];
        float lossb = 0.0f;
        if (tot > 0.0f) {
            double ll = log((double)tot)
                      + (double)E * 0.69314718055994530942
                      + (double)(-(double)Tn - (double)sl);
            lossb = (float)(-ll / (double)L);
        }
        loss_out[b] = lossb;
    }
    #undef STEP
    #undef RESCALE
    #undef LOADROW
}

// ---------------------------------------------------------------- mean
__global__ void mean_kernel(const float* __restrict__ loss, float* __restrict__ out)
{
    float v = loss[threadIdx.x];   // 64 threads
    #pragma unroll
    for (int off = 32; off; off >>= 1) v += __shfl_xor(v, off);
    if (threadIdx.x == 0) out[0] = v * (1.0f / 64.0f);
}

extern "C" void kernel_launch(void* const* d_in, const int* in_sizes, int n_in,
                              void* d_out, int out_size, void* d_ws, size_t ws_size,
                              hipStream_t stream)
{
    // setup_inputs order: attn (unused), in_lens, out_lens, attn_logprob
    const int*   in_lens  = (const int*)d_in[1];
    const int*   out_lens = (const int*)d_in[2];
    const float* ap       = (const float*)d_in[3];
    float*       out      = (float*)d_out;

    if (ws_size >= WS_NEED) {
        char*     wsb     = (char*)d_ws;
        _Float16* g       = (_Float16*)wsb;
        float*    lse_ws  = (float*)(wsb + LSE_OFF);
        float*    zb      = (float*)(wsb + ZERO_OFF);
        float*    loss_ws = (float*)(wsb + LOSS_OFF);
        hipLaunchKernelGGL(prep_kernel, dim3(32, 64), dim3(256), 0, stream,
                           ap, in_lens, out_lens, lse_ws, g, zb);
        hipLaunchKernelGGL(ctc_scan24_kernel, dim3(64), dim3(64), 0, stream,
                           (const char*)wsb, in_lens, out_lens, loss_ws);
        hipLaunchKernelGGL(mean_kernel, dim3(1), dim3(64), 0, stream, loss_ws, out);
    } else {
        float* lse_ws  = (float*)d_ws;
        float* loss_ws = (float*)((char*)d_ws + (size_t)64 * T_MAXN * 4);
        hipLaunchKernelGGL(lse_kernel, dim3(512), dim3(256), 0, stream,
                           ap, in_lens, lse_ws);
        hipLaunchKernelGGL(ctc_scan_kernel, dim3(64), dim3(64), 0, stream,
                           ap, in_lens, out_lens, lse_ws, loss_ws);
        hipLaunchKernelGGL(mean_kernel, dim3(1), dim3(64), 0, stream, loss_ws, out);
    }
}

// Round 13
// 156.043 us; speedup vs baseline: 7.1407x; 1.2095x over previous
//
#include <hip/hip_runtime.h>
#include <cmath>

// CTC alignment loss (RAD-TTS style), B=64, T<=2000, K<=400, S=2K+1<=801.
//
// Round-12 post-mortem: loads pinned (VGPR 88->128) but time unchanged ->
// NOT latency-bound. 184 cy/step with ~45 VALU ops matches a single-wave
// issue cadence of 1 instr / 4 cy => instruction-count bound.
// Round-13: v_fma_mix_f32 (inline asm) consumes f16 factors directly from
// the loaded dwords: 8 cvt + 8 mul -> 8 fma_mix per step (~45 -> ~33 ops).
// Bit-identical numerics. Everything else unchanged from round 12.

#define T_MAXN 2000
#define K_MAXN 400

typedef uint32_t uint4v __attribute__((ext_vector_type(4)));

// ws layout (fast path)
#define G_BYTES   ((size_t)64 * T_MAXN * K_MAXN * 2)   // 102,400,000
#define LSE_OFF   G_BYTES
#define LSE_BYTES ((size_t)64 * T_MAXN * 4)            // 512,000
#define ZERO_OFF  (LSE_OFF + LSE_BYTES)                // 4KB zero block
#define LOSS_OFF  (ZERO_OFF + 4096)
#define WS_NEED   (LOSS_OFF + 64 * 4)

// lane-1's value (shift wave right by 1), lane 0 -> 0.0f; single VALU op
__device__ __forceinline__ float dpp_wave_shr1(float x)
{
    int r = __builtin_amdgcn_update_dpp(0, (int)__float_as_uint(x),
                                        0x138 /*wave_shr:1*/, 0xF, 0xF, true);
    return __uint_as_float((uint32_t)r);
}

template <int CTRL>
__device__ __forceinline__ float dpp_mov(float x)
{
    int r = __builtin_amdgcn_update_dpp(0, (int)__float_as_uint(x),
                                        CTRL, 0xF, 0xF, true);
    return __uint_as_float((uint32_t)r);
}

// ---------------------------------------------------------- fast path: prep
__global__ __launch_bounds__(256)
void prep_kernel(const float* __restrict__ ap_all,
                 const int* __restrict__ in_lens,
                 const int* __restrict__ out_lens,
                 float* __restrict__ lse_out,
                 _Float16* __restrict__ g_out,
                 float* __restrict__ zerobuf)
{
    const int b    = blockIdx.y;
    const int L    = in_lens[b];
    const int Tn   = out_lens[b];
    const int lane = threadIdx.x & 63;
    const int wid  = blockIdx.x * (blockDim.x >> 6) + (threadIdx.x >> 6);
    const int nw   = gridDim.x * (blockDim.x >> 6);

    if (b == 0 && wid == 0) {                     // 4KB zero block for dead lanes
        for (int i = lane; i < 1024; i += 64) zerobuf[i] = 0.0f;
    }

    const float* base = ap_all + (size_t)b * (T_MAXN * K_MAXN);
    _Float16*    gb   = g_out  + (size_t)b * (T_MAXN * K_MAXN);
    const int c0 = lane * 8;
    const int cb = (c0 < 392) ? c0 : 392;         // clamped (lanes >= 50 fully masked)

    for (int t = wid; t < Tn; t += nw) {
        const float4* p = reinterpret_cast<const float4*>(base + (size_t)t * K_MAXN + cb);
        float4 x0 = p[0], x1 = p[1];
        float v[8] = {x0.x, x0.y, x0.z, x0.w, x1.x, x1.y, x1.z, x1.w};
        float m = -1.0f;                          // blank logit
        #pragma unroll
        for (int j = 0; j < 8; ++j) {
            v[j] = (c0 + j < L) ? v[j] : -1e30f;
            m = fmaxf(m, v[j]);
        }
        #pragma unroll
        for (int off = 32; off; off >>= 1) m = fmaxf(m, __shfl_xor(m, off));
        float s = (lane == 0) ? __expf(-1.0f - m) : 0.0f;
        #pragma unroll
        for (int j = 0; j < 8; ++j) s += __expf(v[j] - m);
        #pragma unroll
        for (int off = 32; off; off >>= 1) s += __shfl_xor(s, off);
        if (lane == 0) lse_out[b * T_MAXN + t] = m + __logf(s);

        _Float16 h[8];
        #pragma unroll
        for (int j = 0; j < 8; ++j) h[j] = (_Float16)__expf(v[j] + 1.0f);  // masked -> 0
        if (c0 < K_MAXN)
            *reinterpret_cast<uint4v*>(gb + (size_t)t * K_MAXN + c0) =
                *reinterpret_cast<const uint4v*>(h);
    }
}

// ---------------------------------------------------------- fast path: scan
__global__ __launch_bounds__(64, 1)
void ctc_scan24_kernel(const char* wsro,
                       const int* __restrict__ in_lens,
                       const int* __restrict__ out_lens,
                       float* loss_out)
{
    __shared__ float afin[1024];

    const int b    = blockIdx.x;
    const int lane = threadIdx.x;
    const int L    = in_lens[b];      // [200,400]
    const int Tn   = out_lens[b];     // [1000,2000]
    const uint32_t goff = (uint32_t)b * (uint32_t)(T_MAXN * K_MAXN * 2);
    const float* lse = (const float*)(wsro + LSE_OFF) + b * T_MAXN;

    // uniform SGPR base + 32-bit rolling voffset; dead lanes park on zero block
    uint32_t off, inc4;
    if (lane < 50) { off = goff + (uint32_t)lane * 16u + 800u; inc4 = 3200u; }
    else           { off = (uint32_t)ZERO_OFF;                  inc4 = 0u;    }

    // prologue: sl = sum_{t<Tn} lse[t]
    float sl = 0.0f;
    for (int t = lane; t < Tn; t += 64) sl += lse[t];
    #pragma unroll
    for (int o = 32; o; o >>= 1) sl += __shfl_xor(sl, o);

    // init t=0 (blank-normalized): alpha^[0]=1, alpha^[1]=g[0][0]
    float a0=0,a1=0,a2=0,a3=0,a4=0,a5=0,a6=0,a7=0;
    float a8=0,a9=0,a10=0,a11=0,a12=0,a13=0,a14=0,a15=0;
    if (lane == 0) {
        a0 = 1.0f;
        a1 = (float)*reinterpret_cast<const _Float16*>(wsro + goff);
    }
    int   E  = 0;
    float t1 = 0.0f;    // boundary: lane-1's a15 from previous step (via DPP)
    float rm = 0.0f;    // pipelined rescale max (all lanes >= 0)

    // 4 pinned loads per group: asm volatile cannot be sunk; outputs live
    // until use -> true 24-row in-flight window. saddr form: 32-bit voffset.
    #define LOADG4(QA, QB, QC, QD) do { \
        asm volatile("global_load_dwordx4 %0, %1, %2 offset:0"    : "=v"(QA) : "v"(off), "s"(wsro)); \
        asm volatile("global_load_dwordx4 %0, %1, %2 offset:800"  : "=v"(QB) : "v"(off), "s"(wsro)); \
        asm volatile("global_load_dwordx4 %0, %1, %2 offset:1600" : "=v"(QC) : "v"(off), "s"(wsro)); \
        asm volatile("global_load_dwordx4 %0, %1, %2 offset:2400" : "=v"(QD) : "v"(off), "s"(wsro)); \
        off += inc4; \
    } while (0)

    // counted-vmcnt wait: oldest 4 of 24 outstanding complete; sched_barrier
    // stops hipcc hoisting register-only consumers above it (rule #18).
    #define WAITG20 do { \
        asm volatile("s_waitcnt vmcnt(20)" ::: "memory"); \
        __builtin_amdgcn_sched_barrier(0); \
    } while (0)
    #define WAITG0 do { \
        asm volatile("s_waitcnt vmcnt(0)" ::: "memory"); \
        __builtin_amdgcn_sched_barrier(0); \
    } while (0)

    uint4v q0,q1,q2,q3,q4,q5,q6,q7,q8,q9,q10,q11;
    uint4v q12,q13,q14,q15,q16,q17,q18,q19,q20,q21,q22,q23;
    LOADG4(q0,q1,q2,q3);     LOADG4(q4,q5,q6,q7);     LOADG4(q8,q9,q10,q11);
    LOADG4(q12,q13,q14,q15); LOADG4(q16,q17,q18,q19); LOADG4(q20,q21,q22,q23);

    // f16 factor consumed directly: a = f(f16)*o + 0 via v_fma_mix_f32.
    // op_sel_hi[0]=1 -> src0 is f16; op_sel[0] picks lo/hi half of the dword.
    #define FMIXLO(DST, SRC, O) \
        asm("v_fma_mix_f32 %0, %1, %2, 0 op_sel:[0,0,0] op_sel_hi:[1,0,0]" \
            : "=v"(DST) : "v"(SRC), "v"(O))
    #define FMIXHI(DST, SRC, O) \
        asm("v_fma_mix_f32 %0, %1, %2, 0 op_sel:[1,0,0] op_sel_hi:[1,0,0]" \
            : "=v"(DST) : "v"(SRC), "v"(O))

    // even s=2j: new = old[2j]+old[2j-1];  odd: new = g*(old[2j+1]+new_even)
    #define STEPF(Q) do { \
        const float e0 = a0 + t1,  e1 = a2 + a1,   e2 = a4 + a3,   e3 = a6 + a5; \
        const float e4 = a8 + a7,  e5 = a10 + a9,  e6 = a12 + a11, e7 = a14 + a13; \
        const float o0 = a1 + e0,  o1 = a3 + e1,   o2 = a5 + e2,   o3 = a7 + e3; \
        const float o4 = a9 + e4,  o5 = a11 + e5,  o6 = a13 + e6,  o7 = a15 + e7; \
        a0 = e0; a2 = e1; a4 = e2; a6 = e3; a8 = e4; a10 = e5; a12 = e6; a14 = e7; \
        FMIXLO(a1,  (Q).x, o0); FMIXHI(a3,  (Q).x, o1); \
        FMIXLO(a5,  (Q).y, o2); FMIXHI(a7,  (Q).y, o3); \
        FMIXLO(a9,  (Q).z, o4); FMIXHI(a11, (Q).z, o5); \
        FMIXLO(a13, (Q).w, o6); FMIXHI(a15, (Q).w, o7); \
        t1 = dpp_wave_shr1(a15); \
    } while (0)

    // pipelined rescale: lane-tree max at ph0; one DPP combine per phase
    // (row_shr 1/2/4/8 then row_bcast15/31 -> lane 63 holds wave max);
    // bound_ctrl zero-fill is identity for max of non-negatives. Wave max is
    // monotone non-decreasing in the blank-normalized domain -> stale-safe.
    #define PH0 do { \
        float m01 = fmaxf(a0,a1),  m23 = fmaxf(a2,a3),   m45 = fmaxf(a4,a5),   m67 = fmaxf(a6,a7); \
        float m89 = fmaxf(a8,a9),  mab = fmaxf(a10,a11), mcd = fmaxf(a12,a13), mef = fmaxf(a14,a15); \
        float mA = fmaxf(m01,m23), mB = fmaxf(m45,m67),  mC = fmaxf(m89,mab),  mD = fmaxf(mcd,mef); \
        rm = fmaxf(fmaxf(mA,mB), fmaxf(mC,mD)); \
    } while (0)
    #define PHD(CTRL) rm = fmaxf(rm, dpp_mov<CTRL>(rm))
    #define PH7 do { \
        float rmu = __uint_as_float((uint32_t)__builtin_amdgcn_readlane((int)__float_as_uint(rm), 63)); \
        int e = (int)((__float_as_uint(rmu) >> 23) & 0xFF) - 127; \
        E += e; \
        const float sc = __uint_as_float((uint32_t)(127 - e) << 23);  /* 2^-e exact */ \
        a0*=sc; a1*=sc; a2*=sc;  a3*=sc;  a4*=sc;  a5*=sc;  a6*=sc;  a7*=sc; \
        a8*=sc; a9*=sc; a10*=sc; a11*=sc; a12*=sc; a13*=sc; a14*=sc; a15*=sc; \
        t1 *= sc; \
    } while (0)
    #define RESCDEP do { \
        PH0; \
        PHD(0x111); PHD(0x112); PHD(0x114); PHD(0x118); \
        PHD(0x142); PHD(0x143); \
        PH7; \
    } while (0)

    int t = 1;
    while (t + 23 < Tn) {
        WAITG20;
        STEPF(q0);  PH0;
        STEPF(q1);  PHD(0x111);
        STEPF(q2);  PHD(0x112);
        STEPF(q3);  PHD(0x114);
        LOADG4(q0,q1,q2,q3);
        WAITG20;
        STEPF(q4);  PHD(0x118);
        STEPF(q5);  PHD(0x142);
        STEPF(q6);  PHD(0x143);
        STEPF(q7);  PH7;
        LOADG4(q4,q5,q6,q7);
        WAITG20;
        STEPF(q8);  PH0;
        STEPF(q9);  PHD(0x111);
        STEPF(q10); PHD(0x112);
        STEPF(q11); PHD(0x114);
        LOADG4(q8,q9,q10,q11);
        WAITG20;
        STEPF(q12); PHD(0x118);
        STEPF(q13); PHD(0x142);
        STEPF(q14); PHD(0x143);
        STEPF(q15); PH7;
        LOADG4(q12,q13,q14,q15);
        WAITG20;
        STEPF(q16); PH0;
        STEPF(q17); PHD(0x111);
        STEPF(q18); PHD(0x112);
        STEPF(q19); PHD(0x114);
        LOADG4(q16,q17,q18,q19);
        WAITG20;
        STEPF(q20); PHD(0x118);
        STEPF(q21); PHD(0x142);
        STEPF(q22); PHD(0x143);
        STEPF(q23); PH7;
        LOADG4(q20,q21,q22,q23);
        t += 24;
    }
    WAITG0;
    {
        const int r = Tn - t;   // 0..23; q_i holds row t+i
        if (r > 0)  STEPF(q0);
        if (r > 1)  STEPF(q1);
        if (r > 2)  STEPF(q2);
        if (r > 3)  STEPF(q3);
        if (r > 4)  STEPF(q4);
        if (r > 5)  STEPF(q5);
        if (r > 6)  STEPF(q6);
        if (r > 7)  STEPF(q7);
        if (r > 8)  { RESCDEP; STEPF(q8); }
        if (r > 9)  STEPF(q9);
        if (r > 10) STEPF(q10);
        if (r > 11) STEPF(q11);
        if (r > 12) STEPF(q12);
        if (r > 13) STEPF(q13);
        if (r > 14) STEPF(q14);
        if (r > 15) STEPF(q15);
        if (r > 16) { RESCDEP; STEPF(q16); }
        if (r > 17) STEPF(q17);
        if (r > 18) STEPF(q18);
        if (r > 19) STEPF(q19);
        if (r > 20) STEPF(q20);
        if (r > 21) STEPF(q21);
        if (r > 22) STEPF(q22);
    }

    afin[16*lane+0]=a0;   afin[16*lane+1]=a1;   afin[16*lane+2]=a2;   afin[16*lane+3]=a3;
    afin[16*lane+4]=a4;   afin[16*lane+5]=a5;   afin[16*lane+6]=a6;   afin[16*lane+7]=a7;
    afin[16*lane+8]=a8;   afin[16*lane+9]=a9;   afin[16*lane+10]=a10; afin[16*lane+11]=a11;
    afin[16*lane+12]=a12; afin[16*lane+13]=a13; afin[16*lane+14]=a14; afin[16*lane+15]=a15;
    __syncthreads();
    if (lane == 0) {
        float tot = afin[2*L] + afin[2*L-1];
        float lossb = 0.0f;
        if (tot > 0.0f) {
            double ll = log((double)tot)
                      + (double)E * 0.69314718055994530942
                      + (double)(-(double)Tn - (double)sl);
            lossb = (float)(-ll / (double)L);
        }
        loss_out[b] = lossb;
    }
    #undef STEPF
    #undef FMIXLO
    #undef FMIXHI
    #undef PH0
    #undef PHD
    #undef PH7
    #undef RESCDEP
    #undef LOADG4
    #undef WAITG20
    #undef WAITG0
}

// ------------------------------------------------- fallback (round-3, proven)
__global__ __launch_bounds__(256)
void lse_kernel(const float* __restrict__ ap_all,
                const int* __restrict__ in_lens,
                float* __restrict__ lse_out)
{
    const int lane = threadIdx.x & 63;
    const int wglob = blockIdx.x * (blockDim.x >> 6) + (threadIdx.x >> 6);
    const int nwav = gridDim.x * (blockDim.x >> 6);
    const int nrows = 64 * T_MAXN;

    for (int row = wglob; row < nrows; row += nwav) {
        const int b = row / T_MAXN;
        const int L = in_lens[b];
        const float* rp = ap_all + (size_t)row * K_MAXN;
        const int c0 = lane * 8;
        const int cb = (c0 < 392) ? c0 : 392;
        const float4* p = reinterpret_cast<const float4*>(rp + cb);
        float4 x0 = p[0], x1 = p[1];
        float v[8] = {x0.x, x0.y, x0.z, x0.w, x1.x, x1.y, x1.z, x1.w};
        float m = -1.0f;
        #pragma unroll
        for (int j = 0; j < 8; ++j) {
            v[j] = (c0 + j < L) ? v[j] : -1e30f;
            m = fmaxf(m, v[j]);
        }
        #pragma unroll
        for (int off = 32; off; off >>= 1) m = fmaxf(m, __shfl_xor(m, off));
        float s = (lane == 0) ? __expf(-1.0f - m) : 0.0f;
        #pragma unroll
        for (int j = 0; j < 8; ++j) s += __expf(v[j] - m);
        #pragma unroll
        for (int off = 32; off; off >>= 1) s += __shfl_xor(s, off);
        if (lane == 0) lse_out[row] = m + __logf(s);
    }
}

__global__ __launch_bounds__(64)
void ctc_scan_kernel(const float* __restrict__ ap_all,
                     const int* __restrict__ in_lens,
                     const int* __restrict__ out_lens,
                     const float* __restrict__ lse_all,
                     float* __restrict__ loss_out)
{
    __shared__ float afin[1024];

    const int b    = blockIdx.x;
    const int lane = threadIdx.x;
    const int L    = in_lens[b];
    const int Tn   = out_lens[b];
    const float* ap  = ap_all + (size_t)b * (T_MAXN * K_MAXN);
    const float* lse = lse_all + b * T_MAXN;

    const float LOG2E = 1.4426950408889634f;
    const int c0 = lane * 8;
    const int cb = (c0 < 392) ? c0 : 392;
    const float* rbase = ap + cb;
    float fa0,fa1,fa2,fa3,fa4,fa5,fa6,fa7;
    float fb0,fb1,fb2,fb3,fb4,fb5,fb6,fb7;
    #define MASKC(J, FA, FB) do { bool ok = (c0 + (J)) < L; \
        FA = ok ? LOG2E : 0.0f; FB = ok ? LOG2E : -1000.0f; } while (0)
    MASKC(0,fa0,fb0); MASKC(1,fa1,fb1); MASKC(2,fa2,fb2); MASKC(3,fa3,fb3);
    MASKC(4,fa4,fb4); MASKC(5,fa5,fb5); MASKC(6,fa6,fb6); MASKC(7,fa7,fb7);
    #undef MASKC

    float4 p0a,p0b,p1a,p1b,p2a,p2b,p3a,p3b;
    #define LOADROW(PA, PB, T) do { \
        const float4* _p = reinterpret_cast<const float4*>(rbase + (size_t)(T) * K_MAXN); \
        PA = _p[0]; PB = _p[1]; } while (0)
    LOADROW(p0a,p0b,1); LOADROW(p1a,p1b,2); LOADROW(p2a,p2b,3); LOADROW(p3a,p3b,4);

    float sl = 0.0f;
    for (int t = lane; t < Tn; t += 64) sl += lse[t];
    #pragma unroll
    for (int off = 32; off; off >>= 1) sl += __shfl_xor(sl, off);

    float x00 = ap[0];
    float a0=0,a1=0,a2=0,a3=0,a4=0,a5=0,a6=0,a7=0;
    float a8=0,a9=0,a10=0,a11=0,a12=0,a13=0,a14=0,a15=0;
    if (lane == 0) {
        a0 = 1.0f;
        a1 = __builtin_amdgcn_exp2f(fmaf(x00, LOG2E, LOG2E));
    }
    int E = 0;

    #define STEP(A0, A1) do { \
        float t1 = __shfl_up(a15, 1); \
        t1 = lane ? t1 : 0.0f; \
        const float f0 = __builtin_amdgcn_exp2f(fmaf((A0).x, fa0, fb0)); \
        const float f1 = __builtin_amdgcn_exp2f(fmaf((A0).y, fa1, fb1)); \
        const float f2 = __builtin_amdgcn_exp2f(fmaf((A0).z, fa2, fb2)); \
        const float f3 = __builtin_amdgcn_exp2f(fmaf((A0).w, fa3, fb3)); \
        const float f4 = __builtin_amdgcn_exp2f(fmaf((A1).x, fa4, fb4)); \
        const float f5 = __builtin_amdgcn_exp2f(fmaf((A1).y, fa5, fb5)); \
        const float f6 = __builtin_amdgcn_exp2f(fmaf((A1).z, fa6, fb6)); \
        const float f7 = __builtin_amdgcn_exp2f(fmaf((A1).w, fa7, fb7)); \
        const float e0 = a0 + t1,   e1 = a2 + a1,   e2 = a4 + a3,   e3 = a6 + a5; \
        const float e4 = a8 + a7,   e5 = a10 + a9,  e6 = a12 + a11, e7 = a14 + a13; \
        const float o0 = a1 + e0,   o1 = a3 + e1,   o2 = a5 + e2,   o3 = a7 + e3; \
        const float o4 = a9 + e4,   o5 = a11 + e5,  o6 = a13 + e6,  o7 = a15 + e7; \
        a0 = e0; a2 = e1; a4 = e2; a6 = e3; a8 = e4; a10 = e5; a12 = e6; a14 = e7; \
        a1 = f0*o0; a3 = f1*o1; a5 = f2*o2; a7 = f3*o3; \
        a9 = f4*o4; a11 = f5*o5; a13 = f6*o6; a15 = f7*o7; \
    } while (0)

    #define RESCALE do { \
        float mx = fmaxf(fmaxf(fmaxf(fmaxf(a0,a1),fmaxf(a2,a3)),fmaxf(fmaxf(a4,a5),fmaxf(a6,a7))), \
                         fmaxf(fmaxf(fmaxf(a8,a9),fmaxf(a10,a11)),fmaxf(fmaxf(a12,a13),fmaxf(a14,a15)))); \
        _Pragma("unroll") \
        for (int off = 32; off; off >>= 1) mx = fmaxf(mx, __shfl_xor(mx, off)); \
        int e = (int)((__float_as_uint(mx) >> 23) & 0xFF) - 127; \
        if (e != 0) { \
            E += e; \
            a0 = ldexpf(a0,-e);  a1 = ldexpf(a1,-e);  a2 = ldexpf(a2,-e);  a3 = ldexpf(a3,-e); \
            a4 = ldexpf(a4,-e);  a5 = ldexpf(a5,-e);  a6 = ldexpf(a6,-e);  a7 = ldexpf(a7,-e); \
            a8 = ldexpf(a8,-e);  a9 = ldexpf(a9,-e);  a10= ldexpf(a10,-e); a11= ldexpf(a11,-e); \
            a12= ldexpf(a12,-e); a13= ldexpf(a13,-e); a14= ldexpf(a14,-e); a15= ldexpf(a15,-e); \
        } \
    } while (0)

    int t = 1;
    while (t + 3 < Tn) {
        int tl;
        STEP(p0a,p0b); tl = (t+4 < T_MAXN) ? t+4 : T_MAXN-1; LOADROW(p0a,p0b,tl);
        STEP(p1a,p1b); tl = (t+5 < T_MAXN) ? t+5 : T_MAXN-1; LOADROW(p1a,p1b,tl);
        STEP(p2a,p2b); tl = (t+6 < T_MAXN) ? t+6 : T_MAXN-1; LOADROW(p2a,p2b,tl);
        STEP(p3a,p3b); tl = (t+7 < T_MAXN) ? t+7 : T_MAXN-1; LOADROW(p3a,p3b,tl);
        if ((t & 7) == 5) RESCALE;
        t += 4;
    }
    if (t < Tn) { STEP(p0a,p0b); ++t; }
    if (t < Tn) { STEP(p1a,p1b); ++t; }
    if (t < Tn) { STEP(p2a,p2b); ++t; }

    afin[16*lane+0]=a0;  afin[16*lane+1]=a1;  afin[16*lane+2]=a2;  afin[16*lane+3]=a3;
    afin[16*lane+4]=a4;  afin[16*lane+5]=a5;  afin[16*lane+6]=a6;  afin[16*lane+7]=a7;
    afin[16*lane+8]=a8;  afin[16*lane+9]=a9;  afin[16*lane+10]=a10; afin[16*lane+11]=a11;
    afin[16*lane+12]=a12; afin[16*lane+13]=a13; afin[16*lane+14]=a14; afin[16*lane+15]=a15;
    __syncthreads();
    if (lane == 0) {
        float tot = afin[2*L] + afin[2*L-1];
        float lossb = 0.0f;
        if (tot > 0.0f) {
            double ll = log((double)tot)
                      + (double)E * 0.69314718055994530942
                      + (double)(-(double)Tn - (double)sl);
            lossb = (float)(-ll / (double)L);
        }
        loss_out[b] = lossb;
    }
    #undef STEP
    #undef RESCALE
    #undef LOADROW
}

// ---------------------------------------------------------------- mean
__global__ void mean_kernel(const float* __restrict__ loss, float* __restrict__ out)
{
    float v = loss[threadIdx.x];   // 64 threads
    #pragma unroll
    for (int off = 32; off; off >>= 1) v += __shfl_xor(v, off);
    if (threadIdx.x == 0) out[0] = v * (1.0f / 64.0f);
}

extern "C" void kernel_launch(void* const* d_in, const int* in_sizes, int n_in,
                              void* d_out, int out_size, void* d_ws, size_t ws_size,
                              hipStream_t stream)
{
    // setup_inputs order: attn (unused), in_lens, out_lens, attn_logprob
    const int*   in_lens  = (const int*)d_in[1];
    const int*   out_lens = (const int*)d_in[2];
    const float* ap       = (const float*)d_in[3];
    float*       out      = (float*)d_out;

    if (ws_size >= WS_NEED) {
        char*     wsb     = (char*)d_ws;
        _Float16* g       = (_Float16*)wsb;
        float*    lse_ws  = (float*)(wsb + LSE_OFF);
        float*    zb      = (float*)(wsb + ZERO_OFF);
        float*    loss_ws = (float*)(wsb + LOSS_OFF);
        hipLaunchKernelGGL(prep_kernel, dim3(32, 64), dim3(256), 0, stream,
                           ap, in_lens, out_lens, lse_ws, g, zb);
        hipLaunchKernelGGL(ctc_scan24_kernel, dim3(64), dim3(64), 0, stream,
                           (const char*)wsb, in_lens, out_lens, loss_ws);
        hipLaunchKernelGGL(mean_kernel, dim3(1), dim3(64), 0, stream, loss_ws, out);
    } else {
        float* lse_ws  = (float*)d_ws;
        float* loss_ws = (float*)((char*)d_ws + (size_t)64 * T_MAXN * 4);
        hipLaunchKernelGGL(lse_kernel, dim3(512), dim3(256), 0, stream,
                           ap, in_lens, lse_ws);
        hipLaunchKernelGGL(ctc_scan_kernel, dim3(64), dim3(64), 0, stream,
                           ap, in_lens, out_lens, lse_ws, loss_ws);
        hipLaunchKernelGGL(mean_kernel, dim3(1), dim3(64), 0, stream, loss_ws, out);
    }
}

// Round 15
// 120.080 us; speedup vs baseline: 9.2792x; 1.2995x over previous
//
#include <hip/hip_runtime.h>
#include <cmath>

// CTC alignment loss (RAD-TTS style), B=64, T<=2000, K<=400, S=2K+1<=801.
//
// Round-13 confirmed: single-wave scan is issue-cadence bound (~4.3 cy/instr,
// time ~ instruction count). Round-14: 4-wave halo split. Wave w owns 224
// states, computes extended [224w-32, 224w+224) (4 states/lane). 32-state
// halo covers 16 steps of leftward dependency (2 states/step); every 16 steps
// one LDS exchange (boundary states + block-max pow2 rescale) with RAW
// s_barrier + lgkmcnt-only waits (prefetch stays in flight). Step = 7 VALU.

#define T_MAXN 2000
#define K_MAXN 400

typedef uint32_t uint4v __attribute__((ext_vector_type(4)));

// ws layout (fast path)
#define G_BYTES   ((size_t)64 * T_MAXN * K_MAXN * 2)   // 102,400,000
#define LSE_OFF   G_BYTES
#define LSE_BYTES ((size_t)64 * T_MAXN * 4)            // 512,000
#define ZERO_OFF  (LSE_OFF + LSE_BYTES)                // 4KB zero block
#define LOSS_OFF  (ZERO_OFF + 4096)
#define WS_NEED   (LOSS_OFF + 64 * 4)

// lane-1's value (shift wave right by 1), lane 0 -> 0.0f; single VALU op
__device__ __forceinline__ float dpp_wave_shr1(float x)
{
    int r = __builtin_amdgcn_update_dpp(0, (int)__float_as_uint(x),
                                        0x138 /*wave_shr:1*/, 0xF, 0xF, true);
    return __uint_as_float((uint32_t)r);
}

template <int CTRL>
__device__ __forceinline__ float dpp_mov(float x)
{
    int r = __builtin_amdgcn_update_dpp(0, (int)__float_as_uint(x),
                                        CTRL, 0xF, 0xF, true);
    return __uint_as_float((uint32_t)r);
}

// ---------------------------------------------------------- fast path: prep
__global__ __launch_bounds__(256)
void prep_kernel(const float* __restrict__ ap_all,
                 const int* __restrict__ in_lens,
                 const int* __restrict__ out_lens,
                 float* __restrict__ lse_out,
                 _Float16* __restrict__ g_out,
                 float* __restrict__ zerobuf)
{
    const int b    = blockIdx.y;
    const int L    = in_lens[b];
    const int Tn   = out_lens[b];
    const int lane = threadIdx.x & 63;
    const int wid  = blockIdx.x * (blockDim.x >> 6) + (threadIdx.x >> 6);
    const int nw   = gridDim.x * (blockDim.x >> 6);

    if (b == 0 && wid == 0) {                     // 4KB zero block for dead lanes
        for (int i = lane; i < 1024; i += 64) zerobuf[i] = 0.0f;
    }

    const float* base = ap_all + (size_t)b * (T_MAXN * K_MAXN);
    _Float16*    gb   = g_out  + (size_t)b * (T_MAXN * K_MAXN);
    const int c0 = lane * 8;
    const int cb = (c0 < 392) ? c0 : 392;         // clamped (lanes >= 50 fully masked)

    for (int t = wid; t < Tn; t += nw) {
        const float4* p = reinterpret_cast<const float4*>(base + (size_t)t * K_MAXN + cb);
        float4 x0 = p[0], x1 = p[1];
        float v[8] = {x0.x, x0.y, x0.z, x0.w, x1.x, x1.y, x1.z, x1.w};
        float m = -1.0f;                          // blank logit
        #pragma unroll
        for (int j = 0; j < 8; ++j) {
            v[j] = (c0 + j < L) ? v[j] : -1e30f;
            m = fmaxf(m, v[j]);
        }
        #pragma unroll
        for (int off = 32; off; off >>= 1) m = fmaxf(m, __shfl_xor(m, off));
        float s = (lane == 0) ? __expf(-1.0f - m) : 0.0f;
        #pragma unroll
        for (int j = 0; j < 8; ++j) s += __expf(v[j] - m);
        #pragma unroll
        for (int off = 32; off; off >>= 1) s += __shfl_xor(s, off);
        if (lane == 0) lse_out[b * T_MAXN + t] = m + __logf(s);

        _Float16 h[8];
        #pragma unroll
        for (int j = 0; j < 8; ++j) h[j] = (_Float16)__expf(v[j] + 1.0f);  // masked -> 0
        if (c0 < K_MAXN)
            *reinterpret_cast<uint4v*>(gb + (size_t)t * K_MAXN + c0) =
                *reinterpret_cast<const uint4v*>(h);
    }
}

// ---------------------------------------------------------- fast path: scan
// 4 waves/block, 1 block/sample. Wave w: extended states [224w-32, 224w+224),
// 4 states/lane (even,odd,even,odd). Odd-state labels -> g columns
// col0 = 112w-16+2*lane and col0+1 (one dword per row per lane).
__global__ __launch_bounds__(256, 1)
void ctc_scan4w_kernel(const char* wsro,
                       const int* __restrict__ in_lens,
                       const int* __restrict__ out_lens,
                       float* loss_out)
{
    __shared__ float afin[1024];
    __shared__ float halo_sh[4][32];
    __shared__ float wmax_sh[4];

    const int b    = blockIdx.x;
    const int tid  = threadIdx.x;
    const int wid  = tid >> 6;
    const int lane = tid & 63;
    const int L    = in_lens[b];      // [200,400]
    const int Tn   = out_lens[b];     // [1000,2000]
    const uint32_t goff = (uint32_t)b * (uint32_t)(T_MAXN * K_MAXN * 2);
    const float* lse = (const float*)(wsro + LSE_OFF) + b * T_MAXN;

    const int col0 = 112 * wid - 16 + 2 * lane;   // even; this lane's 2 label cols
    uint32_t off, inc;
    if (col0 >= 0 && col0 < K_MAXN) { off = goff + (uint32_t)(col0 * 2) + 800u; inc = 3200u; }
    else                            { off = (uint32_t)ZERO_OFF;                 inc = 0u;    }

    // prologue: sl = sum_{t<Tn} lse[t]   (wave 0 only; used by tid 0)
    float sl = 0.0f;
    if (wid == 0) {
        for (int t = lane; t < Tn; t += 64) sl += lse[t];
        #pragma unroll
        for (int o = 32; o; o >>= 1) sl += __shfl_xor(sl, o);
    }

    // init t=0 (blank-normalized): alpha^[0]=1 (wave0 lane8 a0), alpha^[1]=g[0][0]
    float a0=0.0f, a1=0.0f, a2=0.0f, a3=0.0f;
    if (wid == 0 && lane == 8) {
        a0 = 1.0f;
        a1 = (float)*reinterpret_cast<const _Float16*>(wsro + goff);
    }
    int   E  = 0;
    float t1 = 0.0f;    // lane-1's a3 (state E+4l-1); 0 initially (those states are 0)

    #define LOADG4(QA, QB, QC, QD) do { \
        asm volatile("global_load_dword %0, %1, %2 offset:0"    : "=v"(QA) : "v"(off), "s"(wsro)); \
        asm volatile("global_load_dword %0, %1, %2 offset:800"  : "=v"(QB) : "v"(off), "s"(wsro)); \
        asm volatile("global_load_dword %0, %1, %2 offset:1600" : "=v"(QC) : "v"(off), "s"(wsro)); \
        asm volatile("global_load_dword %0, %1, %2 offset:2400" : "=v"(QD) : "v"(off), "s"(wsro)); \
        off += inc; \
    } while (0)

    #define WAITG12 do { \
        asm volatile("s_waitcnt vmcnt(12)" ::: "memory"); \
        __builtin_amdgcn_sched_barrier(0); \
    } while (0)

    // f16 factor consumed directly: a = f16*o + 0 (exact convert+mul)
    #define FMIXLO(DST, SRC, O) \
        asm("v_fma_mix_f32 %0, %1, %2, 0 op_sel:[0,0,0] op_sel_hi:[1,0,0]" \
            : "=v"(DST) : "v"(SRC), "v"(O))
    #define FMIXHI(DST, SRC, O) \
        asm("v_fma_mix_f32 %0, %1, %2, 0 op_sel:[1,0,0] op_sel_hi:[1,0,0]" \
            : "=v"(DST) : "v"(SRC), "v"(O))

    // even s: new = old[s]+old[s-1]; odd s: new = g*(old[s]+new_even) — 7 VALU
    #define STEPF(Q) do { \
        const float e0 = a0 + t1; \
        const float e1 = a2 + a1; \
        const float o0 = a1 + e0; \
        const float o1 = a3 + e1; \
        a0 = e0; a2 = e1; \
        FMIXLO(a1, (Q), o0); \
        FMIXHI(a3, (Q), o1); \
        t1 = dpp_wave_shr1(a3); \
    } while (0)

    // raw barrier: LDS-visibility only (lgkmcnt), prefetch NOT drained
    #define BARR do { \
        asm volatile("s_waitcnt lgkmcnt(0)" ::: "memory"); \
        __builtin_amdgcn_s_barrier(); \
        asm volatile("" ::: "memory"); \
    } while (0)

    // every 16 steps: boundary handoff + block-max pow2 rescale.
    // Wave w lanes 56..63 (owned top 32 states = next wave's halo) -> LDS;
    // wave w>0 lanes 0..7 reload halo; all scale by 2^-e of block max.
    #define EXCHANGE do { \
        float mx = fmaxf(fmaxf(a0, a1), fmaxf(a2, a3)); \
        mx = fmaxf(mx, dpp_mov<0x111>(mx)); \
        mx = fmaxf(mx, dpp_mov<0x112>(mx)); \
        mx = fmaxf(mx, dpp_mov<0x114>(mx)); \
        mx = fmaxf(mx, dpp_mov<0x118>(mx)); \
        mx = fmaxf(mx, dpp_mov<0x142>(mx)); \
        mx = fmaxf(mx, dpp_mov<0x143>(mx)); \
        if (lane == 63) wmax_sh[wid] = mx; \
        if (lane >= 56) { \
            float4 bv; bv.x = a0; bv.y = a1; bv.z = a2; bv.w = a3; \
            *reinterpret_cast<float4*>(&halo_sh[wid][(lane - 56) * 4]) = bv; \
        } \
        BARR; \
        float bm = fmaxf(fmaxf(wmax_sh[0], wmax_sh[1]), fmaxf(wmax_sh[2], wmax_sh[3])); \
        int e = (int)((__float_as_uint(bm) >> 23) & 0xFF) - 127; \
        E += e; \
        const float sc = __uint_as_float((uint32_t)(127 - e) << 23);  /* 2^-e exact */ \
        if (wid > 0 && lane < 8) { \
            float4 hv = *reinterpret_cast<const float4*>(&halo_sh[wid - 1][lane * 4]); \
            a0 = hv.x; a1 = hv.y; a2 = hv.z; a3 = hv.w; \
        } \
        a0 *= sc; a1 *= sc; a2 *= sc; a3 *= sc; \
        t1 = dpp_wave_shr1(a3); \
        BARR; \
    } while (0)

    uint32_t q0,q1,q2,q3,q4,q5,q6,q7,q8,q9,q10,q11,q12,q13,q14,q15;
    LOADG4(q0,q1,q2,q3); LOADG4(q4,q5,q6,q7);
    LOADG4(q8,q9,q10,q11); LOADG4(q12,q13,q14,q15);

    int t = 1;
    while (t + 15 < Tn) {
        WAITG12; STEPF(q0);  STEPF(q1);  STEPF(q2);  STEPF(q3);  LOADG4(q0,q1,q2,q3);
        WAITG12; STEPF(q4);  STEPF(q5);  STEPF(q6);  STEPF(q7);  LOADG4(q4,q5,q6,q7);
        WAITG12; STEPF(q8);  STEPF(q9);  STEPF(q10); STEPF(q11); LOADG4(q8,q9,q10,q11);
        WAITG12; STEPF(q12); STEPF(q13); STEPF(q14); STEPF(q15); LOADG4(q12,q13,q14,q15);
        EXCHANGE;
        t += 16;
    }
    asm volatile("s_waitcnt vmcnt(0)" ::: "memory");
    __builtin_amdgcn_sched_barrier(0);
    {
        const int r = Tn - t;   // 0..15; halo degradation <= 30 <= 32 -> owned ok
        if (r > 0)  STEPF(q0);
        if (r > 1)  STEPF(q1);
        if (r > 2)  STEPF(q2);
        if (r > 3)  STEPF(q3);
        if (r > 4)  STEPF(q4);
        if (r > 5)  STEPF(q5);
        if (r > 6)  STEPF(q6);
        if (r > 7)  STEPF(q7);
        if (r > 8)  STEPF(q8);
        if (r > 9)  STEPF(q9);
        if (r > 10) STEPF(q10);
        if (r > 11) STEPF(q11);
        if (r > 12) STEPF(q12);
        if (r > 13) STEPF(q13);
        if (r > 14) STEPF(q14);
    }

    // readout: owned lanes (>=8) publish their 4 states
    if (lane >= 8) {
        const int gidx = 224 * wid - 32 + 4 * lane;   // global state index of a0
        afin[gidx]     = a0;
        afin[gidx + 1] = a1;
        afin[gidx + 2] = a2;
        afin[gidx + 3] = a3;
    }
    __syncthreads();
    if (tid == 0) {
        float tot = afin[2 * L] + afin[2 * L - 1];
        float lossb = 0.0f;
        if (tot > 0.0f) {
            double ll = log((double)tot)
                      + (double)E * 0.69314718055994530942
                      + (double)(-(double)Tn - (double)sl);
            lossb = (float)(-ll / (double)L);
        }
        loss_out[b] = lossb;
    }
    #undef STEPF
    #undef FMIXLO
    #undef FMIXHI
    #undef LOADG4
    #undef WAITG12
    #undef BARR
    #undef EXCHANGE
}

// ------------------------------------------------- fallback (round-3, proven)
__global__ __launch_bounds__(256)
void lse_kernel(const float* __restrict__ ap_all,
                const int* __restrict__ in_lens,
                float* __restrict__ lse_out)
{
    const int lane = threadIdx.x & 63;
    const int wglob = blockIdx.x * (blockDim.x >> 6) + (threadIdx.x >> 6);
    const int nwav = gridDim.x * (blockDim.x >> 6);
    const int nrows = 64 * T_MAXN;

    for (int row = wglob; row < nrows; row += nwav) {
        const int b = row / T_MAXN;
        const int L = in_lens[b];
        const float* rp = ap_all + (size_t)row * K_MAXN;
        const int c0 = lane * 8;
        const int cb = (c0 < 392) ? c0 : 392;
        const float4* p = reinterpret_cast<const float4*>(rp + cb);
        float4 x0 = p[0], x1 = p[1];
        float v[8] = {x0.x, x0.y, x0.z, x0.w, x1.x, x1.y, x1.z, x1.w};
        float m = -1.0f;
        #pragma unroll
        for (int j = 0; j < 8; ++j) {
            v[j] = (c0 + j < L) ? v[j] : -1e30f;
            m = fmaxf(m, v[j]);
        }
        #pragma unroll
        for (int off = 32; off; off >>= 1) m = fmaxf(m, __shfl_xor(m, off));
        float s = (lane == 0) ? __expf(-1.0f - m) : 0.0f;
        #pragma unroll
        for (int j = 0; j < 8; ++j) s += __expf(v[j] - m);
        #pragma unroll
        for (int off = 32; off; off >>= 1) s += __shfl_xor(s, off);
        if (lane == 0) lse_out[row] = m + __logf(s);
    }
}

__global__ __launch_bounds__(64)
void ctc_scan_kernel(const float* __restrict__ ap_all,
                     const int* __restrict__ in_lens,
                     const int* __restrict__ out_lens,
                     const float* __restrict__ lse_all,
                     float* __restrict__ loss_out)
{
    __shared__ float afin[1024];

    const int b    = blockIdx.x;
    const int lane = threadIdx.x;
    const int L    = in_lens[b];
    const int Tn   = out_lens[b];
    const float* ap  = ap_all + (size_t)b * (T_MAXN * K_MAXN);
    const float* lse = lse_all + b * T_MAXN;

    const float LOG2E = 1.4426950408889634f;
    const int c0 = lane * 8;
    const int cb = (c0 < 392) ? c0 : 392;
    const float* rbase = ap + cb;
    float fa0,fa1,fa2,fa3,fa4,fa5,fa6,fa7;
    float fb0,fb1,fb2,fb3,fb4,fb5,fb6,fb7;
    #define MASKC(J, FA, FB) do { bool ok = (c0 + (J)) < L; \
        FA = ok ? LOG2E : 0.0f; FB = ok ? LOG2E : -1000.0f; } while (0)
    MASKC(0,fa0,fb0); MASKC(1,fa1,fb1); MASKC(2,fa2,fb2); MASKC(3,fa3,fb3);
    MASKC(4,fa4,fb4); MASKC(5,fa5,fb5); MASKC(6,fa6,fb6); MASKC(7,fa7,fb7);
    #undef MASKC

    float4 p0a,p0b,p1a,p1b,p2a,p2b,p3a,p3b;
    #define LOADROW(PA, PB, T) do { \
        const float4* _p = reinterpret_cast<const float4*>(rbase + (size_t)(T) * K_MAXN); \
        PA = _p[0]; PB = _p[1]; } while (0)
    LOADROW(p0a,p0b,1); LOADROW(p1a,p1b,2); LOADROW(p2a,p2b,3); LOADROW(p3a,p3b,4);

    float sl = 0.0f;
    for (int t = lane; t < Tn; t += 64) sl += lse[t];
    #pragma unroll
    for (int off = 32; off; off >>= 1) sl += __shfl_xor(sl, off);

    float x00 = ap[0];
    float a0=0,a1=0,a2=0,a3=0,a4=0,a5=0,a6=0,a7=0;
    float a8=0,a9=0,a10=0,a11=0,a12=0,a13=0,a14=0,a15=0;
    if (lane == 0) {
        a0 = 1.0f;
        a1 = __builtin_amdgcn_exp2f(fmaf(x00, LOG2E, LOG2E));
    }
    int E = 0;

    #define STEP(A0, A1) do { \
        float t1 = __shfl_up(a15, 1); \
        t1 = lane ? t1 : 0.0f; \
        const float f0 = __builtin_amdgcn_exp2f(fmaf((A0).x, fa0, fb0)); \
        const float f1 = __builtin_amdgcn_exp2f(fmaf((A0).y, fa1, fb1)); \
        const float f2 = __builtin_amdgcn_exp2f(fmaf((A0).z, fa2, fb2)); \
        const float f3 = __builtin_amdgcn_exp2f(fmaf((A0).w, fa3, fb3)); \
        const float f4 = __builtin_amdgcn_exp2f(fmaf((A1).x, fa4, fb4)); \
        const float f5 = __builtin_amdgcn_exp2f(fmaf((A1).y, fa5, fb5)); \
        const float f6 = __builtin_amdgcn_exp2f(fmaf((A1).z, fa6, fb6)); \
        const float f7 = __builtin_amdgcn_exp2f(fmaf((A1).w, fa7, fb7)); \
        const float e0 = a0 + t1,   e1 = a2 + a1,   e2 = a4 + a3,   e3 = a6 + a5; \
        const float e4 = a8 + a7,   e5 = a10 + a9,  e6 = a12 + a11, e7 = a14 + a13; \
        const float o0 = a1 + e0,   o1 = a3 + e1,   o2 = a5 + e2,   o3 = a7 + e3; \
        const float o4 = a9 + e4,   o5 = a11 + e5,  o6 = a13 + e6,  o7 = a15 + e7; \
        a0 = e0; a2 = e1; a4 = e2; a6 = e3; a8 = e4; a10 = e5; a12 = e6; a14 = e7; \
        a1 = f0*o0; a3 = f1*o1; a5 = f2*o2; a7 = f3*o3; \
        a9 = f4*o4; a11 = f5*o5; a13 = f6*o6; a15 = f7*o7; \
    } while (0)

    #define RESCALE do { \
        float mx = fmaxf(fmaxf(fmaxf(fmaxf(a0,a1),fmaxf(a2,a3)),fmaxf(fmaxf(a4,a5),fmaxf(a6,a7))), \
                         fmaxf(fmaxf(fmaxf(a8,a9),fmaxf(a10,a11)),fmaxf(fmaxf(a12,a13),fmaxf(a14,a15)))); \
        _Pragma("unroll") \
        for (int off = 32; off; off >>= 1) mx = fmaxf(mx, __shfl_xor(mx, off)); \
        int e = (int)((__float_as_uint(mx) >> 23) & 0xFF) - 127; \
        if (e != 0) { \
            E += e; \
            a0 = ldexpf(a0,-e);  a1 = ldexpf(a1,-e);  a2 = ldexpf(a2,-e);  a3 = ldexpf(a3,-e); \
            a4 = ldexpf(a4,-e);  a5 = ldexpf(a5,-e);  a6 = ldexpf(a6,-e);  a7 = ldexpf(a7,-e); \
            a8 = ldexpf(a8,-e);  a9 = ldexpf(a9,-e);  a10= ldexpf(a10,-e); a11= ldexpf(a11,-e); \
            a12= ldexpf(a12,-e); a13= ldexpf(a13,-e); a14= ldexpf(a14,-e); a15= ldexpf(a15,-e); \
        } \
    } while (0)

    int t = 1;
    while (t + 3 < Tn) {
        int tl;
        STEP(p0a,p0b); tl = (t+4 < T_MAXN) ? t+4 : T_MAXN-1; LOADROW(p0a,p0b,tl);
        STEP(p1a,p1b); tl = (t+5 < T_MAXN) ? t+5 : T_MAXN-1; LOADROW(p1a,p1b,tl);
        STEP(p2a,p2b); tl = (t+6 < T_MAXN) ? t+6 : T_MAXN-1; LOADROW(p2a,p2b,tl);
        STEP(p3a,p3b); tl = (t+7 < T_MAXN) ? t+7 : T_MAXN-1; LOADROW(p3a,p3b,tl);
        if ((t & 7) == 5) RESCALE;
        t += 4;
    }
    if (t < Tn) { STEP(p0a,p0b); ++t; }
    if (t < Tn) { STEP(p1a,p1b); ++t; }
    if (t < Tn) { STEP(p2a,p2b); ++t; }

    afin[16*lane+0]=a0;  afin[16*lane+1]=a1;  afin[16*lane+2]=a2;  afin[16*lane+3]=a3;
    afin[16*lane+4]=a4;  afin[16*lane+5]=a5;  afin[16*lane+6]=a6;  afin[16*lane+7]=a7;
    afin[16*lane+8]=a8;  afin[16*lane+9]=a9;  afin[16*lane+10]=a10; afin[16*lane+11]=a11;
    afin[16*lane+12]=a12; afin[16*lane+13]=a13; afin[16*lane+14]=a14; afin[16*lane+15]=a15;
    __syncthreads();
    if (lane == 0) {
        float tot = afin[2*L] + afin[2*L-1];
        float lossb = 0.0f;
        if (tot > 0.0f) {
            double ll = log((double)tot)
                      + (double)E * 0.69314718055994530942
                      + (double)(-(double)Tn - (double)sl);
            lossb = (float)(-ll / (double)L);
        }
        loss_out[b] = lossb;
    }
    #undef STEP
    #undef RESCALE
    #undef LOADROW
}

// ---------------------------------------------------------------- mean
__global__ void mean_kernel(const float* __restrict__ loss, float* __restrict__ out)
{
    float v = loss[threadIdx.x];   // 64 threads
    #pragma unroll
    for (int off = 32; off; off >>= 1) v += __shfl_xor(v, off);
    if (threadIdx.x == 0) out[0] = v * (1.0f / 64.0f);
}

extern "C" void kernel_launch(void* const* d_in, const int* in_sizes, int n_in,
                              void* d_out, int out_size, void* d_ws, size_t ws_size,
                              hipStream_t stream)
{
    // setup_inputs order: attn (unused), in_lens, out_lens, attn_logprob
    const int*   in_lens  = (const int*)d_in[1];
    const int*   out_lens = (const int*)d_in[2];
    const float* ap       = (const float*)d_in[3];
    float*       out      = (float*)d_out;

    if (ws_size >= WS_NEED) {
        char*     wsb     = (char*)d_ws;
        _Float16* g       = (_Float16*)wsb;
        float*    lse_ws  = (float*)(wsb + LSE_OFF);
        float*    zb      = (float*)(wsb + ZERO_OFF);
        float*    loss_ws = (float*)(wsb + LOSS_OFF);
        hipLaunchKernelGGL(prep_kernel, dim3(32, 64), dim3(256), 0, stream,
                           ap, in_lens, out_lens, lse_ws, g, zb);
        hipLaunchKernelGGL(ctc_scan4w_kernel, dim3(64), dim3(256), 0, stream,
                           (const char*)wsb, in_lens, out_lens, loss_ws);
        hipLaunchKernelGGL(mean_kernel, dim3(1), dim3(64), 0, stream, loss_ws, out);
    } else {
        float* lse_ws  = (float*)d_ws;
        float* loss_ws = (float*)((char*)d_ws + (size_t)64 * T_MAXN * 4);
        hipLaunchKernelGGL(lse_kernel, dim3(512), dim3(256), 0, stream,
                           ap, in_lens, lse_ws);
        hipLaunchKernelGGL(ctc_scan_kernel, dim3(64), dim3(64), 0, stream,
                           ap, in_lens, out_lens, lse_ws, loss_ws);
        hipLaunchKernelGGL(mean_kernel, dim3(1), dim3(64), 0, stream, loss_ws, out);
    }
}

// Round 17
// 116.659 us; speedup vs baseline: 9.5514x; 1.0293x over previous
//
#include <hip/hip_runtime.h>
#include <cmath>

// CTC alignment loss (RAD-TTS style), B=64, T<=2000, K<=400, S=2K+1<=801.
//
// Round-15: 4-wave halo scan landed (total 156->120us). Round-16 trims the
// scan's per-step budget on the same proven structure:
//  1. single-barrier exchange (double-buffered halo/wmax, parity-alternating)
//     -- WAR distance becomes a full 16-step group, 2nd barrier unneeded.
//  2. plain HIP loads (round-12 proved prefetch depth immaterial; drop the
//     per-group s_waitcnt/sched_barrier overhead, compiler auto-waits).

#define T_MAXN 2000
#define K_MAXN 400

typedef uint32_t uint4v __attribute__((ext_vector_type(4)));

// ws layout (fast path)
#define G_BYTES   ((size_t)64 * T_MAXN * K_MAXN * 2)   // 102,400,000
#define LSE_OFF   G_BYTES
#define LSE_BYTES ((size_t)64 * T_MAXN * 4)            // 512,000
#define ZERO_OFF  (LSE_OFF + LSE_BYTES)                // 4KB zero block
#define LOSS_OFF  (ZERO_OFF + 4096)
#define WS_NEED   (LOSS_OFF + 64 * 4)

// lane-1's value (shift wave right by 1), lane 0 -> 0.0f; single VALU op
__device__ __forceinline__ float dpp_wave_shr1(float x)
{
    int r = __builtin_amdgcn_update_dpp(0, (int)__float_as_uint(x),
                                        0x138 /*wave_shr:1*/, 0xF, 0xF, true);
    return __uint_as_float((uint32_t)r);
}

template <int CTRL>
__device__ __forceinline__ float dpp_mov(float x)
{
    int r = __builtin_amdgcn_update_dpp(0, (int)__float_as_uint(x),
                                        CTRL, 0xF, 0xF, true);
    return __uint_as_float((uint32_t)r);
}

// ---------------------------------------------------------- fast path: prep
__global__ __launch_bounds__(256)
void prep_kernel(const float* __restrict__ ap_all,
                 const int* __restrict__ in_lens,
                 const int* __restrict__ out_lens,
                 float* __restrict__ lse_out,
                 _Float16* __restrict__ g_out,
                 float* __restrict__ zerobuf)
{
    const int b    = blockIdx.y;
    const int L    = in_lens[b];
    const int Tn   = out_lens[b];
    const int lane = threadIdx.x & 63;
    const int wid  = blockIdx.x * (blockDim.x >> 6) + (threadIdx.x >> 6);
    const int nw   = gridDim.x * (blockDim.x >> 6);

    if (b == 0 && wid == 0) {                     // 4KB zero block for dead lanes
        for (int i = lane; i < 1024; i += 64) zerobuf[i] = 0.0f;
    }

    const float* base = ap_all + (size_t)b * (T_MAXN * K_MAXN);
    _Float16*    gb   = g_out  + (size_t)b * (T_MAXN * K_MAXN);
    const int c0 = lane * 8;
    const int cb = (c0 < 392) ? c0 : 392;         // clamped (lanes >= 50 fully masked)

    for (int t = wid; t < Tn; t += nw) {
        const float4* p = reinterpret_cast<const float4*>(base + (size_t)t * K_MAXN + cb);
        float4 x0 = p[0], x1 = p[1];
        float v[8] = {x0.x, x0.y, x0.z, x0.w, x1.x, x1.y, x1.z, x1.w};
        float m = -1.0f;                          // blank logit
        #pragma unroll
        for (int j = 0; j < 8; ++j) {
            v[j] = (c0 + j < L) ? v[j] : -1e30f;
            m = fmaxf(m, v[j]);
        }
        #pragma unroll
        for (int off = 32; off; off >>= 1) m = fmaxf(m, __shfl_xor(m, off));
        float s = (lane == 0) ? __expf(-1.0f - m) : 0.0f;
        #pragma unroll
        for (int j = 0; j < 8; ++j) s += __expf(v[j] - m);
        #pragma unroll
        for (int off = 32; off; off >>= 1) s += __shfl_xor(s, off);
        if (lane == 0) lse_out[b * T_MAXN + t] = m + __logf(s);

        _Float16 h[8];
        #pragma unroll
        for (int j = 0; j < 8; ++j) h[j] = (_Float16)__expf(v[j] + 1.0f);  // masked -> 0
        if (c0 < K_MAXN)
            *reinterpret_cast<uint4v*>(gb + (size_t)t * K_MAXN + c0) =
                *reinterpret_cast<const uint4v*>(h);
    }
}

// ---------------------------------------------------------- fast path: scan
// 4 waves/block, 1 block/sample. Wave w: extended states [224w-32, 224w+224),
// 4 states/lane (even,odd,even,odd). Odd-state labels -> g columns
// col0 = 112w-16+2*lane and col0+1 (one dword per row per lane).
__global__ __launch_bounds__(256, 1)
void ctc_scan4w_kernel(const char* wsro,
                       const int* __restrict__ in_lens,
                       const int* __restrict__ out_lens,
                       float* loss_out)
{
    __shared__ float afin[1024];
    __shared__ float halo_sh[2][4][32];   // double-buffered (parity)
    __shared__ float wmax_sh[2][4];

    const int b    = blockIdx.x;
    const int tid  = threadIdx.x;
    const int wid  = tid >> 6;
    const int lane = tid & 63;
    const int L    = in_lens[b];      // [200,400]
    const int Tn   = out_lens[b];     // [1000,2000]
    const uint32_t goff = (uint32_t)b * (uint32_t)(T_MAXN * K_MAXN * 2);
    const float* lse = (const float*)(wsro + LSE_OFF) + b * T_MAXN;

    const int col0 = 112 * wid - 16 + 2 * lane;   // even; this lane's 2 label cols
    uint32_t off, inc;
    if (col0 >= 0 && col0 < K_MAXN) { off = goff + (uint32_t)(col0 * 2) + 800u; inc = 3200u; }
    else                            { off = (uint32_t)ZERO_OFF;                 inc = 0u;    }

    // prologue: sl = sum_{t<Tn} lse[t]   (wave 0 only; used by tid 0)
    float sl = 0.0f;
    if (wid == 0) {
        for (int t = lane; t < Tn; t += 64) sl += lse[t];
        #pragma unroll
        for (int o = 32; o; o >>= 1) sl += __shfl_xor(sl, o);
    }

    // init t=0 (blank-normalized): alpha^[0]=1 (wave0 lane8 a0), alpha^[1]=g[0][0]
    float a0=0.0f, a1=0.0f, a2=0.0f, a3=0.0f;
    if (wid == 0 && lane == 8) {
        a0 = 1.0f;
        a1 = (float)*reinterpret_cast<const _Float16*>(wsro + goff);
    }
    int   E  = 0;
    float t1 = 0.0f;    // lane-1's a3 (state E+4l-1); 0 initially (those states are 0)

    // plain loads: compiler schedules + auto-inserts waitcnt (depth immaterial,
    // proven round-12)
    #define LOADG4(QA, QB, QC, QD) do { \
        QA = *reinterpret_cast<const uint32_t*>(wsro + off); \
        QB = *reinterpret_cast<const uint32_t*>(wsro + off + 800); \
        QC = *reinterpret_cast<const uint32_t*>(wsro + off + 1600); \
        QD = *reinterpret_cast<const uint32_t*>(wsro + off + 2400); \
        off += inc; \
    } while (0)

    // f16 factor consumed directly: a = f16*o + 0 (exact convert+mul)
    #define FMIXLO(DST, SRC, O) \
        asm("v_fma_mix_f32 %0, %1, %2, 0 op_sel:[0,0,0] op_sel_hi:[1,0,0]" \
            : "=v"(DST) : "v"(SRC), "v"(O))
    #define FMIXHI(DST, SRC, O) \
        asm("v_fma_mix_f32 %0, %1, %2, 0 op_sel:[1,0,0] op_sel_hi:[1,0,0]" \
            : "=v"(DST) : "v"(SRC), "v"(O))

    // even s: new = old[s]+old[s-1]; odd s: new = g*(old[s]+new_even) — 7 VALU
    #define STEPF(Q) do { \
        const float e0 = a0 + t1; \
        const float e1 = a2 + a1; \
        const float o0 = a1 + e0; \
        const float o1 = a3 + e1; \
        a0 = e0; a2 = e1; \
        FMIXLO(a1, (Q), o0); \
        FMIXHI(a3, (Q), o1); \
        t1 = dpp_wave_shr1(a3); \
    } while (0)

    // single raw barrier: LDS-visibility only (lgkmcnt), prefetch NOT drained
    #define BARR do { \
        asm volatile("s_waitcnt lgkmcnt(0)" ::: "memory"); \
        __builtin_amdgcn_s_barrier(); \
        asm volatile("" ::: "memory"); \
    } while (0)

    // every 16 steps: boundary handoff + block-max pow2 rescale. Wave w lanes
    // 56..63 (owned top 32 states = next wave's halo) -> LDS buffer [pp];
    // wave w>0 lanes 0..7 reload; all scale by 2^-e of block max. SINGLE
    // barrier: next exchange writes buffer [pp^1] (WAR distance = 16 steps).
    #define EXCHANGE(PP) do { \
        float mx = fmaxf(fmaxf(a0, a1), fmaxf(a2, a3)); \
        mx = fmaxf(mx, dpp_mov<0x111>(mx)); \
        mx = fmaxf(mx, dpp_mov<0x112>(mx)); \
        mx = fmaxf(mx, dpp_mov<0x114>(mx)); \
        mx = fmaxf(mx, dpp_mov<0x118>(mx)); \
        mx = fmaxf(mx, dpp_mov<0x142>(mx)); \
        mx = fmaxf(mx, dpp_mov<0x143>(mx)); \
        if (lane == 63) wmax_sh[PP][wid] = mx; \
        if (lane >= 56) { \
            float4 bv; bv.x = a0; bv.y = a1; bv.z = a2; bv.w = a3; \
            *reinterpret_cast<float4*>(&halo_sh[PP][wid][(lane - 56) * 4]) = bv; \
        } \
        BARR; \
        float bm = fmaxf(fmaxf(wmax_sh[PP][0], wmax_sh[PP][1]), \
                         fmaxf(wmax_sh[PP][2], wmax_sh[PP][3])); \
        int e = (int)((__float_as_uint(bm) >> 23) & 0xFF) - 127; \
        E += e; \
        const float sc = __uint_as_float((uint32_t)(127 - e) << 23);  /* 2^-e exact */ \
        if (wid > 0 && lane < 8) { \
            float4 hv = *reinterpret_cast<const float4*>(&halo_sh[PP][wid - 1][lane * 4]); \
            a0 = hv.x; a1 = hv.y; a2 = hv.z; a3 = hv.w; \
        } \
        a0 *= sc; a1 *= sc; a2 *= sc; a3 *= sc; \
        t1 = dpp_wave_shr1(a3); \
    } while (0)

    uint32_t q0,q1,q2,q3,q4,q5,q6,q7,q8,q9,q10,q11,q12,q13,q14,q15;
    LOADG4(q0,q1,q2,q3); LOADG4(q4,q5,q6,q7);
    LOADG4(q8,q9,q10,q11); LOADG4(q12,q13,q14,q15);

    int t = 1;
    int pp = 0;
    while (t + 15 < Tn) {
        STEPF(q0);  STEPF(q1);  STEPF(q2);  STEPF(q3);  LOADG4(q0,q1,q2,q3);
        STEPF(q4);  STEPF(q5);  STEPF(q6);  STEPF(q7);  LOADG4(q4,q5,q6,q7);
        STEPF(q8);  STEPF(q9);  STEPF(q10); STEPF(q11); LOADG4(q8,q9,q10,q11);
        STEPF(q12); STEPF(q13); STEPF(q14); STEPF(q15); LOADG4(q12,q13,q14,q15);
        EXCHANGE(pp);
        pp ^= 1;
        t += 16;
    }
    {
        const int r = Tn - t;   // 0..15; halo degradation <= 30 <= 32 -> owned ok
        if (r > 0)  STEPF(q0);
        if (r > 1)  STEPF(q1);
        if (r > 2)  STEPF(q2);
        if (r > 3)  STEPF(q3);
        if (r > 4)  STEPF(q4);
        if (r > 5)  STEPF(q5);
        if (r > 6)  STEPF(q6);
        if (r > 7)  STEPF(q7);
        if (r > 8)  STEPF(q8);
        if (r > 9)  STEPF(q9);
        if (r > 10) STEPF(q10);
        if (r > 11) STEPF(q11);
        if (r > 12) STEPF(q12);
        if (r > 13) STEPF(q13);
        if (r > 14) STEPF(q14);
    }

    // readout: owned lanes (>=8) publish their 4 states
    if (lane >= 8) {
        const int gidx = 224 * wid - 32 + 4 * lane;   // global state index of a0
        afin[gidx]     = a0;
        afin[gidx + 1] = a1;
        afin[gidx + 2] = a2;
        afin[gidx + 3] = a3;
    }
    __syncthreads();
    if (tid == 0) {
        float tot = afin[2 * L] + afin[2 * L - 1];
        float lossb = 0.0f;
        if (tot > 0.0f) {
            double ll = log((double)tot)
                      + (double)E * 0.69314718055994530942
                      + (double)(-(double)Tn - (double)sl);
            lossb = (float)(-ll / (double)L);
        }
        loss_out[b] = lossb;
    }
    #undef STEPF
    #undef FMIXLO
    #undef FMIXHI
    #undef LOADG4
    #undef BARR
    #undef EXCHANGE
}

// ------------------------------------------------- fallback (round-3, proven)
__global__ __launch_bounds__(256)
void lse_kernel(const float* __restrict__ ap_all,
                const int* __restrict__ in_lens,
                float* __restrict__ lse_out)
{
    const int lane = threadIdx.x & 63;
    const int wglob = blockIdx.x * (blockDim.x >> 6) + (threadIdx.x >> 6);
    const int nwav = gridDim.x * (blockDim.x >> 6);
    const int nrows = 64 * T_MAXN;

    for (int row = wglob; row < nrows; row += nwav) {
        const int b = row / T_MAXN;
        const int L = in_lens[b];
        const float* rp = ap_all + (size_t)row * K_MAXN;
        const int c0 = lane * 8;
        const int cb = (c0 < 392) ? c0 : 392;
        const float4* p = reinterpret_cast<const float4*>(rp + cb);
        float4 x0 = p[0], x1 = p[1];
        float v[8] = {x0.x, x0.y, x0.z, x0.w, x1.x, x1.y, x1.z, x1.w};
        float m = -1.0f;
        #pragma unroll
        for (int j = 0; j < 8; ++j) {
            v[j] = (c0 + j < L) ? v[j] : -1e30f;
            m = fmaxf(m, v[j]);
        }
        #pragma unroll
        for (int off = 32; off; off >>= 1) m = fmaxf(m, __shfl_xor(m, off));
        float s = (lane == 0) ? __expf(-1.0f - m) : 0.0f;
        #pragma unroll
        for (int j = 0; j < 8; ++j) s += __expf(v[j] - m);
        #pragma unroll
        for (int off = 32; off; off >>= 1) s += __shfl_xor(s, off);
        if (lane == 0) lse_out[row] = m + __logf(s);
    }
}

__global__ __launch_bounds__(64)
void ctc_scan_kernel(const float* __restrict__ ap_all,
                     const int* __restrict__ in_lens,
                     const int* __restrict__ out_lens,
                     const float* __restrict__ lse_all,
                     float* __restrict__ loss_out)
{
    __shared__ float afin[1024];

    const int b    = blockIdx.x;
    const int lane = threadIdx.x;
    const int L    = in_lens[b];
    const int Tn   = out_lens[b];
    const float* ap  = ap_all + (size_t)b * (T_MAXN * K_MAXN);
    const float* lse = lse_all + b * T_MAXN;

    const float LOG2E = 1.4426950408889634f;
    const int c0 = lane * 8;
    const int cb = (c0 < 392) ? c0 : 392;
    const float* rbase = ap + cb;
    float fa0,fa1,fa2,fa3,fa4,fa5,fa6,fa7;
    float fb0,fb1,fb2,fb3,fb4,fb5,fb6,fb7;
    #define MASKC(J, FA, FB) do { bool ok = (c0 + (J)) < L; \
        FA = ok ? LOG2E : 0.0f; FB = ok ? LOG2E : -1000.0f; } while (0)
    MASKC(0,fa0,fb0); MASKC(1,fa1,fb1); MASKC(2,fa2,fb2); MASKC(3,fa3,fb3);
    MASKC(4,fa4,fb4); MASKC(5,fa5,fb5); MASKC(6,fa6,fb6); MASKC(7,fa7,fb7);
    #undef MASKC

    float4 p0a,p0b,p1a,p1b,p2a,p2b,p3a,p3b;
    #define LOADROW(PA, PB, T) do { \
        const float4* _p = reinterpret_cast<const float4*>(rbase + (size_t)(T) * K_MAXN); \
        PA = _p[0]; PB = _p[1]; } while (0)
    LOADROW(p0a,p0b,1); LOADROW(p1a,p1b,2); LOADROW(p2a,p2b,3); LOADROW(p3a,p3b,4);

    float sl = 0.0f;
    for (int t = lane; t < Tn; t += 64) sl += lse[t];
    #pragma unroll
    for (int off = 32; off; off >>= 1) sl += __shfl_xor(sl, off);

    float x00 = ap[0];
    float a0=0,a1=0,a2=0,a3=0,a4=0,a5=0,a6=0,a7=0;
    float a8=0,a9=0,a10=0,a11=0,a12=0,a13=0,a14=0,a15=0;
    if (lane == 0) {
        a0 = 1.0f;
        a1 = __builtin_amdgcn_exp2f(fmaf(x00, LOG2E, LOG2E));
    }
    int E = 0;

    #define STEP(A0, A1) do { \
        float t1 = __shfl_up(a15, 1); \
        t1 = lane ? t1 : 0.0f; \
        const float f0 = __builtin_amdgcn_exp2f(fmaf((A0).x, fa0, fb0)); \
        const float f1 = __builtin_amdgcn_exp2f(fmaf((A0).y, fa1, fb1)); \
        const float f2 = __builtin_amdgcn_exp2f(fmaf((A0).z, fa2, fb2)); \
        const float f3 = __builtin_amdgcn_exp2f(fmaf((A0).w, fa3, fb3)); \
        const float f4 = __builtin_amdgcn_exp2f(fmaf((A1).x, fa4, fb4)); \
        const float f5 = __builtin_amdgcn_exp2f(fmaf((A1).y, fa5, fb5)); \
        const float f6 = __builtin_amdgcn_exp2f(fmaf((A1).z, fa6, fb6)); \
        const float f7 = __builtin_amdgcn_exp2f(fmaf((A1).w, fa7, fb7)); \
        const float e0 = a0 + t1,   e1 = a2 + a1,   e2 = a4 + a3,   e3 = a6 + a5; \
        const float e4 = a8 + a7,   e5 = a10 + a9,  e6 = a12 + a11, e7 = a14 + a13; \
        const float o0 = a1 + e0,   o1 = a3 + e1,   o2 = a5 + e2,   o3 = a7 + e3; \
        const float o4 = a9 + e4,   o5 = a11 + e5,  o6 = a13 + e6,  o7 = a15 + e7; \
        a0 = e0; a2 = e1; a4 = e2; a6 = e3; a8 = e4; a10 = e5; a12 = e6; a14 = e7; \
        a1 = f0*o0; a3 = f1*o1; a5 = f2*o2; a7 = f3*o3; \
        a9 = f4*o4; a11 = f5*o5; a13 = f6*o6; a15 = f7*o7; \
    } while (0)

    #define RESCALE do { \
        float mx = fmaxf(fmaxf(fmaxf(fmaxf(a0,a1),fmaxf(a2,a3)),fmaxf(fmaxf(a4,a5),fmaxf(a6,a7))), \
                         fmaxf(fmaxf(fmaxf(a8,a9),fmaxf(a10,a11)),fmaxf(fmaxf(a12,a13),fmaxf(a14,a15)))); \
        _Pragma("unroll") \
        for (int off = 32; off; off >>= 1) mx = fmaxf(mx, __shfl_xor(mx, off)); \
        int e = (int)((__float_as_uint(mx) >> 23) & 0xFF) - 127; \
        if (e != 0) { \
            E += e; \
            a0 = ldexpf(a0,-e);  a1 = ldexpf(a1,-e);  a2 = ldexpf(a2,-e);  a3 = ldexpf(a3,-e); \
            a4 = ldexpf(a4,-e);  a5 = ldexpf(a5,-e);  a6 = ldexpf(a6,-e);  a7 = ldexpf(a7,-e); \
            a8 = ldexpf(a8,-e);  a9 = ldexpf(a9,-e);  a10= ldexpf(a10,-e); a11= ldexpf(a11,-e); \
            a12= ldexpf(a12,-e); a13= ldexpf(a13,-e); a14= ldexpf(a14,-e); a15= ldexpf(a15,-e); \
        } \
    } while (0)

    int t = 1;
    while (t + 3 < Tn) {
        int tl;
        STEP(p0a,p0b); tl = (t+4 < T_MAXN) ? t+4 : T_MAXN-1; LOADROW(p0a,p0b,tl);
        STEP(p1a,p1b); tl = (t+5 < T_MAXN) ? t+5 : T_MAXN-1; LOADROW(p1a,p1b,tl);
        STEP(p2a,p2b); tl = (t+6 < T_MAXN) ? t+6 : T_MAXN-1; LOADROW(p2a,p2b,tl);
        STEP(p3a,p3b); tl = (t+7 < T_MAXN) ? t+7 : T_MAXN-1; LOADROW(p3a,p3b,tl);
        if ((t & 7) == 5) RESCALE;
        t += 4;
    }
    if (t < Tn) { STEP(p0a,p0b); ++t; }
    if (t < Tn) { STEP(p1a,p1b); ++t; }
    if (t < Tn) { STEP(p2a,p2b); ++t; }

    afin[16*lane+0]=a0;  afin[16*lane+1]=a1;  afin[16*lane+2]=a2;  afin[16*lane+3]=a3;
    afin[16*lane+4]=a4;  afin[16*lane+5]=a5;  afin[16*lane+6]=a6;  afin[16*lane+7]=a7;
    afin[16*lane+8]=a8;  afin[16*lane+9]=a9;  afin[16*lane+10]=a10; afin[16*lane+11]=a11;
    afin[16*lane+12]=a12; afin[16*lane+13]=a13; afin[16*lane+14]=a14; afin[16*lane+15]=a15;
    __syncthreads();
    if (lane == 0) {
        float tot = afin[2*L] + afin[2*L-1];
        float lossb = 0.0f;
        if (tot > 0.0f) {
            double ll = log((double)tot)
                      + (double)E * 0.69314718055994530942
                      + (double)(-(double)Tn - (double)sl);
            lossb = (float)(-ll / (double)L);
        }
        loss_out[b] = lossb;
    }
    #undef STEP
    #undef RESCALE
    #undef LOADROW
}

// ---------------------------------------------------------------- mean
__global__ void mean_kernel(const float* __restrict__ loss, float* __restrict__ out)
{
    float v = loss[threadIdx.x];   // 64 threads
    #pragma unroll
    for (int off = 32; off; off >>= 1) v += __shfl_xor(v, off);
    if (threadIdx.x == 0) out[0] = v * (1.0f / 64.0f);
}

extern "C" void kernel_launch(void* const* d_in, const int* in_sizes, int n_in,
                              void* d_out, int out_size, void* d_ws, size_t ws_size,
                              hipStream_t stream)
{
    // setup_inputs order: attn (unused), in_lens, out_lens, attn_logprob
    const int*   in_lens  = (const int*)d_in[1];
    const int*   out_lens = (const int*)d_in[2];
    const float* ap       = (const float*)d_in[3];
    float*       out      = (float*)d_out;

    if (ws_size >= WS_NEED) {
        char*     wsb     = (char*)d_ws;
        _Float16* g       = (_Float16*)wsb;
        float*    lse_ws  = (float*)(wsb + LSE_OFF);
        float*    zb      = (float*)(wsb + ZERO_OFF);
        float*    loss_ws = (float*)(wsb + LOSS_OFF);
        hipLaunchKernelGGL(prep_kernel, dim3(32, 64), dim3(256), 0, stream,
                           ap, in_lens, out_lens, lse_ws, g, zb);
        hipLaunchKernelGGL(ctc_scan4w_kernel, dim3(64), dim3(256), 0, stream,
                           (const char*)wsb, in_lens, out_lens, loss_ws);
        hipLaunchKernelGGL(mean_kernel, dim3(1), dim3(64), 0, stream, loss_ws, out);
    } else {
        float* lse_ws  = (float*)d_ws;
        float* loss_ws = (float*)((char*)d_ws + (size_t)64 * T_MAXN * 4);
        hipLaunchKernelGGL(lse_kernel, dim3(512), dim3(256), 0, stream,
                           ap, in_lens, lse_ws);
        hipLaunchKernelGGL(ctc_scan_kernel, dim3(64), dim3(64), 0, stream,
                           ap, in_lens, out_lens, lse_ws, loss_ws);
        hipLaunchKernelGGL(mean_kernel, dim3(1), dim3(64), 0, stream, loss_ws, out);
    }
}